// Round 6
// baseline (235.271 us; speedup 1.0000x reference)
//
#include <hip/hip_runtime.h>

typedef __bf16 bf16x8 __attribute__((ext_vector_type(8)));
typedef float f32x4 __attribute__((ext_vector_type(4)));
typedef unsigned short us4 __attribute__((ext_vector_type(4)));

constexpr int TT = 2048;   // tokens
constexpr int CC = 2048;   // channels
constexpr int HH = 16;     // heads
constexpr int DD = 128;    // head dim

__device__ __forceinline__ unsigned short f2bf(float f) {
  unsigned u = __builtin_bit_cast(unsigned, f);
  u += 0x7FFFu + ((u >> 16) & 1u);
  return (unsigned short)(u >> 16);
}
__device__ __forceinline__ float bf2f(unsigned short b) {
  unsigned u = ((unsigned)b) << 16;
  return __builtin_bit_cast(float, u);
}

// async global->LDS, 16B per lane. C-style casts lower to addrspacecast.
__device__ __forceinline__ void gld_lds16(const unsigned short* g, unsigned short* l) {
  __builtin_amdgcn_global_load_lds(
      (const __attribute__((address_space(1))) unsigned int*)g,
      (__attribute__((address_space(3))) unsigned int*)l,
      16, 0, 0);
}

// split-slot table for QBLK=128, SPLIT=512 keys: ns(qt)=qt/4+1, 40 slots/head
__device__ __forceinline__ int soff(int qt) {
  int g = qt >> 2, rem = qt & 3;
  return (g + 1) * (2 * g + rem);
}

// ---------------- f32 -> bf16 convert ----------------
__global__ __launch_bounds__(256) void k_f32_to_bf16(
    const float* __restrict__ src, unsigned short* __restrict__ dst, int n8) {
  int i = blockIdx.x * 256 + threadIdx.x;
  if (i >= n8) return;
  const float4* s = (const float4*)src;
  float4 a = s[2 * i], b = s[2 * i + 1];
  us4 lo = { f2bf(a.x), f2bf(a.y), f2bf(a.z), f2bf(a.w) };
  us4 hi = { f2bf(b.x), f2bf(b.y), f2bf(b.z), f2bf(b.w) };
  us4* d = (us4*)dst;
  d[2 * i] = lo;
  d[2 * i + 1] = hi;
}

// ---------------- 256x256 GEMM, counted-vmcnt 4-phase schedule ----------------
// C = A(MxK) * B(NxK)^T. 512 threads = 8 waves (2M x 4N), BK=64.
// LDS: 2 buf x 2 half x (128x64) per matrix = 128KB, XOR-swizzled (stage src + read).
// Stage ledger (steady state, tile T): p1 stages (T+1).A1, p3 stages (T+2).B0,
// p4 stages (T+2).{B1,A0}; once-per-tile s_waitcnt vmcnt(6) leaves tile T+2's
// 3 half-tiles in flight (T4: never drain to 0 in the main loop).
template <int MODE>
__global__ __launch_bounds__(512, 2) void k_gemm256(
    const unsigned short* __restrict__ A, const unsigned short* __restrict__ B,
    int N, int K, int kspan,
    float* __restrict__ out0, float* __restrict__ out1, float* __restrict__ out2) {
  __shared__ alignas(16) unsigned short As[2][2][128 * 64];
  __shared__ alignas(16) unsigned short Bs[2][2][128 * 64];
  const int tid = threadIdx.x;

  // T1: bijective XCD swizzle over (x,y); launch configs keep nwg % 8 == 0
  const int nbx = gridDim.x;
  const int nwg = nbx * gridDim.y;
  int flat = blockIdx.y * nbx + blockIdx.x;
  flat = (flat & 7) * (nwg >> 3) + (flat >> 3);
  const int m0 = (flat / nbx) * 256, n0 = (flat % nbx) * 256;

  const int kbeg = blockIdx.z * kspan;
  const int NT = kspan >> 6;
  const int wid = tid >> 6, lane = tid & 63;
  const int wr = wid >> 2, wc = wid & 3;
  const int lr = lane & 15, lg = lane >> 4;
  const int swz = lr & 7;
  const int bh = wc >> 1;             // B half this wave reads
  const int brow0 = (wc & 1) * 64;    // row base within that half

  // staging: chunk c = tid + j*512 of a 128x64 half-tile; row=c>>3, chunk-in-row=c&7
  const int sr0 = tid >> 3, sc0 = tid & 7;
  const unsigned short* Ab = A + kbeg;
  const unsigned short* Bb = B + kbeg;

  auto stageA = [&](int buf, int half, int koff) {
#pragma unroll
    for (int j = 0; j < 2; ++j) {
      const int r = sr0 + j * 64;
      gld_lds16(Ab + (size_t)(m0 + half * 128 + r) * K + koff + ((sc0 ^ (r & 7)) * 8),
                &As[buf][half][(tid + j * 512) * 8]);
    }
  };
  auto stageB = [&](int buf, int half, int koff) {
#pragma unroll
    for (int j = 0; j < 2; ++j) {
      const int r = sr0 + j * 64;
      gld_lds16(Bb + (size_t)(n0 + half * 128 + r) * K + koff + ((sc0 ^ (r & 7)) * 8),
                &Bs[buf][half][(tid + j * 512) * 8]);
    }
  };

  f32x4 acc[8][4] = {};
  bf16x8 av_lo[4][2], av_hi[4][2], bv_a[2][2], bv_b[2][2];

  // ---- prologue: tile0 fully + tile1 {B0,B1,A0}; vmcnt(6) ----
  stageA(0, 0, 0); stageA(0, 1, 0); stageB(0, 0, 0); stageB(0, 1, 0);
  if (NT > 1) {
    stageB(1, 0, 64); stageB(1, 1, 64); stageA(1, 0, 64);
    asm volatile("s_waitcnt vmcnt(6)" ::: "memory");
  } else {
    asm volatile("s_waitcnt vmcnt(0)" ::: "memory");
  }
  __builtin_amdgcn_sched_barrier(0);
  __builtin_amdgcn_s_barrier();

  for (int t = 0; t < NT; ++t) {
    const int cur = t & 1, nxt = cur ^ 1;
    const int kN1 = (t + 1) * 64, kN2 = (t + 2) * 64;

    // ===== phase 1: read A-lo + B-a ; stage (t+1).A1 =====
#pragma unroll
    for (int im = 0; im < 4; ++im)
#pragma unroll
      for (int kk = 0; kk < 2; ++kk)
        av_lo[im][kk] = *(const bf16x8*)(&As[cur][wr][(im * 16 + lr) * 64 + (((kk * 4 + lg) ^ swz) * 8)]);
#pragma unroll
    for (int in = 0; in < 2; ++in)
#pragma unroll
      for (int kk = 0; kk < 2; ++kk)
        bv_a[in][kk] = *(const bf16x8*)(&Bs[cur][bh][(brow0 + in * 16 + lr) * 64 + (((kk * 4 + lg) ^ swz) * 8)]);
    if (t + 1 < NT) stageA(nxt, 1, kN1);
    __builtin_amdgcn_s_barrier();
    asm volatile("s_waitcnt lgkmcnt(0)" ::: "memory");
    __builtin_amdgcn_sched_barrier(0);
    __builtin_amdgcn_s_setprio(1);
#pragma unroll
    for (int im = 0; im < 4; ++im)
#pragma unroll
      for (int in = 0; in < 2; ++in)
#pragma unroll
        for (int kk = 0; kk < 2; ++kk)
          acc[im][in] = __builtin_amdgcn_mfma_f32_16x16x32_bf16(av_lo[im][kk], bv_a[in][kk], acc[im][in], 0, 0, 0);
    __builtin_amdgcn_s_setprio(0);
    __builtin_amdgcn_sched_barrier(0);
    __builtin_amdgcn_s_barrier();

    // ===== phase 2: read B-b =====
#pragma unroll
    for (int in = 0; in < 2; ++in)
#pragma unroll
      for (int kk = 0; kk < 2; ++kk)
        bv_b[in][kk] = *(const bf16x8*)(&Bs[cur][bh][(brow0 + (2 + in) * 16 + lr) * 64 + (((kk * 4 + lg) ^ swz) * 8)]);
    __builtin_amdgcn_s_barrier();
    asm volatile("s_waitcnt lgkmcnt(0)" ::: "memory");
    __builtin_amdgcn_sched_barrier(0);
    __builtin_amdgcn_s_setprio(1);
#pragma unroll
    for (int im = 0; im < 4; ++im)
#pragma unroll
      for (int in = 0; in < 2; ++in)
#pragma unroll
        for (int kk = 0; kk < 2; ++kk)
          acc[im][2 + in] = __builtin_amdgcn_mfma_f32_16x16x32_bf16(av_lo[im][kk], bv_b[in][kk], acc[im][2 + in], 0, 0, 0);
    __builtin_amdgcn_s_setprio(0);
    __builtin_amdgcn_sched_barrier(0);
    __builtin_amdgcn_s_barrier();

    // ===== phase 3: read A-hi ; stage (t+2).B0 (cur B0 reads done after p2 barrier) =====
#pragma unroll
    for (int im = 0; im < 4; ++im)
#pragma unroll
      for (int kk = 0; kk < 2; ++kk)
        av_hi[im][kk] = *(const bf16x8*)(&As[cur][wr][((4 + im) * 16 + lr) * 64 + (((kk * 4 + lg) ^ swz) * 8)]);
    if (t + 2 < NT) stageB(cur, 0, kN2);
    __builtin_amdgcn_s_barrier();
    asm volatile("s_waitcnt lgkmcnt(0)" ::: "memory");
    __builtin_amdgcn_sched_barrier(0);
    __builtin_amdgcn_s_setprio(1);
#pragma unroll
    for (int im = 0; im < 4; ++im)
#pragma unroll
      for (int in = 0; in < 2; ++in)
#pragma unroll
        for (int kk = 0; kk < 2; ++kk)
          acc[4 + im][2 + in] = __builtin_amdgcn_mfma_f32_16x16x32_bf16(av_hi[im][kk], bv_b[in][kk], acc[4 + im][2 + in], 0, 0, 0);
    __builtin_amdgcn_s_setprio(0);
    __builtin_amdgcn_sched_barrier(0);
    __builtin_amdgcn_s_barrier();

    // ===== phase 4: stage (t+2).{B1,A0} ; MFMA hi x a ; counted wait =====
    if (t + 2 < NT) { stageB(cur, 1, kN2); stageA(cur, 0, kN2); }
    __builtin_amdgcn_s_setprio(1);
#pragma unroll
    for (int im = 0; im < 4; ++im)
#pragma unroll
      for (int in = 0; in < 2; ++in)
#pragma unroll
        for (int kk = 0; kk < 2; ++kk)
          acc[4 + im][in] = __builtin_amdgcn_mfma_f32_16x16x32_bf16(av_hi[im][kk], bv_a[in][kk], acc[4 + im][in], 0, 0, 0);
    __builtin_amdgcn_s_setprio(0);
    __builtin_amdgcn_sched_barrier(0);
    if (t + 2 < NT) {
      asm volatile("s_waitcnt vmcnt(6)" ::: "memory");  // leave (t+2)'s 3 halves in flight
    } else {
      asm volatile("s_waitcnt vmcnt(0)" ::: "memory");  // tail: force last tile resident
    }
    __builtin_amdgcn_sched_barrier(0);
    __builtin_amdgcn_s_barrier();
  }

  // ---- epilogue ----
  float* dst = (MODE == 1 && blockIdx.z) ? out1 : out0;
#pragma unroll
  for (int mf = 0; mf < 8; ++mf) {
    const int row = m0 + wr * 128 + mf * 16 + lg * 4;
#pragma unroll
    for (int nf = 0; nf < 4; ++nf) {
      const int col = n0 + wc * 64 + nf * 16 + lr;
#pragma unroll
      for (int r = 0; r < 4; ++r) {
        float v = acc[mf][nf][r];
        int rr = row + r;
        if (MODE == 0) {
          if (col < 2048) {
            out0[(size_t)rr * 2048 + col] = v;
          } else if (col < 4096) {
            int c = col - 2048;
            out1[(size_t)(c >> 7) * (TT * DD) + (size_t)rr * DD + (c & 127)] = v;
          } else {
            int c = col - 4096;
            out2[(size_t)(c >> 7) * (TT * DD) + (size_t)rr * DD + (c & 127)] = v;
          }
        } else {
          dst[(size_t)rr * N + col] = v;
        }
      }
    }
  }
}

// ---------------- RoPE + scale, pack q/k as bf16 [h][t][d] ----------------
__global__ __launch_bounds__(256) void k_rope(
    const float* __restrict__ Qf, const float* __restrict__ Kraw,
    const float* __restrict__ sqk,
    unsigned short* __restrict__ qb, unsigned short* __restrict__ kb) {
  const int t = blockIdx.x;
  for (int i = threadIdx.x; i < HH * 64; i += 256) {
    int h = i >> 6, dp = i & 63;
    float theta = expf(-(float)dp * 0.14391156831212787f);
    float ang = (float)t * theta;
    float sn, cs;
    sincosf(ang, &sn, &cs);
    float qr = Qf[(size_t)t * CC + h * DD + dp];
    float qi = Qf[(size_t)t * CC + h * DD + dp + 64];
    const float* kp = Kraw + (size_t)h * TT * DD + (size_t)t * DD;
    float kr = kp[dp], ki = kp[dp + 64];
    float sr = sqk[h * DD + dp];
    float si = sqk[h * DD + dp + 64];
    float qsr = sr * 512.0f, qsi = si * 512.0f;                         // sqrt(C)*sqrt(D)
    float ksr = sr * 45.25483399593904f, ksi = si * 45.25483399593904f; // sqrt(C)
    unsigned short* qo = qb + ((size_t)h * TT + t) * DD;
    unsigned short* ko = kb + ((size_t)h * TT + t) * DD;
    qo[dp]      = f2bf((qr * cs - qi * sn) * qsr);
    qo[dp + 64] = f2bf((qr * sn + qi * cs) * qsi);
    ko[dp]      = f2bf((kr * cs - ki * sn) * ksr);
    ko[dp + 64] = f2bf((kr * sn + ki * cs) * ksi);
  }
}

// ---------------- V transpose: new_v f32 [h][t][d] -> vt bf16 [h][d][t] ----------------
__global__ __launch_bounds__(256) void k_vt(
    const float* __restrict__ Vraw, unsigned short* __restrict__ vt) {
  const int h = blockIdx.z;
  const int t0 = blockIdx.x * 64, d0 = blockIdx.y * 64;
  __shared__ unsigned short tile[64][65];
  const float* vp = Vraw + (size_t)h * TT * DD;
  for (int i = threadIdx.x; i < 4096; i += 256) {
    int r = i >> 6, c = i & 63;
    tile[r][c] = f2bf(vp[(size_t)(t0 + r) * DD + d0 + c]);
  }
  __syncthreads();
  unsigned short* op = vt + (size_t)h * DD * TT;
  for (int i = threadIdx.x; i < 4096; i += 256) {
    int dr = i >> 6, tc = i & 63;
    op[(size_t)(d0 + dr) * TT + t0 + tc] = tile[tc][dr];
  }
}

// ---------------- causal flash attention, 8-wave LDS-staged, split-K ----------------
__global__ __launch_bounds__(512) void k_attn_split(
    const unsigned short* __restrict__ qb, const unsigned short* __restrict__ kb,
    const unsigned short* __restrict__ vt,
    unsigned short* __restrict__ po, float* __restrict__ marr, float* __restrict__ larr) {
  const int qt = blockIdx.x, h = blockIdx.y, s = blockIdx.z;
  if (4 * s > qt) return;
  const int slot = h * 40 + soff(qt) + s;
  const int kbeg = 512 * s;
  const int kend = min(kbeg + 512, 128 * qt + 128);
  const int ntiles = (kend - kbeg) >> 6;
  const int tid = threadIdx.x;
  const int wid = tid >> 6, lane = tid & 63;
  const int lr = lane & 15, lg = lane >> 4;
  const int q0 = qt * 128 + wid * 16;

  __shared__ alignas(16) unsigned short Ks[64 * 128];
  __shared__ alignas(16) unsigned short Vs[128 * 64];
  __shared__ alignas(16) unsigned short P[8][16][72];

  const unsigned short* qh = qb + (size_t)h * TT * DD;
  const unsigned short* kh = kb + (size_t)h * TT * DD;
  const unsigned short* vh = vt + (size_t)h * DD * TT;

  bf16x8 qf[4];
#pragma unroll
  for (int c = 0; c < 4; ++c)
    qf[c] = *(const bf16x8*)(qh + (size_t)(q0 + lr) * DD + c * 32 + lg * 8);

  f32x4 acc[8] = {};
  float mrow[4] = {-3e38f, -3e38f, -3e38f, -3e38f};
  float lsum[4] = {0.f, 0.f, 0.f, 0.f};

  for (int kt = 0; kt < ntiles; ++kt) {
    const int k0 = kbeg + kt * 64;
#pragma unroll
    for (int half = 0; half < 2; ++half) {
      int ch = tid + half * 512;
      int r = ch >> 4, c4 = ch & 15;
      gld_lds16(kh + (size_t)(k0 + r) * DD + ((c4 ^ (r & 7)) * 8), Ks + ch * 8);
    }
#pragma unroll
    for (int half = 0; half < 2; ++half) {
      int ch = tid + half * 512;
      int d = ch >> 3, c8 = ch & 7;
      gld_lds16(vh + (size_t)d * TT + k0 + ((c8 ^ (d & 7)) * 8), Vs + ch * 8);
    }
    __syncthreads();

    if (k0 <= q0 + 15) {
      f32x4 sv[4] = {};
#pragma unroll
      for (int ktile = 0; ktile < 4; ++ktile) {
        const int row = ktile * 16 + lr;
#pragma unroll
        for (int c = 0; c < 4; ++c) {
          int chn = (c * 4 + lg) ^ (lr & 7);
          bf16x8 kf = *(const bf16x8*)(Ks + row * 128 + chn * 8);
          sv[ktile] = __builtin_amdgcn_mfma_f32_16x16x32_bf16(qf[c], kf, sv[ktile], 0, 0, 0);
        }
      }
      if (k0 + 63 > q0) {
#pragma unroll
        for (int ktile = 0; ktile < 4; ++ktile)
#pragma unroll
          for (int r = 0; r < 4; ++r) {
            int key = k0 + ktile * 16 + lr;
            int qrow = q0 + lg * 4 + r;
            if (key > qrow) sv[ktile][r] = -1e30f;
          }
      }
      float pmax[4];
#pragma unroll
      for (int r = 0; r < 4; ++r)
        pmax[r] = fmaxf(fmaxf(sv[0][r], sv[1][r]), fmaxf(sv[2][r], sv[3][r]));
#pragma unroll
      for (int msk = 1; msk <= 8; msk <<= 1)
#pragma unroll
        for (int r = 0; r < 4; ++r) pmax[r] = fmaxf(pmax[r], __shfl_xor(pmax[r], msk));
      float p[4][4], ps[4], scl[4];
#pragma unroll
      for (int r = 0; r < 4; ++r) {
        float mn = fmaxf(mrow[r], pmax[r]);
        scl[r] = __expf(mrow[r] - mn);
        mrow[r] = mn;
        ps[r] = 0.f;
#pragma unroll
        for (int ktile = 0; ktile < 4; ++ktile) {
          p[ktile][r] = __expf(sv[ktile][r] - mn);
          ps[r] += p[ktile][r];
        }
      }
#pragma unroll
      for (int msk = 1; msk <= 8; msk <<= 1)
#pragma unroll
        for (int r = 0; r < 4; ++r) ps[r] += __shfl_xor(ps[r], msk);
#pragma unroll
      for (int r = 0; r < 4; ++r) lsum[r] = lsum[r] * scl[r] + ps[r];
#pragma unroll
      for (int n = 0; n < 8; ++n)
#pragma unroll
        for (int r = 0; r < 4; ++r) acc[n][r] *= scl[r];
#pragma unroll
      for (int ktile = 0; ktile < 4; ++ktile)
#pragma unroll
        for (int r = 0; r < 4; ++r)
          P[wid][lg * 4 + r][ktile * 16 + lr] = f2bf(p[ktile][r]);
      asm volatile("s_waitcnt lgkmcnt(0)" ::: "memory");
      __builtin_amdgcn_sched_barrier(0);
      bf16x8 pf[2];
#pragma unroll
      for (int ks = 0; ks < 2; ++ks)
        pf[ks] = *(const bf16x8*)(&P[wid][lr][ks * 32 + lg * 8]);
#pragma unroll
      for (int n = 0; n < 8; ++n) {
        const int row = n * 16 + lr;
#pragma unroll
        for (int ks = 0; ks < 2; ++ks) {
          int chn = (ks * 4 + lg) ^ (lr & 7);
          bf16x8 vf = *(const bf16x8*)(Vs + row * 64 + chn * 8);
          acc[n] = __builtin_amdgcn_mfma_f32_16x16x32_bf16(pf[ks], vf, acc[n], 0, 0, 0);
        }
      }
    }
    __syncthreads();
  }

  unsigned short* pob = po + (size_t)slot * (128 * DD);
#pragma unroll
  for (int n = 0; n < 8; ++n)
#pragma unroll
    for (int r = 0; r < 4; ++r) {
      int row = wid * 16 + lg * 4 + r;
      pob[(size_t)row * DD + n * 16 + lr] = f2bf(acc[n][r]);
    }
  if (lr == 0) {
#pragma unroll
    for (int r = 0; r < 4; ++r) {
      int row = wid * 16 + lg * 4 + r;
      marr[(size_t)slot * 128 + row] = mrow[r];
      larr[(size_t)slot * 128 + row] = lsum[r];
    }
  }
}

// ---------------- split reduce ----------------
__global__ __launch_bounds__(256) void k_attn_reduce(
    const unsigned short* __restrict__ po, const float* __restrict__ marr,
    const float* __restrict__ larr, unsigned short* __restrict__ ob) {
  const int qt = blockIdx.x, h = blockIdx.y;
  const int ns = (qt >> 2) + 1;
  const int sb = h * 40 + soff(qt);
  const int tid = threadIdx.x;
  const int row = tid >> 1, d0 = (tid & 1) * 64;
  float mstar = -3e38f;
  for (int s = 0; s < ns; ++s) mstar = fmaxf(mstar, marr[(size_t)(sb + s) * 128 + row]);
  float w[4];
  float ltot = 0.f;
  for (int s = 0; s < ns; ++s) {
    w[s] = __expf(marr[(size_t)(sb + s) * 128 + row] - mstar);
    ltot += w[s] * larr[(size_t)(sb + s) * 128 + row];
  }
  float inv = 1.0f / ltot;
  float o[64] = {};
  for (int s = 0; s < ns; ++s) {
    const bf16x8* pp = (const bf16x8*)(po + (size_t)(sb + s) * (128 * DD) + (size_t)row * DD + d0);
    float ws = w[s];
#pragma unroll
    for (int j = 0; j < 8; ++j) {
      bf16x8 v = pp[j];
#pragma unroll
      for (int e = 0; e < 8; ++e) o[j * 8 + e] += ws * (float)v[e];
    }
  }
  unsigned short* op = ob + (size_t)(qt * 128 + row) * CC + h * DD + d0;
#pragma unroll
  for (int j = 0; j < 16; ++j) {
    us4 t = { f2bf(o[4 * j] * inv), f2bf(o[4 * j + 1] * inv),
              f2bf(o[4 * j + 2] * inv), f2bf(o[4 * j + 3] * inv) };
    ((us4*)op)[j] = t;
  }
}

// ---------------- row l2norm over sum of two split-K partials ----------------
__global__ __launch_bounds__(256) void k_l2norm(
    const float* __restrict__ Of0, const float* __restrict__ Of1, float* __restrict__ out) {
  const int t = blockIdx.x;
  const int tid = threadIdx.x;
  const float4* p0 = (const float4*)(Of0 + (size_t)t * CC);
  const float4* p1 = (const float4*)(Of1 + (size_t)t * CC);
  float4 a = p0[2 * tid], b = p0[2 * tid + 1];
  float4 a1 = p1[2 * tid], b1 = p1[2 * tid + 1];
  a.x += a1.x; a.y += a1.y; a.z += a1.z; a.w += a1.w;
  b.x += b1.x; b.y += b1.y; b.z += b1.z; b.w += b1.w;
  float ss = a.x * a.x + a.y * a.y + a.z * a.z + a.w * a.w +
             b.x * b.x + b.y * b.y + b.z * b.z + b.w * b.w;
#pragma unroll
  for (int msk = 1; msk < 64; msk <<= 1) ss += __shfl_xor(ss, msk);
  __shared__ float red[4];
  if ((tid & 63) == 0) red[tid >> 6] = ss;
  __syncthreads();
  ss = red[0] + red[1] + red[2] + red[3];
  float sc = 1.0f / fmaxf(sqrtf(ss), 1e-12f);
  float4 oa = { a.x * sc, a.y * sc, a.z * sc, a.w * sc };
  float4 obv = { b.x * sc, b.y * sc, b.z * sc, b.w * sc };
  float4* o = (float4*)(out + (size_t)t * CC);
  o[2 * tid] = oa;
  o[2 * tid + 1] = obv;
}

extern "C" void kernel_launch(void* const* d_in, const int* in_sizes, int n_in,
                              void* d_out, int out_size, void* d_ws, size_t ws_size,
                              hipStream_t stream) {
  const float* x   = (const float*)d_in[0];
  const float* wq  = (const float*)d_in[1];
  const float* wk  = (const float*)d_in[2];
  const float* wv  = (const float*)d_in[3];
  const float* wo  = (const float*)d_in[4];
  const float* sqk = (const float*)d_in[5];

  float* out_norm = (float*)d_out;
  float* out_k = out_norm + (size_t)4 * 1024 * 1024;
  float* out_v = out_norm + (size_t)8 * 1024 * 1024;

  char* ws = (char*)d_ws;
  unsigned short* xb  = (unsigned short*)(ws);                      // 0..8MB  (dead after QKV)
  unsigned short* w1b = (unsigned short*)(ws + (8u << 20));         // 8..32MB (dead after QKV)
  unsigned short* wob = (unsigned short*)(ws + (32u << 20));
  unsigned short* qb  = (unsigned short*)(ws + (40u << 20));
  unsigned short* kb  = (unsigned short*)(ws + (48u << 20));
  unsigned short* vtb = (unsigned short*)(ws + (56u << 20));
  unsigned short* obb = (unsigned short*)(ws + (64u << 20));
  float* Qf = (float*)(ws + (72u << 20));

  // attention split partials reuse 0..24MB (dead after QKV GEMM)
  unsigned short* po = (unsigned short*)(ws);                       // 640 slots * 32KB = 20MB
  float* marr = (float*)(ws + (22u << 20));
  float* larr = (float*)(ws + (23u << 20));

  // out-proj split-K partials: Of0 reuses Qf (dead after rope), Of1 reuses 0..16MB
  float* Of0 = Qf;
  float* Of1 = (float*)(ws);

  const int n8 = (CC * CC) / 8;
  k_f32_to_bf16<<<n8 / 256, 256, 0, stream>>>(x,  xb, n8);
  k_f32_to_bf16<<<n8 / 256, 256, 0, stream>>>(wq, w1b, n8);
  k_f32_to_bf16<<<n8 / 256, 256, 0, stream>>>(wk, w1b + (size_t)4 * 1024 * 1024, n8);
  k_f32_to_bf16<<<n8 / 256, 256, 0, stream>>>(wv, w1b + (size_t)8 * 1024 * 1024, n8);
  k_f32_to_bf16<<<n8 / 256, 256, 0, stream>>>(wo, wob, n8);

  // fused QKV projection: 2048 x 6144 x 2048 (192 blocks, nwg%8==0)
  k_gemm256<0><<<dim3(24, 8, 1), 512, 0, stream>>>(xb, w1b, 3 * CC, CC, CC, Qf, out_k, out_v);

  k_rope<<<TT, 256, 0, stream>>>(Qf, out_k, sqk, qb, kb);
  k_vt<<<dim3(32, 2, 16), 256, 0, stream>>>(out_v, vtb);

  k_attn_split<<<dim3(16, 16, 4), 512, 0, stream>>>(qb, kb, vtb, po, marr, larr);
  k_attn_reduce<<<dim3(16, 16), 256, 0, stream>>>(po, marr, larr, obb);

  // output projection: 2048 x 2048 x 2048, split-K=2 (64 blocks/slice, nwg%8==0)
  k_gemm256<1><<<dim3(8, 8, 2), 512, 0, stream>>>(obb, wob, CC, CC, CC / 2, Of0, Of1, nullptr);

  k_l2norm<<<TT, 256, 0, stream>>>(Of0, Of1, out_norm);
}

// Round 7
// 226.860 us; speedup vs baseline: 1.0371x; 1.0371x over previous
//
#include <hip/hip_runtime.h>

typedef __bf16 bf16x8 __attribute__((ext_vector_type(8)));
typedef float f32x4 __attribute__((ext_vector_type(4)));
typedef unsigned short us4 __attribute__((ext_vector_type(4)));

constexpr int TT = 2048;   // tokens
constexpr int CC = 2048;   // channels
constexpr int HH = 16;     // heads
constexpr int DD = 128;    // head dim

__device__ __forceinline__ unsigned short f2bf(float f) {
  unsigned u = __builtin_bit_cast(unsigned, f);
  u += 0x7FFFu + ((u >> 16) & 1u);
  return (unsigned short)(u >> 16);
}
__device__ __forceinline__ float bf2f(unsigned short b) {
  unsigned u = ((unsigned)b) << 16;
  return __builtin_bit_cast(float, u);
}

// async global->LDS, 16B per lane. C-style casts lower to addrspacecast.
__device__ __forceinline__ void gld_lds16(const unsigned short* g, unsigned short* l) {
  __builtin_amdgcn_global_load_lds(
      (const __attribute__((address_space(1))) unsigned int*)g,
      (__attribute__((address_space(3))) unsigned int*)l,
      16, 0, 0);
}

// split-slot table for QBLK=128, SPLIT=512 keys: ns(qt)=qt/4+1, 40 slots/head
__device__ __forceinline__ int soff(int qt) {
  int g = qt >> 2, rem = qt & 3;
  return (g + 1) * (2 * g + rem);
}

// ---------------- f32 -> bf16 convert ----------------
__global__ __launch_bounds__(256) void k_f32_to_bf16(
    const float* __restrict__ src, unsigned short* __restrict__ dst, int n8) {
  int i = blockIdx.x * 256 + threadIdx.x;
  if (i >= n8) return;
  const float4* s = (const float4*)src;
  float4 a = s[2 * i], b = s[2 * i + 1];
  us4 lo = { f2bf(a.x), f2bf(a.y), f2bf(a.z), f2bf(a.w) };
  us4 hi = { f2bf(b.x), f2bf(b.y), f2bf(b.z), f2bf(b.w) };
  us4* d = (us4*)dst;
  d[2 * i] = lo;
  d[2 * i + 1] = hi;
}

// ---------------- 256x256 GEMM: 3-barrier K-tile, read/MFMA overlap ----------------
// C = A(MxK) * B(NxK)^T. 512 threads = 8 waves (2M x 4N), BK=64.
// LDS: 2 buf x 2 half x (128x64) per matrix = 128KB, XOR-swizzled.
// Tile t stages tile t+2 into its own buffer after consumption (MID barriers);
// vmcnt(8) at tile end forces t+1 resident, keeps t+2's 8 loads in flight.
template <int MODE>
__global__ __launch_bounds__(512, 2) void k_gemm256(
    const unsigned short* __restrict__ A, const unsigned short* __restrict__ B,
    int N, int K, int kspan,
    float* __restrict__ out0, float* __restrict__ out1,
    float* __restrict__ out2, float* __restrict__ out3) {
  __shared__ alignas(16) unsigned short As[2][2][128 * 64];
  __shared__ alignas(16) unsigned short Bs[2][2][128 * 64];
  const int tid = threadIdx.x;
  const int m0 = blockIdx.y * 256, n0 = blockIdx.x * 256;   // plain raster (swizzle reverted)
  const int kbeg = blockIdx.z * kspan;
  const int NT = kspan >> 6;
  const int wid = tid >> 6, lane = tid & 63;
  const int wr = wid >> 2, wc = wid & 3;
  const int lr = lane & 15, lg = lane >> 4;
  const int swz = lr & 7;
  const int bh = wc >> 1;
  const int brow0 = (wc & 1) * 64;

  const int sr0 = tid >> 3, sc0 = tid & 7;
  const unsigned short* Ab = A + kbeg;
  const unsigned short* Bb = B + kbeg;

  auto stageA = [&](int buf, int half, int koff) {
#pragma unroll
    for (int j = 0; j < 2; ++j) {
      const int r = sr0 + j * 64;
      gld_lds16(Ab + (size_t)(m0 + half * 128 + r) * K + koff + ((sc0 ^ (r & 7)) * 8),
                &As[buf][half][(tid + j * 512) * 8]);
    }
  };
  auto stageB = [&](int buf, int half, int koff) {
#pragma unroll
    for (int j = 0; j < 2; ++j) {
      const int r = sr0 + j * 64;
      gld_lds16(Bb + (size_t)(n0 + half * 128 + r) * K + koff + ((sc0 ^ (r & 7)) * 8),
                &Bs[buf][half][(tid + j * 512) * 8]);
    }
  };

  f32x4 acc[8][4] = {};

  // ---- prologue: stage tile0 + tile1; force tile0 resident ----
  stageA(0, 0, 0); stageA(0, 1, 0); stageB(0, 0, 0); stageB(0, 1, 0);
  if (NT > 1) {
    stageA(1, 0, 64); stageA(1, 1, 64); stageB(1, 0, 64); stageB(1, 1, 64);
    asm volatile("s_waitcnt vmcnt(8)" ::: "memory");
  } else {
    asm volatile("s_waitcnt vmcnt(0)" ::: "memory");
  }
  __builtin_amdgcn_sched_barrier(0);
  __builtin_amdgcn_s_barrier();

  for (int t = 0; t < NT; ++t) {
    const int cur = t & 1;
    const int kN2 = (t + 2) * 64;
    const bool pf = (t + 2) < NT;
    bf16x8 alo[4][2], ahi[4][2], ba[2][2], bb[2][2];

    // ---- reads: A-lo(8) + B-a(4) + B-b(4) ----
#pragma unroll
    for (int im = 0; im < 4; ++im)
#pragma unroll
      for (int kk = 0; kk < 2; ++kk)
        alo[im][kk] = *(const bf16x8*)(&As[cur][wr][(im * 16 + lr) * 64 + (((kk * 4 + lg) ^ swz) * 8)]);
#pragma unroll
    for (int in = 0; in < 2; ++in)
#pragma unroll
      for (int kk = 0; kk < 2; ++kk)
        ba[in][kk] = *(const bf16x8*)(&Bs[cur][bh][(brow0 + in * 16 + lr) * 64 + (((kk * 4 + lg) ^ swz) * 8)]);
#pragma unroll
    for (int in = 0; in < 2; ++in)
#pragma unroll
      for (int kk = 0; kk < 2; ++kk)
        bb[in][kk] = *(const bf16x8*)(&Bs[cur][bh][(brow0 + (2 + in) * 16 + lr) * 64 + (((kk * 4 + lg) ^ swz) * 8)]);
    asm volatile("s_waitcnt lgkmcnt(4)" ::: "memory");  // alo+ba ready; bb in flight
    __builtin_amdgcn_sched_barrier(0);

    // ---- Q1: lo x a ----
    __builtin_amdgcn_s_setprio(1);
#pragma unroll
    for (int im = 0; im < 4; ++im)
#pragma unroll
      for (int in = 0; in < 2; ++in)
#pragma unroll
        for (int kk = 0; kk < 2; ++kk)
          acc[im][in] = __builtin_amdgcn_mfma_f32_16x16x32_bf16(alo[im][kk], ba[in][kk], acc[im][in], 0, 0, 0);
    __builtin_amdgcn_s_setprio(0);
    asm volatile("s_waitcnt lgkmcnt(0)" ::: "memory");  // bb ready (drained under Q1)
    __builtin_amdgcn_sched_barrier(0);

    // ---- Q2: lo x b ----
    __builtin_amdgcn_s_setprio(1);
#pragma unroll
    for (int im = 0; im < 4; ++im)
#pragma unroll
      for (int in = 0; in < 2; ++in)
#pragma unroll
        for (int kk = 0; kk < 2; ++kk)
          acc[im][2 + in] = __builtin_amdgcn_mfma_f32_16x16x32_bf16(alo[im][kk], bb[in][kk], acc[im][2 + in], 0, 0, 0);
    __builtin_amdgcn_s_setprio(0);
    __builtin_amdgcn_sched_barrier(0);

    // ---- read A-hi(8) (drains under MID1 + stage issue) ----
#pragma unroll
    for (int im = 0; im < 4; ++im)
#pragma unroll
      for (int kk = 0; kk < 2; ++kk)
        ahi[im][kk] = *(const bf16x8*)(&As[cur][wr][((4 + im) * 16 + lr) * 64 + (((kk * 4 + lg) ^ swz) * 8)]);

    // ---- MID1: all waves consumed B[cur] (ba: lgkm(4) pre-Q1; bb: lgkm(0) pre-Q2) ----
    __builtin_amdgcn_s_barrier();
    if (pf) { stageB(cur, 0, kN2); stageB(cur, 1, kN2); }
    asm volatile("s_waitcnt lgkmcnt(0)" ::: "memory");  // ahi ready
    __builtin_amdgcn_sched_barrier(0);

    // ---- Q3: hi x b ----
    __builtin_amdgcn_s_setprio(1);
#pragma unroll
    for (int im = 0; im < 4; ++im)
#pragma unroll
      for (int in = 0; in < 2; ++in)
#pragma unroll
        for (int kk = 0; kk < 2; ++kk)
          acc[4 + im][2 + in] = __builtin_amdgcn_mfma_f32_16x16x32_bf16(ahi[im][kk], bb[in][kk], acc[4 + im][2 + in], 0, 0, 0);
    __builtin_amdgcn_s_setprio(0);
    __builtin_amdgcn_sched_barrier(0);

    // ---- MID2: all waves consumed A[cur] (alo: lgkm(4) pre-Q1; ahi: lgkm(0) pre-Q3) ----
    __builtin_amdgcn_s_barrier();
    if (pf) { stageA(cur, 0, kN2); stageA(cur, 1, kN2); }

    // ---- Q4: hi x a (frags held in regs; no LDS reads) ----
    __builtin_amdgcn_s_setprio(1);
#pragma unroll
    for (int im = 0; im < 4; ++im)
#pragma unroll
      for (int in = 0; in < 2; ++in)
#pragma unroll
        for (int kk = 0; kk < 2; ++kk)
          acc[4 + im][in] = __builtin_amdgcn_mfma_f32_16x16x32_bf16(ahi[im][kk], ba[in][kk], acc[4 + im][in], 0, 0, 0);
    __builtin_amdgcn_s_setprio(0);
    __builtin_amdgcn_sched_barrier(0);
    if (pf) {
      asm volatile("s_waitcnt vmcnt(8)" ::: "memory");  // force t+1, keep t+2 in flight
    } else {
      asm volatile("s_waitcnt vmcnt(0)" ::: "memory");  // tail
    }
    __builtin_amdgcn_sched_barrier(0);
    __builtin_amdgcn_s_barrier();  // tile-end
  }

  // ---- epilogue ----
  float* dst = out0;
  if (MODE == 1) {
    int z = blockIdx.z;
    dst = (z == 0) ? out0 : (z == 1) ? out1 : (z == 2) ? out2 : out3;
  }
#pragma unroll
  for (int mf = 0; mf < 8; ++mf) {
    const int row = m0 + wr * 128 + mf * 16 + lg * 4;
#pragma unroll
    for (int nf = 0; nf < 4; ++nf) {
      const int col = n0 + wc * 64 + nf * 16 + lr;
#pragma unroll
      for (int r = 0; r < 4; ++r) {
        float v = acc[mf][nf][r];
        int rr = row + r;
        if (MODE == 0) {
          if (col < 2048) {
            out0[(size_t)rr * 2048 + col] = v;
          } else if (col < 4096) {
            int c = col - 2048;
            out1[(size_t)(c >> 7) * (TT * DD) + (size_t)rr * DD + (c & 127)] = v;
          } else {
            int c = col - 4096;
            out2[(size_t)(c >> 7) * (TT * DD) + (size_t)rr * DD + (c & 127)] = v;
          }
        } else {
          dst[(size_t)rr * N + col] = v;
        }
      }
    }
  }
}

// ---------------- RoPE + scale, pack q/k as bf16 [h][t][d] ----------------
__global__ __launch_bounds__(256) void k_rope(
    const float* __restrict__ Qf, const float* __restrict__ Kraw,
    const float* __restrict__ sqk,
    unsigned short* __restrict__ qb, unsigned short* __restrict__ kb) {
  const int t = blockIdx.x;
  for (int i = threadIdx.x; i < HH * 64; i += 256) {
    int h = i >> 6, dp = i & 63;
    float theta = expf(-(float)dp * 0.14391156831212787f);
    float ang = (float)t * theta;
    float sn, cs;
    sincosf(ang, &sn, &cs);
    float qr = Qf[(size_t)t * CC + h * DD + dp];
    float qi = Qf[(size_t)t * CC + h * DD + dp + 64];
    const float* kp = Kraw + (size_t)h * TT * DD + (size_t)t * DD;
    float kr = kp[dp], ki = kp[dp + 64];
    float sr = sqk[h * DD + dp];
    float si = sqk[h * DD + dp + 64];
    float qsr = sr * 512.0f, qsi = si * 512.0f;                         // sqrt(C)*sqrt(D)
    float ksr = sr * 45.25483399593904f, ksi = si * 45.25483399593904f; // sqrt(C)
    unsigned short* qo = qb + ((size_t)h * TT + t) * DD;
    unsigned short* ko = kb + ((size_t)h * TT + t) * DD;
    qo[dp]      = f2bf((qr * cs - qi * sn) * qsr);
    qo[dp + 64] = f2bf((qr * sn + qi * cs) * qsi);
    ko[dp]      = f2bf((kr * cs - ki * sn) * ksr);
    ko[dp + 64] = f2bf((kr * sn + ki * cs) * ksi);
  }
}

// ---------------- V transpose: new_v f32 [h][t][d] -> vt bf16 [h][d][t] ----------------
__global__ __launch_bounds__(256) void k_vt(
    const float* __restrict__ Vraw, unsigned short* __restrict__ vt) {
  const int h = blockIdx.z;
  const int t0 = blockIdx.x * 64, d0 = blockIdx.y * 64;
  __shared__ unsigned short tile[64][65];
  const float* vp = Vraw + (size_t)h * TT * DD;
  for (int i = threadIdx.x; i < 4096; i += 256) {
    int r = i >> 6, c = i & 63;
    tile[r][c] = f2bf(vp[(size_t)(t0 + r) * DD + d0 + c]);
  }
  __syncthreads();
  unsigned short* op = vt + (size_t)h * DD * TT;
  for (int i = threadIdx.x; i < 4096; i += 256) {
    int dr = i >> 6, tc = i & 63;
    op[(size_t)(d0 + dr) * TT + t0 + tc] = tile[tc][dr];
  }
}

// ---------------- causal flash attention, 8-wave LDS-staged, split-K ----------------
__global__ __launch_bounds__(512) void k_attn_split(
    const unsigned short* __restrict__ qb, const unsigned short* __restrict__ kb,
    const unsigned short* __restrict__ vt,
    unsigned short* __restrict__ po, float* __restrict__ marr, float* __restrict__ larr) {
  const int qt = blockIdx.x, h = blockIdx.y, s = blockIdx.z;
  if (4 * s > qt) return;
  const int slot = h * 40 + soff(qt) + s;
  const int kbeg = 512 * s;
  const int kend = min(kbeg + 512, 128 * qt + 128);
  const int ntiles = (kend - kbeg) >> 6;
  const int tid = threadIdx.x;
  const int wid = tid >> 6, lane = tid & 63;
  const int lr = lane & 15, lg = lane >> 4;
  const int q0 = qt * 128 + wid * 16;

  __shared__ alignas(16) unsigned short Ks[64 * 128];
  __shared__ alignas(16) unsigned short Vs[128 * 64];
  __shared__ alignas(16) unsigned short P[8][16][72];

  const unsigned short* qh = qb + (size_t)h * TT * DD;
  const unsigned short* kh = kb + (size_t)h * TT * DD;
  const unsigned short* vh = vt + (size_t)h * DD * TT;

  bf16x8 qf[4];
#pragma unroll
  for (int c = 0; c < 4; ++c)
    qf[c] = *(const bf16x8*)(qh + (size_t)(q0 + lr) * DD + c * 32 + lg * 8);

  f32x4 acc[8] = {};
  float mrow[4] = {-3e38f, -3e38f, -3e38f, -3e38f};
  float lsum[4] = {0.f, 0.f, 0.f, 0.f};

  for (int kt = 0; kt < ntiles; ++kt) {
    const int k0 = kbeg + kt * 64;
#pragma unroll
    for (int half = 0; half < 2; ++half) {
      int ch = tid + half * 512;
      int r = ch >> 4, c4 = ch & 15;
      gld_lds16(kh + (size_t)(k0 + r) * DD + ((c4 ^ (r & 7)) * 8), Ks + ch * 8);
    }
#pragma unroll
    for (int half = 0; half < 2; ++half) {
      int ch = tid + half * 512;
      int d = ch >> 3, c8 = ch & 7;
      gld_lds16(vh + (size_t)d * TT + k0 + ((c8 ^ (d & 7)) * 8), Vs + ch * 8);
    }
    __syncthreads();

    if (k0 <= q0 + 15) {
      f32x4 sv[4] = {};
#pragma unroll
      for (int ktile = 0; ktile < 4; ++ktile) {
        const int row = ktile * 16 + lr;
#pragma unroll
        for (int c = 0; c < 4; ++c) {
          int chn = (c * 4 + lg) ^ (lr & 7);
          bf16x8 kf = *(const bf16x8*)(Ks + row * 128 + chn * 8);
          sv[ktile] = __builtin_amdgcn_mfma_f32_16x16x32_bf16(qf[c], kf, sv[ktile], 0, 0, 0);
        }
      }
      if (k0 + 63 > q0) {
#pragma unroll
        for (int ktile = 0; ktile < 4; ++ktile)
#pragma unroll
          for (int r = 0; r < 4; ++r) {
            int key = k0 + ktile * 16 + lr;
            int qrow = q0 + lg * 4 + r;
            if (key > qrow) sv[ktile][r] = -1e30f;
          }
      }
      float pmax[4];
#pragma unroll
      for (int r = 0; r < 4; ++r)
        pmax[r] = fmaxf(fmaxf(sv[0][r], sv[1][r]), fmaxf(sv[2][r], sv[3][r]));
#pragma unroll
      for (int msk = 1; msk <= 8; msk <<= 1)
#pragma unroll
        for (int r = 0; r < 4; ++r) pmax[r] = fmaxf(pmax[r], __shfl_xor(pmax[r], msk));
      float p[4][4], ps[4], scl[4];
#pragma unroll
      for (int r = 0; r < 4; ++r) {
        float mn = fmaxf(mrow[r], pmax[r]);
        scl[r] = __expf(mrow[r] - mn);
        mrow[r] = mn;
        ps[r] = 0.f;
#pragma unroll
        for (int ktile = 0; ktile < 4; ++ktile) {
          p[ktile][r] = __expf(sv[ktile][r] - mn);
          ps[r] += p[ktile][r];
        }
      }
#pragma unroll
      for (int msk = 1; msk <= 8; msk <<= 1)
#pragma unroll
        for (int r = 0; r < 4; ++r) ps[r] += __shfl_xor(ps[r], msk);
#pragma unroll
      for (int r = 0; r < 4; ++r) lsum[r] = lsum[r] * scl[r] + ps[r];
#pragma unroll
      for (int n = 0; n < 8; ++n)
#pragma unroll
        for (int r = 0; r < 4; ++r) acc[n][r] *= scl[r];
#pragma unroll
      for (int ktile = 0; ktile < 4; ++ktile)
#pragma unroll
        for (int r = 0; r < 4; ++r)
          P[wid][lg * 4 + r][ktile * 16 + lr] = f2bf(p[ktile][r]);
      asm volatile("s_waitcnt lgkmcnt(0)" ::: "memory");
      __builtin_amdgcn_sched_barrier(0);
      bf16x8 pf[2];
#pragma unroll
      for (int ks = 0; ks < 2; ++ks)
        pf[ks] = *(const bf16x8*)(&P[wid][lr][ks * 32 + lg * 8]);
#pragma unroll
      for (int n = 0; n < 8; ++n) {
        const int row = n * 16 + lr;
#pragma unroll
        for (int ks = 0; ks < 2; ++ks) {
          int chn = (ks * 4 + lg) ^ (lr & 7);
          bf16x8 vf = *(const bf16x8*)(Vs + row * 64 + chn * 8);
          acc[n] = __builtin_amdgcn_mfma_f32_16x16x32_bf16(pf[ks], vf, acc[n], 0, 0, 0);
        }
      }
    }
    __syncthreads();
  }

  unsigned short* pob = po + (size_t)slot * (128 * DD);
#pragma unroll
  for (int n = 0; n < 8; ++n)
#pragma unroll
    for (int r = 0; r < 4; ++r) {
      int row = wid * 16 + lg * 4 + r;
      pob[(size_t)row * DD + n * 16 + lr] = f2bf(acc[n][r]);
    }
  if (lr == 0) {
#pragma unroll
    for (int r = 0; r < 4; ++r) {
      int row = wid * 16 + lg * 4 + r;
      marr[(size_t)slot * 128 + row] = mrow[r];
      larr[(size_t)slot * 128 + row] = lsum[r];
    }
  }
}

// ---------------- split reduce ----------------
__global__ __launch_bounds__(256) void k_attn_reduce(
    const unsigned short* __restrict__ po, const float* __restrict__ marr,
    const float* __restrict__ larr, unsigned short* __restrict__ ob) {
  const int qt = blockIdx.x, h = blockIdx.y;
  const int ns = (qt >> 2) + 1;
  const int sb = h * 40 + soff(qt);
  const int tid = threadIdx.x;
  const int row = tid >> 1, d0 = (tid & 1) * 64;
  float mstar = -3e38f;
  for (int s = 0; s < ns; ++s) mstar = fmaxf(mstar, marr[(size_t)(sb + s) * 128 + row]);
  float w[4];
  float ltot = 0.f;
  for (int s = 0; s < ns; ++s) {
    w[s] = __expf(marr[(size_t)(sb + s) * 128 + row] - mstar);
    ltot += w[s] * larr[(size_t)(sb + s) * 128 + row];
  }
  float inv = 1.0f / ltot;
  float o[64] = {};
  for (int s = 0; s < ns; ++s) {
    const bf16x8* pp = (const bf16x8*)(po + (size_t)(sb + s) * (128 * DD) + (size_t)row * DD + d0);
    float ws = w[s];
#pragma unroll
    for (int j = 0; j < 8; ++j) {
      bf16x8 v = pp[j];
#pragma unroll
      for (int e = 0; e < 8; ++e) o[j * 8 + e] += ws * (float)v[e];
    }
  }
  unsigned short* op = ob + (size_t)(qt * 128 + row) * CC + h * DD + d0;
#pragma unroll
  for (int j = 0; j < 16; ++j) {
    us4 t = { f2bf(o[4 * j] * inv), f2bf(o[4 * j + 1] * inv),
              f2bf(o[4 * j + 2] * inv), f2bf(o[4 * j + 3] * inv) };
    ((us4*)op)[j] = t;
  }
}

// ---------------- row l2norm over sum of four split-K partials ----------------
__global__ __launch_bounds__(256) void k_l2norm(
    const float* __restrict__ Of0, const float* __restrict__ Of1,
    const float* __restrict__ Of2, const float* __restrict__ Of3,
    float* __restrict__ out) {
  const int t = blockIdx.x;
  const int tid = threadIdx.x;
  const float4* p0 = (const float4*)(Of0 + (size_t)t * CC);
  const float4* p1 = (const float4*)(Of1 + (size_t)t * CC);
  const float4* p2 = (const float4*)(Of2 + (size_t)t * CC);
  const float4* p3 = (const float4*)(Of3 + (size_t)t * CC);
  float4 a = p0[2 * tid], b = p0[2 * tid + 1];
  float4 a1 = p1[2 * tid], b1 = p1[2 * tid + 1];
  float4 a2 = p2[2 * tid], b2 = p2[2 * tid + 1];
  float4 a3 = p3[2 * tid], b3 = p3[2 * tid + 1];
  a.x += a1.x + a2.x + a3.x; a.y += a1.y + a2.y + a3.y;
  a.z += a1.z + a2.z + a3.z; a.w += a1.w + a2.w + a3.w;
  b.x += b1.x + b2.x + b3.x; b.y += b1.y + b2.y + b3.y;
  b.z += b1.z + b2.z + b3.z; b.w += b1.w + b2.w + b3.w;
  float ss = a.x * a.x + a.y * a.y + a.z * a.z + a.w * a.w +
             b.x * b.x + b.y * b.y + b.z * b.z + b.w * b.w;
#pragma unroll
  for (int msk = 1; msk < 64; msk <<= 1) ss += __shfl_xor(ss, msk);
  __shared__ float red[4];
  if ((tid & 63) == 0) red[tid >> 6] = ss;
  __syncthreads();
  ss = red[0] + red[1] + red[2] + red[3];
  float sc = 1.0f / fmaxf(sqrtf(ss), 1e-12f);
  float4 oa = { a.x * sc, a.y * sc, a.z * sc, a.w * sc };
  float4 obv = { b.x * sc, b.y * sc, b.z * sc, b.w * sc };
  float4* o = (float4*)(out + (size_t)t * CC);
  o[2 * tid] = oa;
  o[2 * tid + 1] = obv;
}

extern "C" void kernel_launch(void* const* d_in, const int* in_sizes, int n_in,
                              void* d_out, int out_size, void* d_ws, size_t ws_size,
                              hipStream_t stream) {
  const float* x   = (const float*)d_in[0];
  const float* wq  = (const float*)d_in[1];
  const float* wk  = (const float*)d_in[2];
  const float* wv  = (const float*)d_in[3];
  const float* wo  = (const float*)d_in[4];
  const float* sqk = (const float*)d_in[5];

  float* out_norm = (float*)d_out;
  float* out_k = out_norm + (size_t)4 * 1024 * 1024;
  float* out_v = out_norm + (size_t)8 * 1024 * 1024;

  char* ws = (char*)d_ws;
  unsigned short* xb  = (unsigned short*)(ws);                      // 0..8MB  (dead after QKV)
  unsigned short* w1b = (unsigned short*)(ws + (8u << 20));         // 8..32MB (dead after QKV)
  unsigned short* wob = (unsigned short*)(ws + (32u << 20));        // 32..40MB (dead after outproj)
  unsigned short* qb  = (unsigned short*)(ws + (40u << 20));        // 40..48MB (dead after attn)
  unsigned short* kb  = (unsigned short*)(ws + (48u << 20));        // 48..56MB (dead after attn)
  unsigned short* vtb = (unsigned short*)(ws + (56u << 20));        // 56..64MB (dead after attn)
  unsigned short* obb = (unsigned short*)(ws + (64u << 20));        // 64..72MB
  float* Qf = (float*)(ws + (72u << 20));                           // 72..88MB

  // attention split partials reuse 0..24MB (dead after QKV GEMM)
  unsigned short* po = (unsigned short*)(ws);                       // 20MB
  float* marr = (float*)(ws + (22u << 20));
  float* larr = (float*)(ws + (23u << 20));

  // out-proj split-K=4 partials (all regions dead during out-proj except obb, wob)
  float* Of0 = Qf;                       // 72..88
  float* Of1 = (float*)(ws);             // 0..16
  float* Of2 = (float*)(ws + (16u << 20));  // 16..32? overlaps wob? no: wob at 32..40 -> 16..32 OK
  float* Of3 = (float*)(ws + (40u << 20));  // 40..56 (qb,kb dead)

  const int n8 = (CC * CC) / 8;
  k_f32_to_bf16<<<n8 / 256, 256, 0, stream>>>(x,  xb, n8);
  k_f32_to_bf16<<<n8 / 256, 256, 0, stream>>>(wq, w1b, n8);
  k_f32_to_bf16<<<n8 / 256, 256, 0, stream>>>(wk, w1b + (size_t)4 * 1024 * 1024, n8);
  k_f32_to_bf16<<<n8 / 256, 256, 0, stream>>>(wv, w1b + (size_t)8 * 1024 * 1024, n8);
  k_f32_to_bf16<<<n8 / 256, 256, 0, stream>>>(wo, wob, n8);

  // fused QKV projection: 2048 x 6144 x 2048
  k_gemm256<0><<<dim3(24, 8, 1), 512, 0, stream>>>(xb, w1b, 3 * CC, CC, CC,
                                                   Qf, out_k, out_v, nullptr);

  k_rope<<<TT, 256, 0, stream>>>(Qf, out_k, sqk, qb, kb);
  k_vt<<<dim3(32, 2, 16), 256, 0, stream>>>(out_v, vtb);

  k_attn_split<<<dim3(16, 16, 4), 512, 0, stream>>>(qb, kb, vtb, po, marr, larr);
  k_attn_reduce<<<dim3(16, 16), 256, 0, stream>>>(po, marr, larr, obb);

  // output projection: 2048 x 2048 x 2048, split-K=4 (256 blocks, full machine)
  k_gemm256<1><<<dim3(8, 8, 4), 512, 0, stream>>>(obb, wob, CC, CC, CC / 4,
                                                  Of0, Of1, Of2, Of3);

  k_l2norm<<<TT, 256, 0, stream>>>(Of0, Of1, Of2, Of3, out_norm);
}

// Round 8
// 224.752 us; speedup vs baseline: 1.0468x; 1.0094x over previous
//
#include <hip/hip_runtime.h>

typedef __bf16 bf16x8 __attribute__((ext_vector_type(8)));
typedef float f32x4 __attribute__((ext_vector_type(4)));
typedef unsigned short us4 __attribute__((ext_vector_type(4)));

constexpr int TT = 2048;   // tokens
constexpr int CC = 2048;   // channels
constexpr int HH = 16;     // heads
constexpr int DD = 128;    // head dim

__device__ __forceinline__ unsigned short f2bf(float f) {
  unsigned u = __builtin_bit_cast(unsigned, f);
  u += 0x7FFFu + ((u >> 16) & 1u);
  return (unsigned short)(u >> 16);
}
__device__ __forceinline__ float bf2f(unsigned short b) {
  unsigned u = ((unsigned)b) << 16;
  return __builtin_bit_cast(float, u);
}

// async global->LDS, 16B per lane. C-style casts lower to addrspacecast.
__device__ __forceinline__ void gld_lds16(const unsigned short* g, unsigned short* l) {
  __builtin_amdgcn_global_load_lds(
      (const __attribute__((address_space(1))) unsigned int*)g,
      (__attribute__((address_space(3))) unsigned int*)l,
      16, 0, 0);
}

// split-slot table for QBLK=128, SPLIT=512 keys: ns(qt)=qt/4+1, 40 slots/head
__device__ __forceinline__ int soff(int qt) {
  int g = qt >> 2, rem = qt & 3;
  return (g + 1) * (2 * g + rem);
}

// ---------------- fused f32 -> bf16 convert (5 matrices, one launch) ----------------
__global__ __launch_bounds__(256) void k_cvt5(
    const float* __restrict__ s0, const float* __restrict__ s1,
    const float* __restrict__ s2, const float* __restrict__ s3,
    const float* __restrict__ s4,
    unsigned short* __restrict__ d0, unsigned short* __restrict__ d1,
    unsigned short* __restrict__ d2, unsigned short* __restrict__ d3,
    unsigned short* __restrict__ d4) {
  const int m = blockIdx.y;
  const float* src = (m == 0) ? s0 : (m == 1) ? s1 : (m == 2) ? s2 : (m == 3) ? s3 : s4;
  unsigned short* dst = (m == 0) ? d0 : (m == 1) ? d1 : (m == 2) ? d2 : (m == 3) ? d3 : d4;
  int i = blockIdx.x * 256 + threadIdx.x;
  const float4* s = (const float4*)src;
  float4 a = s[2 * i], b = s[2 * i + 1];
  us4 lo = { f2bf(a.x), f2bf(a.y), f2bf(a.z), f2bf(a.w) };
  us4 hi = { f2bf(b.x), f2bf(b.y), f2bf(b.z), f2bf(b.w) };
  us4* d = (us4*)dst;
  d[2 * i] = lo;
  d[2 * i + 1] = hi;
}

// ---------------- 128x128 GEMM, 4 waves, 2 blocks/CU, counted vmcnt ----------------
// C = A(MxK) * B(NxK)^T. 4 waves (2M x 2N), per-wave 64x64 output, BK=64.
// LDS: 2buf x (128x64) per matrix = 64KB -> 2 resident blocks/CU (TLP covers waits).
// Per tile: {16 ds_reads; lgkm(4)->Q1; lgkm(0)->Q2; MID barrier; stage t+2 -> cur;
// vmcnt(8)} -- one barrier/tile, stage loads covered by the next tile's compute.
// MODE 0: fused QKV epilogue; MODE 1: f32 store to (z ? out1 : out0).
template <int MODE>
__global__ __launch_bounds__(256, 2) void k_gemm128(
    const unsigned short* __restrict__ A, const unsigned short* __restrict__ B,
    int N, int K, int kspan,
    float* __restrict__ out0, float* __restrict__ out1, float* __restrict__ out2) {
  __shared__ alignas(16) unsigned short As[2][128 * 64];
  __shared__ alignas(16) unsigned short Bs[2][128 * 64];
  const int tid = threadIdx.x;
  const int m0 = blockIdx.y * 128, n0 = blockIdx.x * 128;
  const int kbeg = blockIdx.z * kspan;
  const int NT = kspan >> 6;
  const int wid = tid >> 6, lane = tid & 63;
  const int wr = wid >> 1, wc = wid & 1;
  const int lr = lane & 15, lg = lane >> 4;

  const unsigned short* Ab = A + kbeg;
  const unsigned short* Bb = B + kbeg;

  // stage one 128x64 tile: 256 threads x 4 chunks of 16B; XOR-swizzled source
  auto stageA = [&](int buf, int koff) {
#pragma unroll
    for (int j = 0; j < 4; ++j) {
      const int ch = tid + j * 256;
      const int r = ch >> 3, c8 = ch & 7;
      gld_lds16(Ab + (size_t)(m0 + r) * K + koff + ((c8 ^ (r & 7)) * 8),
                &As[buf][ch * 8]);
    }
  };
  auto stageB = [&](int buf, int koff) {
#pragma unroll
    for (int j = 0; j < 4; ++j) {
      const int ch = tid + j * 256;
      const int r = ch >> 3, c8 = ch & 7;
      gld_lds16(Bb + (size_t)(n0 + r) * K + koff + ((c8 ^ (r & 7)) * 8),
                &Bs[buf][ch * 8]);
    }
  };

  f32x4 acc[4][4] = {};

  // ---- prologue: tile0 (8 loads) + tile1 (8 loads); force tile0 resident ----
  stageA(0, 0); stageB(0, 0);
  if (NT > 1) {
    stageA(1, 64); stageB(1, 64);
    asm volatile("s_waitcnt vmcnt(8)" ::: "memory");
  } else {
    asm volatile("s_waitcnt vmcnt(0)" ::: "memory");
  }
  __builtin_amdgcn_sched_barrier(0);
  __builtin_amdgcn_s_barrier();

  for (int t = 0; t < NT; ++t) {
    const int cur = t & 1;
    bf16x8 av[4][2], b01[2][2], b23[2][2];

    // ---- issue all 16 reads (in-order DS completion: a first, then b01, b23) ----
#pragma unroll
    for (int m = 0; m < 4; ++m)
#pragma unroll
      for (int kk = 0; kk < 2; ++kk) {
        const int row = wr * 64 + m * 16 + lr;
        av[m][kk] = *(const bf16x8*)(&As[cur][row * 64 + (((kk * 4 + lg) ^ (row & 7)) * 8)]);
      }
#pragma unroll
    for (int n = 0; n < 2; ++n)
#pragma unroll
      for (int kk = 0; kk < 2; ++kk) {
        const int row = wc * 64 + n * 16 + lr;
        b01[n][kk] = *(const bf16x8*)(&Bs[cur][row * 64 + (((kk * 4 + lg) ^ (row & 7)) * 8)]);
      }
#pragma unroll
    for (int n = 0; n < 2; ++n)
#pragma unroll
      for (int kk = 0; kk < 2; ++kk) {
        const int row = wc * 64 + (2 + n) * 16 + lr;
        b23[n][kk] = *(const bf16x8*)(&Bs[cur][row * 64 + (((kk * 4 + lg) ^ (row & 7)) * 8)]);
      }
    asm volatile("s_waitcnt lgkmcnt(4)" ::: "memory");  // av + b01 ready; b23 in flight
    __builtin_amdgcn_sched_barrier(0);

    // ---- Q1: av x b01 ----
    __builtin_amdgcn_s_setprio(1);
#pragma unroll
    for (int m = 0; m < 4; ++m)
#pragma unroll
      for (int n = 0; n < 2; ++n)
#pragma unroll
        for (int kk = 0; kk < 2; ++kk)
          acc[m][n] = __builtin_amdgcn_mfma_f32_16x16x32_bf16(av[m][kk], b01[n][kk], acc[m][n], 0, 0, 0);
    __builtin_amdgcn_s_setprio(0);
    asm volatile("s_waitcnt lgkmcnt(0)" ::: "memory");  // b23 drained under Q1
    __builtin_amdgcn_sched_barrier(0);

    // ---- Q2: av x b23 ----
    __builtin_amdgcn_s_setprio(1);
#pragma unroll
    for (int m = 0; m < 4; ++m)
#pragma unroll
      for (int n = 0; n < 2; ++n)
#pragma unroll
        for (int kk = 0; kk < 2; ++kk)
          acc[m][2 + n] = __builtin_amdgcn_mfma_f32_16x16x32_bf16(av[m][kk], b23[n][kk], acc[m][2 + n], 0, 0, 0);
    __builtin_amdgcn_s_setprio(0);
    __builtin_amdgcn_sched_barrier(0);

    // ---- MID: all waves consumed buf[cur]; restage it for tile t+2 ----
    __builtin_amdgcn_s_barrier();
    if (t + 2 < NT) {
      stageA(cur, (t + 2) * 64); stageB(cur, (t + 2) * 64);
      asm volatile("s_waitcnt vmcnt(8)" ::: "memory");  // force t+1, keep t+2 in flight
      __builtin_amdgcn_sched_barrier(0);
    } else if (t + 1 < NT) {
      asm volatile("s_waitcnt vmcnt(0)" ::: "memory");  // tail: force last tile
      __builtin_amdgcn_sched_barrier(0);
    }
  }

  // ---- epilogue ----
  float* dst = (MODE == 1 && blockIdx.z) ? out1 : out0;
#pragma unroll
  for (int m = 0; m < 4; ++m) {
    const int row = m0 + wr * 64 + m * 16 + lg * 4;
#pragma unroll
    for (int n = 0; n < 4; ++n) {
      const int col = n0 + wc * 64 + n * 16 + lr;
#pragma unroll
      for (int r = 0; r < 4; ++r) {
        float v = acc[m][n][r];
        int rr = row + r;
        if (MODE == 0) {
          if (col < 2048) {
            out0[(size_t)rr * 2048 + col] = v;
          } else if (col < 4096) {
            int c = col - 2048;
            out1[(size_t)(c >> 7) * (TT * DD) + (size_t)rr * DD + (c & 127)] = v;
          } else {
            int c = col - 4096;
            out2[(size_t)(c >> 7) * (TT * DD) + (size_t)rr * DD + (c & 127)] = v;
          }
        } else {
          dst[(size_t)rr * N + col] = v;
        }
      }
    }
  }
}

// ---------------- RoPE + scale, pack q/k as bf16 [h][t][d] ----------------
__global__ __launch_bounds__(256) void k_rope(
    const float* __restrict__ Qf, const float* __restrict__ Kraw,
    const float* __restrict__ sqk,
    unsigned short* __restrict__ qb, unsigned short* __restrict__ kb) {
  const int t = blockIdx.x;
  for (int i = threadIdx.x; i < HH * 64; i += 256) {
    int h = i >> 6, dp = i & 63;
    float theta = expf(-(float)dp * 0.14391156831212787f);
    float ang = (float)t * theta;
    float sn, cs;
    sincosf(ang, &sn, &cs);
    float qr = Qf[(size_t)t * CC + h * DD + dp];
    float qi = Qf[(size_t)t * CC + h * DD + dp + 64];
    const float* kp = Kraw + (size_t)h * TT * DD + (size_t)t * DD;
    float kr = kp[dp], ki = kp[dp + 64];
    float sr = sqk[h * DD + dp];
    float si = sqk[h * DD + dp + 64];
    float qsr = sr * 512.0f, qsi = si * 512.0f;                         // sqrt(C)*sqrt(D)
    float ksr = sr * 45.25483399593904f, ksi = si * 45.25483399593904f; // sqrt(C)
    unsigned short* qo = qb + ((size_t)h * TT + t) * DD;
    unsigned short* ko = kb + ((size_t)h * TT + t) * DD;
    qo[dp]      = f2bf((qr * cs - qi * sn) * qsr);
    qo[dp + 64] = f2bf((qr * sn + qi * cs) * qsi);
    ko[dp]      = f2bf((kr * cs - ki * sn) * ksr);
    ko[dp + 64] = f2bf((kr * sn + ki * cs) * ksi);
  }
}

// ---------------- V transpose: new_v f32 [h][t][d] -> vt bf16 [h][d][t] ----------------
__global__ __launch_bounds__(256) void k_vt(
    const float* __restrict__ Vraw, unsigned short* __restrict__ vt) {
  const int h = blockIdx.z;
  const int t0 = blockIdx.x * 64, d0 = blockIdx.y * 64;
  __shared__ unsigned short tile[64][65];
  const float* vp = Vraw + (size_t)h * TT * DD;
  for (int i = threadIdx.x; i < 4096; i += 256) {
    int r = i >> 6, c = i & 63;
    tile[r][c] = f2bf(vp[(size_t)(t0 + r) * DD + d0 + c]);
  }
  __syncthreads();
  unsigned short* op = vt + (size_t)h * DD * TT;
  for (int i = threadIdx.x; i < 4096; i += 256) {
    int dr = i >> 6, tc = i & 63;
    op[(size_t)(d0 + dr) * TT + t0 + tc] = tile[tc][dr];
  }
}

// ---------------- causal flash attention, 8-wave LDS-staged, split-K ----------------
__global__ __launch_bounds__(512) void k_attn_split(
    const unsigned short* __restrict__ qb, const unsigned short* __restrict__ kb,
    const unsigned short* __restrict__ vt,
    unsigned short* __restrict__ po, float* __restrict__ marr, float* __restrict__ larr) {
  const int qt = blockIdx.x, h = blockIdx.y, s = blockIdx.z;
  if (4 * s > qt) return;
  const int slot = h * 40 + soff(qt) + s;
  const int kbeg = 512 * s;
  const int kend = min(kbeg + 512, 128 * qt + 128);
  const int ntiles = (kend - kbeg) >> 6;
  const int tid = threadIdx.x;
  const int wid = tid >> 6, lane = tid & 63;
  const int lr = lane & 15, lg = lane >> 4;
  const int q0 = qt * 128 + wid * 16;

  __shared__ alignas(16) unsigned short Ks[64 * 128];
  __shared__ alignas(16) unsigned short Vs[128 * 64];
  __shared__ alignas(16) unsigned short P[8][16][72];

  const unsigned short* qh = qb + (size_t)h * TT * DD;
  const unsigned short* kh = kb + (size_t)h * TT * DD;
  const unsigned short* vh = vt + (size_t)h * DD * TT;

  bf16x8 qf[4];
#pragma unroll
  for (int c = 0; c < 4; ++c)
    qf[c] = *(const bf16x8*)(qh + (size_t)(q0 + lr) * DD + c * 32 + lg * 8);

  f32x4 acc[8] = {};
  float mrow[4] = {-3e38f, -3e38f, -3e38f, -3e38f};
  float lsum[4] = {0.f, 0.f, 0.f, 0.f};

  for (int kt = 0; kt < ntiles; ++kt) {
    const int k0 = kbeg + kt * 64;
#pragma unroll
    for (int half = 0; half < 2; ++half) {
      int ch = tid + half * 512;
      int r = ch >> 4, c4 = ch & 15;
      gld_lds16(kh + (size_t)(k0 + r) * DD + ((c4 ^ (r & 7)) * 8), Ks + ch * 8);
    }
#pragma unroll
    for (int half = 0; half < 2; ++half) {
      int ch = tid + half * 512;
      int d = ch >> 3, c8 = ch & 7;
      gld_lds16(vh + (size_t)d * TT + k0 + ((c8 ^ (d & 7)) * 8), Vs + ch * 8);
    }
    __syncthreads();

    if (k0 <= q0 + 15) {
      f32x4 sv[4] = {};
#pragma unroll
      for (int ktile = 0; ktile < 4; ++ktile) {
        const int row = ktile * 16 + lr;
#pragma unroll
        for (int c = 0; c < 4; ++c) {
          int chn = (c * 4 + lg) ^ (lr & 7);
          bf16x8 kf = *(const bf16x8*)(Ks + row * 128 + chn * 8);
          sv[ktile] = __builtin_amdgcn_mfma_f32_16x16x32_bf16(qf[c], kf, sv[ktile], 0, 0, 0);
        }
      }
      if (k0 + 63 > q0) {
#pragma unroll
        for (int ktile = 0; ktile < 4; ++ktile)
#pragma unroll
          for (int r = 0; r < 4; ++r) {
            int key = k0 + ktile * 16 + lr;
            int qrow = q0 + lg * 4 + r;
            if (key > qrow) sv[ktile][r] = -1e30f;
          }
      }
      float pmax[4];
#pragma unroll
      for (int r = 0; r < 4; ++r)
        pmax[r] = fmaxf(fmaxf(sv[0][r], sv[1][r]), fmaxf(sv[2][r], sv[3][r]));
#pragma unroll
      for (int msk = 1; msk <= 8; msk <<= 1)
#pragma unroll
        for (int r = 0; r < 4; ++r) pmax[r] = fmaxf(pmax[r], __shfl_xor(pmax[r], msk));
      float p[4][4], ps[4], scl[4];
#pragma unroll
      for (int r = 0; r < 4; ++r) {
        float mn = fmaxf(mrow[r], pmax[r]);
        scl[r] = __expf(mrow[r] - mn);
        mrow[r] = mn;
        ps[r] = 0.f;
#pragma unroll
        for (int ktile = 0; ktile < 4; ++ktile) {
          p[ktile][r] = __expf(sv[ktile][r] - mn);
          ps[r] += p[ktile][r];
        }
      }
#pragma unroll
      for (int msk = 1; msk <= 8; msk <<= 1)
#pragma unroll
        for (int r = 0; r < 4; ++r) ps[r] += __shfl_xor(ps[r], msk);
#pragma unroll
      for (int r = 0; r < 4; ++r) lsum[r] = lsum[r] * scl[r] + ps[r];
#pragma unroll
      for (int n = 0; n < 8; ++n)
#pragma unroll
        for (int r = 0; r < 4; ++r) acc[n][r] *= scl[r];
#pragma unroll
      for (int ktile = 0; ktile < 4; ++ktile)
#pragma unroll
        for (int r = 0; r < 4; ++r)
          P[wid][lg * 4 + r][ktile * 16 + lr] = f2bf(p[ktile][r]);
      asm volatile("s_waitcnt lgkmcnt(0)" ::: "memory");
      __builtin_amdgcn_sched_barrier(0);
      bf16x8 pf[2];
#pragma unroll
      for (int ks = 0; ks < 2; ++ks)
        pf[ks] = *(const bf16x8*)(&P[wid][lr][ks * 32 + lg * 8]);
#pragma unroll
      for (int n = 0; n < 8; ++n) {
        const int row = n * 16 + lr;
#pragma unroll
        for (int ks = 0; ks < 2; ++ks) {
          int chn = (ks * 4 + lg) ^ (lr & 7);
          bf16x8 vf = *(const bf16x8*)(Vs + row * 64 + chn * 8);
          acc[n] = __builtin_amdgcn_mfma_f32_16x16x32_bf16(pf[ks], vf, acc[n], 0, 0, 0);
        }
      }
    }
    __syncthreads();
  }

  unsigned short* pob = po + (size_t)slot * (128 * DD);
#pragma unroll
  for (int n = 0; n < 8; ++n)
#pragma unroll
    for (int r = 0; r < 4; ++r) {
      int row = wid * 16 + lg * 4 + r;
      pob[(size_t)row * DD + n * 16 + lr] = f2bf(acc[n][r]);
    }
  if (lr == 0) {
#pragma unroll
    for (int r = 0; r < 4; ++r) {
      int row = wid * 16 + lg * 4 + r;
      marr[(size_t)slot * 128 + row] = mrow[r];
      larr[(size_t)slot * 128 + row] = lsum[r];
    }
  }
}

// ---------------- split reduce ----------------
__global__ __launch_bounds__(256) void k_attn_reduce(
    const unsigned short* __restrict__ po, const float* __restrict__ marr,
    const float* __restrict__ larr, unsigned short* __restrict__ ob) {
  const int qt = blockIdx.x, h = blockIdx.y;
  const int ns = (qt >> 2) + 1;
  const int sb = h * 40 + soff(qt);
  const int tid = threadIdx.x;
  const int row = tid >> 1, d0 = (tid & 1) * 64;
  float mstar = -3e38f;
  for (int s = 0; s < ns; ++s) mstar = fmaxf(mstar, marr[(size_t)(sb + s) * 128 + row]);
  float w[4];
  float ltot = 0.f;
  for (int s = 0; s < ns; ++s) {
    w[s] = __expf(marr[(size_t)(sb + s) * 128 + row] - mstar);
    ltot += w[s] * larr[(size_t)(sb + s) * 128 + row];
  }
  float inv = 1.0f / ltot;
  float o[64] = {};
  for (int s = 0; s < ns; ++s) {
    const bf16x8* pp = (const bf16x8*)(po + (size_t)(sb + s) * (128 * DD) + (size_t)row * DD + d0);
    float ws = w[s];
#pragma unroll
    for (int j = 0; j < 8; ++j) {
      bf16x8 v = pp[j];
#pragma unroll
      for (int e = 0; e < 8; ++e) o[j * 8 + e] += ws * (float)v[e];
    }
  }
  unsigned short* op = ob + (size_t)(qt * 128 + row) * CC + h * DD + d0;
#pragma unroll
  for (int j = 0; j < 16; ++j) {
    us4 t = { f2bf(o[4 * j] * inv), f2bf(o[4 * j + 1] * inv),
              f2bf(o[4 * j + 2] * inv), f2bf(o[4 * j + 3] * inv) };
    ((us4*)op)[j] = t;
  }
}

// ---------------- row l2norm over sum of two split-K partials ----------------
__global__ __launch_bounds__(256) void k_l2norm(
    const float* __restrict__ Of0, const float* __restrict__ Of1, float* __restrict__ out) {
  const int t = blockIdx.x;
  const int tid = threadIdx.x;
  const float4* p0 = (const float4*)(Of0 + (size_t)t * CC);
  const float4* p1 = (const float4*)(Of1 + (size_t)t * CC);
  float4 a = p0[2 * tid], b = p0[2 * tid + 1];
  float4 a1 = p1[2 * tid], b1 = p1[2 * tid + 1];
  a.x += a1.x; a.y += a1.y; a.z += a1.z; a.w += a1.w;
  b.x += b1.x; b.y += b1.y; b.z += b1.z; b.w += b1.w;
  float ss = a.x * a.x + a.y * a.y + a.z * a.z + a.w * a.w +
             b.x * b.x + b.y * b.y + b.z * b.z + b.w * b.w;
#pragma unroll
  for (int msk = 1; msk < 64; msk <<= 1) ss += __shfl_xor(ss, msk);
  __shared__ float red[4];
  if ((tid & 63) == 0) red[tid >> 6] = ss;
  __syncthreads();
  ss = red[0] + red[1] + red[2] + red[3];
  float sc = 1.0f / fmaxf(sqrtf(ss), 1e-12f);
  float4 oa = { a.x * sc, a.y * sc, a.z * sc, a.w * sc };
  float4 obv = { b.x * sc, b.y * sc, b.z * sc, b.w * sc };
  float4* o = (float4*)(out + (size_t)t * CC);
  o[2 * tid] = oa;
  o[2 * tid + 1] = obv;
}

extern "C" void kernel_launch(void* const* d_in, const int* in_sizes, int n_in,
                              void* d_out, int out_size, void* d_ws, size_t ws_size,
                              hipStream_t stream) {
  const float* x   = (const float*)d_in[0];
  const float* wq  = (const float*)d_in[1];
  const float* wk  = (const float*)d_in[2];
  const float* wv  = (const float*)d_in[3];
  const float* wo  = (const float*)d_in[4];
  const float* sqk = (const float*)d_in[5];

  float* out_norm = (float*)d_out;
  float* out_k = out_norm + (size_t)4 * 1024 * 1024;
  float* out_v = out_norm + (size_t)8 * 1024 * 1024;

  char* ws = (char*)d_ws;
  unsigned short* xb  = (unsigned short*)(ws);                      // 0..8MB  (dead after QKV)
  unsigned short* w1b = (unsigned short*)(ws + (8u << 20));         // 8..32MB (dead after QKV)
  unsigned short* wob = (unsigned short*)(ws + (32u << 20));        // 32..40MB
  unsigned short* qb  = (unsigned short*)(ws + (40u << 20));        // 40..48MB (dead after attn)
  unsigned short* kb  = (unsigned short*)(ws + (48u << 20));        // 48..56MB
  unsigned short* vtb = (unsigned short*)(ws + (56u << 20));        // 56..64MB
  unsigned short* obb = (unsigned short*)(ws + (64u << 20));        // 64..72MB
  float* Qf = (float*)(ws + (72u << 20));                           // 72..88MB

  // attention split partials reuse 0..24MB (dead after QKV GEMM)
  unsigned short* po = (unsigned short*)(ws);                       // 20MB
  float* marr = (float*)(ws + (22u << 20));
  float* larr = (float*)(ws + (23u << 20));

  // out-proj split-K=2 partials: Of0 reuses Qf (dead after rope), Of1 reuses 40..56 (qb/kb dead)
  float* Of0 = Qf;
  float* Of1 = (float*)(ws + (40u << 20));

  // fused converts: one launch, 5 matrices
  k_cvt5<<<dim3(2048, 5), 256, 0, stream>>>(
      x, wq, wk, wv, wo,
      xb, w1b, w1b + (size_t)4 * 1024 * 1024, w1b + (size_t)8 * 1024 * 1024, wob);

  // fused QKV projection: 2048 x 6144 x 2048 (768 blocks = 3/CU, 2 resident)
  k_gemm128<0><<<dim3(48, 16, 1), 256, 0, stream>>>(xb, w1b, 3 * CC, CC, CC,
                                                    Qf, out_k, out_v);

  k_rope<<<TT, 256, 0, stream>>>(Qf, out_k, sqk, qb, kb);
  k_vt<<<dim3(32, 2, 16), 256, 0, stream>>>(out_v, vtb);

  k_attn_split<<<dim3(16, 16, 4), 512, 0, stream>>>(qb, kb, vtb, po, marr, larr);
  k_attn_reduce<<<dim3(16, 16), 256, 0, stream>>>(po, marr, larr, obb);

  // output projection: 2048 x 2048 x 2048, split-K=2 (512 blocks = 2/CU)
  k_gemm128<1><<<dim3(16, 16, 2), 256, 0, stream>>>(obb, wob, CC, CC, CC / 2,
                                                    Of0, Of1, nullptr);

  k_l2norm<<<TT, 256, 0, stream>>>(Of0, Of1, out_norm);
}

// Round 9
// 223.422 us; speedup vs baseline: 1.0530x; 1.0060x over previous
//
#include <hip/hip_runtime.h>

typedef __bf16 bf16x8 __attribute__((ext_vector_type(8)));
typedef float f32x4 __attribute__((ext_vector_type(4)));
typedef unsigned short us4 __attribute__((ext_vector_type(4)));

constexpr int TT = 2048;   // tokens
constexpr int CC = 2048;   // channels
constexpr int HH = 16;     // heads
constexpr int DD = 128;    // head dim

__device__ __forceinline__ unsigned short f2bf(float f) {
  unsigned u = __builtin_bit_cast(unsigned, f);
  u += 0x7FFFu + ((u >> 16) & 1u);
  return (unsigned short)(u >> 16);
}
__device__ __forceinline__ float bf2f(unsigned short b) {
  unsigned u = ((unsigned)b) << 16;
  return __builtin_bit_cast(float, u);
}

// async global->LDS, 16B per lane. C-style casts lower to addrspacecast.
__device__ __forceinline__ void gld_lds16(const unsigned short* g, unsigned short* l) {
  __builtin_amdgcn_global_load_lds(
      (const __attribute__((address_space(1))) unsigned int*)g,
      (__attribute__((address_space(3))) unsigned int*)l,
      16, 0, 0);
}

// split-slot table for QBLK=128, SPLIT=512 keys: ns(qt)=qt/4+1, 40 slots/head
__device__ __forceinline__ int soff(int qt) {
  int g = qt >> 2, rem = qt & 3;
  return (g + 1) * (2 * g + rem);
}

// ---------------- fused f32 -> bf16 convert (5 matrices, one launch) ----------------
__global__ __launch_bounds__(256) void k_cvt5(
    const float* __restrict__ s0, const float* __restrict__ s1,
    const float* __restrict__ s2, const float* __restrict__ s3,
    const float* __restrict__ s4,
    unsigned short* __restrict__ d0, unsigned short* __restrict__ d1,
    unsigned short* __restrict__ d2, unsigned short* __restrict__ d3,
    unsigned short* __restrict__ d4) {
  const int m = blockIdx.y;
  const float* src = (m == 0) ? s0 : (m == 1) ? s1 : (m == 2) ? s2 : (m == 3) ? s3 : s4;
  unsigned short* dst = (m == 0) ? d0 : (m == 1) ? d1 : (m == 2) ? d2 : (m == 3) ? d3 : d4;
  int i = blockIdx.x * 256 + threadIdx.x;
  const float4* s = (const float4*)src;
  float4 a = s[2 * i], b = s[2 * i + 1];
  us4 lo = { f2bf(a.x), f2bf(a.y), f2bf(a.z), f2bf(a.w) };
  us4 hi = { f2bf(b.x), f2bf(b.y), f2bf(b.z), f2bf(b.w) };
  us4* d = (us4*)dst;
  d[2 * i] = lo;
  d[2 * i + 1] = hi;
}

// ---------------- 256x256 GEMM, faithful 8-phase + counted vmcnt (T3+T4+T5+T2) ----
// C = A(MxK) * B(NxK)^T. 512 threads = 8 waves (2M x 4N), per-wave 128x64 out.
// 2 K-tiles (BK=64 each) per loop iteration; dbuf0 holds even tiles, dbuf1 odd.
// Per phase: {ds-read subtile; stage 1 half-tile (2 gld_lds); barrier; lgkm(0);
// setprio(1); 16 MFMA; setprio(0); barrier}. vmcnt(4) ONLY at end of p4/p8:
//   p4 forces tile 2t+1 (read from p5), leaves (2t+2).B0,B1 in flight;
//   p8 forces tile 2t+2 (read next p1), leaves (2t+3).B0,B1 in flight.
// Stage slots: p1,p2=(2t+1).A0/A1->d1; p3,p4=(2t+2).B0/B1->d0;
//              p5,p6=(2t+2).A0/A1->d0; p7,p8=(2t+3).B0/B1->d1.
template <int MODE>
__global__ __launch_bounds__(512, 2) void k_gemm8p(
    const unsigned short* __restrict__ A, const unsigned short* __restrict__ B,
    int N, int K, int kspan,
    float* __restrict__ out0, float* __restrict__ out1,
    float* __restrict__ out2, float* __restrict__ out3) {
  __shared__ alignas(16) unsigned short As[2][2][128 * 64];
  __shared__ alignas(16) unsigned short Bs[2][2][128 * 64];
  const int tid = threadIdx.x;
  const int m0 = blockIdx.y * 256, n0 = blockIdx.x * 256;
  const int kbeg = blockIdx.z * kspan;
  const int NT = kspan >> 6, NT2 = NT >> 1;
  const int wid = tid >> 6, lane = tid & 63;
  const int wr = wid >> 2, wc = wid & 3;
  const int lr = lane & 15, lg = lane >> 4;
  const int bh = wc >> 1, brow0 = (wc & 1) * 64;

  const int sr0 = tid >> 3, sc0 = tid & 7;
  const unsigned short* Ab = A + kbeg;
  const unsigned short* Bb = B + kbeg;

  auto stageA = [&](int buf, int half, int tile) {
    const int koff = tile * 64;
#pragma unroll
    for (int j = 0; j < 2; ++j) {
      const int r = sr0 + j * 64;
      gld_lds16(Ab + (size_t)(m0 + half * 128 + r) * K + koff + ((sc0 ^ (r & 7)) * 8),
                &As[buf][half][(tid + j * 512) * 8]);
    }
  };
  auto stageB = [&](int buf, int half, int tile) {
    const int koff = tile * 64;
#pragma unroll
    for (int j = 0; j < 2; ++j) {
      const int r = sr0 + j * 64;
      gld_lds16(Bb + (size_t)(n0 + half * 128 + r) * K + koff + ((sc0 ^ (r & 7)) * 8),
                &Bs[buf][half][(tid + j * 512) * 8]);
    }
  };

  f32x4 acc[8][4] = {};
  bf16x8 alo[4][2], ahi[4][2], ba[2][2], bb[2][2];

  auto rdAlo = [&](int d) {
#pragma unroll
    for (int im = 0; im < 4; ++im)
#pragma unroll
      for (int kk = 0; kk < 2; ++kk) {
        const int row = im * 16 + lr;
        alo[im][kk] = *(const bf16x8*)(&As[d][wr][row * 64 + (((kk * 4 + lg) ^ (row & 7)) * 8)]);
      }
  };
  auto rdAhi = [&](int d) {
#pragma unroll
    for (int im = 0; im < 4; ++im)
#pragma unroll
      for (int kk = 0; kk < 2; ++kk) {
        const int row = (4 + im) * 16 + lr;
        ahi[im][kk] = *(const bf16x8*)(&As[d][wr][row * 64 + (((kk * 4 + lg) ^ (row & 7)) * 8)]);
      }
  };
  auto rdBa = [&](int d) {
#pragma unroll
    for (int in = 0; in < 2; ++in)
#pragma unroll
      for (int kk = 0; kk < 2; ++kk) {
        const int row = brow0 + in * 16 + lr;
        ba[in][kk] = *(const bf16x8*)(&Bs[d][bh][row * 64 + (((kk * 4 + lg) ^ (row & 7)) * 8)]);
      }
  };
  auto rdBb = [&](int d) {
#pragma unroll
    for (int in = 0; in < 2; ++in)
#pragma unroll
      for (int kk = 0; kk < 2; ++kk) {
        const int row = brow0 + (2 + in) * 16 + lr;
        bb[in][kk] = *(const bf16x8*)(&Bs[d][bh][row * 64 + (((kk * 4 + lg) ^ (row & 7)) * 8)]);
      }
  };

#define MFMA_Q(MB, NB, AF, BF)                                                     \
  __builtin_amdgcn_s_setprio(1);                                                   \
  _Pragma("unroll") for (int im = 0; im < 4; ++im)                                 \
      _Pragma("unroll") for (int in = 0; in < 2; ++in)                             \
          _Pragma("unroll") for (int kk = 0; kk < 2; ++kk)                         \
              acc[MB + im][NB + in] = __builtin_amdgcn_mfma_f32_16x16x32_bf16(     \
                  AF[im][kk], BF[in][kk], acc[MB + im][NB + in], 0, 0, 0);         \
  __builtin_amdgcn_s_setprio(0);

#define WAIT_LGKM0                                      \
  asm volatile("s_waitcnt lgkmcnt(0)" ::: "memory");    \
  __builtin_amdgcn_sched_barrier(0);
#define BAR __builtin_amdgcn_s_barrier();

  // ---- prologue: tile0 fully + tile1.{B0,B1}; vmcnt(4) forces tile0 ----
  stageB(0, 0, 0); stageB(0, 1, 0); stageA(0, 0, 0); stageA(0, 1, 0);
  if (NT > 1) { stageB(1, 0, 1); stageB(1, 1, 1); }
  asm volatile("s_waitcnt vmcnt(4)" ::: "memory");
  __builtin_amdgcn_sched_barrier(0);
  BAR

  for (int t = 0; t < NT2; ++t) {
    const int t1 = 2 * t + 1, t2 = 2 * t + 2, t3 = 2 * t + 3;
    const bool s2 = t2 < NT, s3 = t3 < NT;

    // ===== phase 1: read d0.Alo + d0.Ba ; stage t1.A0 -> d1 =====
    rdAlo(0); rdBa(0);
    stageA(1, 0, t1);
    BAR WAIT_LGKM0
    MFMA_Q(0, 0, alo, ba)
    BAR

    // ===== phase 2: read d0.Bb ; stage t1.A1 -> d1 =====
    rdBb(0);
    stageA(1, 1, t1);
    BAR WAIT_LGKM0
    MFMA_Q(0, 2, alo, bb)
    BAR

    // ===== phase 3: read d0.Ahi ; stage t2.B0 -> d0 =====
    rdAhi(0);
    if (s2) stageB(0, 0, t2);
    BAR WAIT_LGKM0
    MFMA_Q(4, 2, ahi, bb)
    BAR

    // ===== phase 4: stage t2.B1 -> d0 ; Q4 ; vmcnt forces t1 =====
    if (s2) stageB(0, 1, t2);
    MFMA_Q(4, 0, ahi, ba)
    if (s2) { asm volatile("s_waitcnt vmcnt(4)" ::: "memory"); }
    else    { asm volatile("s_waitcnt vmcnt(0)" ::: "memory"); }
    __builtin_amdgcn_sched_barrier(0);
    BAR

    // ===== phase 5: read d1.Alo + d1.Ba ; stage t2.A0 -> d0 =====
    rdAlo(1); rdBa(1);
    if (s2) stageA(0, 0, t2);
    BAR WAIT_LGKM0
    MFMA_Q(0, 0, alo, ba)
    BAR

    // ===== phase 6: read d1.Bb ; stage t2.A1 -> d0 =====
    rdBb(1);
    if (s2) stageA(0, 1, t2);
    BAR WAIT_LGKM0
    MFMA_Q(0, 2, alo, bb)
    BAR

    // ===== phase 7: read d1.Ahi ; stage t3.B0 -> d1 =====
    rdAhi(1);
    if (s3) stageB(1, 0, t3);
    BAR WAIT_LGKM0
    MFMA_Q(4, 2, ahi, bb)
    BAR

    // ===== phase 8: stage t3.B1 -> d1 ; Q4' ; vmcnt forces t2 =====
    if (s3) stageB(1, 1, t3);
    MFMA_Q(4, 0, ahi, ba)
    if (s3) { asm volatile("s_waitcnt vmcnt(4)" ::: "memory"); }
    else    { asm volatile("s_waitcnt vmcnt(0)" ::: "memory"); }
    __builtin_amdgcn_sched_barrier(0);
    BAR
  }
#undef MFMA_Q
#undef WAIT_LGKM0
#undef BAR

  // ---- epilogue ----
  float* dst = out0;
  if (MODE == 1) {
    int z = blockIdx.z;
    dst = (z == 0) ? out0 : (z == 1) ? out1 : (z == 2) ? out2 : out3;
  }
#pragma unroll
  for (int mf = 0; mf < 8; ++mf) {
    const int row = m0 + wr * 128 + mf * 16 + lg * 4;
#pragma unroll
    for (int nf = 0; nf < 4; ++nf) {
      const int col = n0 + wc * 64 + nf * 16 + lr;
#pragma unroll
      for (int r = 0; r < 4; ++r) {
        float v = acc[mf][nf][r];
        int rr = row + r;
        if (MODE == 0) {
          if (col < 2048) {
            out0[(size_t)rr * 2048 + col] = v;
          } else if (col < 4096) {
            int c = col - 2048;
            out1[(size_t)(c >> 7) * (TT * DD) + (size_t)rr * DD + (c & 127)] = v;
          } else {
            int c = col - 4096;
            out2[(size_t)(c >> 7) * (TT * DD) + (size_t)rr * DD + (c & 127)] = v;
          }
        } else {
          dst[(size_t)rr * N + col] = v;
        }
      }
    }
  }
}

// ---------------- RoPE + scale, pack q/k as bf16 [h][t][d] ----------------
__global__ __launch_bounds__(256) void k_rope(
    const float* __restrict__ Qf, const float* __restrict__ Kraw,
    const float* __restrict__ sqk,
    unsigned short* __restrict__ qb, unsigned short* __restrict__ kb) {
  const int t = blockIdx.x;
  for (int i = threadIdx.x; i < HH * 64; i += 256) {
    int h = i >> 6, dp = i & 63;
    float theta = expf(-(float)dp * 0.14391156831212787f);
    float ang = (float)t * theta;
    float sn, cs;
    sincosf(ang, &sn, &cs);
    float qr = Qf[(size_t)t * CC + h * DD + dp];
    float qi = Qf[(size_t)t * CC + h * DD + dp + 64];
    const float* kp = Kraw + (size_t)h * TT * DD + (size_t)t * DD;
    float kr = kp[dp], ki = kp[dp + 64];
    float sr = sqk[h * DD + dp];
    float si = sqk[h * DD + dp + 64];
    float qsr = sr * 512.0f, qsi = si * 512.0f;                         // sqrt(C)*sqrt(D)
    float ksr = sr * 45.25483399593904f, ksi = si * 45.25483399593904f; // sqrt(C)
    unsigned short* qo = qb + ((size_t)h * TT + t) * DD;
    unsigned short* ko = kb + ((size_t)h * TT + t) * DD;
    qo[dp]      = f2bf((qr * cs - qi * sn) * qsr);
    qo[dp + 64] = f2bf((qr * sn + qi * cs) * qsi);
    ko[dp]      = f2bf((kr * cs - ki * sn) * ksr);
    ko[dp + 64] = f2bf((kr * sn + ki * cs) * ksi);
  }
}

// ---------------- V transpose: new_v f32 [h][t][d] -> vt bf16 [h][d][t] ----------------
__global__ __launch_bounds__(256) void k_vt(
    const float* __restrict__ Vraw, unsigned short* __restrict__ vt) {
  const int h = blockIdx.z;
  const int t0 = blockIdx.x * 64, d0 = blockIdx.y * 64;
  __shared__ unsigned short tile[64][65];
  const float* vp = Vraw + (size_t)h * TT * DD;
  for (int i = threadIdx.x; i < 4096; i += 256) {
    int r = i >> 6, c = i & 63;
    tile[r][c] = f2bf(vp[(size_t)(t0 + r) * DD + d0 + c]);
  }
  __syncthreads();
  unsigned short* op = vt + (size_t)h * DD * TT;
  for (int i = threadIdx.x; i < 4096; i += 256) {
    int dr = i >> 6, tc = i & 63;
    op[(size_t)(d0 + dr) * TT + t0 + tc] = tile[tc][dr];
  }
}

// ---------------- causal flash attention, 8-wave LDS-staged, split-K ----------------
__global__ __launch_bounds__(512) void k_attn_split(
    const unsigned short* __restrict__ qb, const unsigned short* __restrict__ kb,
    const unsigned short* __restrict__ vt,
    unsigned short* __restrict__ po, float* __restrict__ marr, float* __restrict__ larr) {
  const int qt = blockIdx.x, h = blockIdx.y, s = blockIdx.z;
  if (4 * s > qt) return;
  const int slot = h * 40 + soff(qt) + s;
  const int kbeg = 512 * s;
  const int kend = min(kbeg + 512, 128 * qt + 128);
  const int ntiles = (kend - kbeg) >> 6;
  const int tid = threadIdx.x;
  const int wid = tid >> 6, lane = tid & 63;
  const int lr = lane & 15, lg = lane >> 4;
  const int q0 = qt * 128 + wid * 16;

  __shared__ alignas(16) unsigned short Ks[64 * 128];
  __shared__ alignas(16) unsigned short Vs[128 * 64];
  __shared__ alignas(16) unsigned short P[8][16][72];

  const unsigned short* qh = qb + (size_t)h * TT * DD;
  const unsigned short* kh = kb + (size_t)h * TT * DD;
  const unsigned short* vh = vt + (size_t)h * DD * TT;

  bf16x8 qf[4];
#pragma unroll
  for (int c = 0; c < 4; ++c)
    qf[c] = *(const bf16x8*)(qh + (size_t)(q0 + lr) * DD + c * 32 + lg * 8);

  f32x4 acc[8] = {};
  float mrow[4] = {-3e38f, -3e38f, -3e38f, -3e38f};
  float lsum[4] = {0.f, 0.f, 0.f, 0.f};

  for (int kt = 0; kt < ntiles; ++kt) {
    const int k0 = kbeg + kt * 64;
#pragma unroll
    for (int half = 0; half < 2; ++half) {
      int ch = tid + half * 512;
      int r = ch >> 4, c4 = ch & 15;
      gld_lds16(kh + (size_t)(k0 + r) * DD + ((c4 ^ (r & 7)) * 8), Ks + ch * 8);
    }
#pragma unroll
    for (int half = 0; half < 2; ++half) {
      int ch = tid + half * 512;
      int d = ch >> 3, c8 = ch & 7;
      gld_lds16(vh + (size_t)d * TT + k0 + ((c8 ^ (d & 7)) * 8), Vs + ch * 8);
    }
    __syncthreads();

    if (k0 <= q0 + 15) {
      f32x4 sv[4] = {};
#pragma unroll
      for (int ktile = 0; ktile < 4; ++ktile) {
        const int row = ktile * 16 + lr;
#pragma unroll
        for (int c = 0; c < 4; ++c) {
          int chn = (c * 4 + lg) ^ (lr & 7);
          bf16x8 kf = *(const bf16x8*)(Ks + row * 128 + chn * 8);
          sv[ktile] = __builtin_amdgcn_mfma_f32_16x16x32_bf16(qf[c], kf, sv[ktile], 0, 0, 0);
        }
      }
      if (k0 + 63 > q0) {
#pragma unroll
        for (int ktile = 0; ktile < 4; ++ktile)
#pragma unroll
          for (int r = 0; r < 4; ++r) {
            int key = k0 + ktile * 16 + lr;
            int qrow = q0 + lg * 4 + r;
            if (key > qrow) sv[ktile][r] = -1e30f;
          }
      }
      float pmax[4];
#pragma unroll
      for (int r = 0; r < 4; ++r)
        pmax[r] = fmaxf(fmaxf(sv[0][r], sv[1][r]), fmaxf(sv[2][r], sv[3][r]));
#pragma unroll
      for (int msk = 1; msk <= 8; msk <<= 1)
#pragma unroll
        for (int r = 0; r < 4; ++r) pmax[r] = fmaxf(pmax[r], __shfl_xor(pmax[r], msk));
      float p[4][4], ps[4], scl[4];
#pragma unroll
      for (int r = 0; r < 4; ++r) {
        float mn = fmaxf(mrow[r], pmax[r]);
        scl[r] = __expf(mrow[r] - mn);
        mrow[r] = mn;
        ps[r] = 0.f;
#pragma unroll
        for (int ktile = 0; ktile < 4; ++ktile) {
          p[ktile][r] = __expf(sv[ktile][r] - mn);
          ps[r] += p[ktile][r];
        }
      }
#pragma unroll
      for (int msk = 1; msk <= 8; msk <<= 1)
#pragma unroll
        for (int r = 0; r < 4; ++r) ps[r] += __shfl_xor(ps[r], msk);
#pragma unroll
      for (int r = 0; r < 4; ++r) lsum[r] = lsum[r] * scl[r] + ps[r];
#pragma unroll
      for (int n = 0; n < 8; ++n)
#pragma unroll
        for (int r = 0; r < 4; ++r) acc[n][r] *= scl[r];
#pragma unroll
      for (int ktile = 0; ktile < 4; ++ktile)
#pragma unroll
        for (int r = 0; r < 4; ++r)
          P[wid][lg * 4 + r][ktile * 16 + lr] = f2bf(p[ktile][r]);
      asm volatile("s_waitcnt lgkmcnt(0)" ::: "memory");
      __builtin_amdgcn_sched_barrier(0);
      bf16x8 pf[2];
#pragma unroll
      for (int ks = 0; ks < 2; ++ks)
        pf[ks] = *(const bf16x8*)(&P[wid][lr][ks * 32 + lg * 8]);
#pragma unroll
      for (int n = 0; n < 8; ++n) {
        const int row = n * 16 + lr;
#pragma unroll
        for (int ks = 0; ks < 2; ++ks) {
          int chn = (ks * 4 + lg) ^ (lr & 7);
          bf16x8 vf = *(const bf16x8*)(Vs + row * 64 + chn * 8);
          acc[n] = __builtin_amdgcn_mfma_f32_16x16x32_bf16(pf[ks], vf, acc[n], 0, 0, 0);
        }
      }
    }
    __syncthreads();
  }

  unsigned short* pob = po + (size_t)slot * (128 * DD);
#pragma unroll
  for (int n = 0; n < 8; ++n)
#pragma unroll
    for (int r = 0; r < 4; ++r) {
      int row = wid * 16 + lg * 4 + r;
      pob[(size_t)row * DD + n * 16 + lr] = f2bf(acc[n][r]);
    }
  if (lr == 0) {
#pragma unroll
    for (int r = 0; r < 4; ++r) {
      int row = wid * 16 + lg * 4 + r;
      marr[(size_t)slot * 128 + row] = mrow[r];
      larr[(size_t)slot * 128 + row] = lsum[r];
    }
  }
}

// ---------------- split reduce ----------------
__global__ __launch_bounds__(256) void k_attn_reduce(
    const unsigned short* __restrict__ po, const float* __restrict__ marr,
    const float* __restrict__ larr, unsigned short* __restrict__ ob) {
  const int qt = blockIdx.x, h = blockIdx.y;
  const int ns = (qt >> 2) + 1;
  const int sb = h * 40 + soff(qt);
  const int tid = threadIdx.x;
  const int row = tid >> 1, d0 = (tid & 1) * 64;
  float mstar = -3e38f;
  for (int s = 0; s < ns; ++s) mstar = fmaxf(mstar, marr[(size_t)(sb + s) * 128 + row]);
  float w[4];
  float ltot = 0.f;
  for (int s = 0; s < ns; ++s) {
    w[s] = __expf(marr[(size_t)(sb + s) * 128 + row] - mstar);
    ltot += w[s] * larr[(size_t)(sb + s) * 128 + row];
  }
  float inv = 1.0f / ltot;
  float o[64] = {};
  for (int s = 0; s < ns; ++s) {
    const bf16x8* pp = (const bf16x8*)(po + (size_t)(sb + s) * (128 * DD) + (size_t)row * DD + d0);
    float ws = w[s];
#pragma unroll
    for (int j = 0; j < 8; ++j) {
      bf16x8 v = pp[j];
#pragma unroll
      for (int e = 0; e < 8; ++e) o[j * 8 + e] += ws * (float)v[e];
    }
  }
  unsigned short* op = ob + (size_t)(qt * 128 + row) * CC + h * DD + d0;
#pragma unroll
  for (int j = 0; j < 16; ++j) {
    us4 t = { f2bf(o[4 * j] * inv), f2bf(o[4 * j + 1] * inv),
              f2bf(o[4 * j + 2] * inv), f2bf(o[4 * j + 3] * inv) };
    ((us4*)op)[j] = t;
  }
}

// ---------------- row l2norm over sum of four split-K partials ----------------
__global__ __launch_bounds__(256) void k_l2norm(
    const float* __restrict__ Of0, const float* __restrict__ Of1,
    const float* __restrict__ Of2, const float* __restrict__ Of3,
    float* __restrict__ out) {
  const int t = blockIdx.x;
  const int tid = threadIdx.x;
  const float4* p0 = (const float4*)(Of0 + (size_t)t * CC);
  const float4* p1 = (const float4*)(Of1 + (size_t)t * CC);
  const float4* p2 = (const float4*)(Of2 + (size_t)t * CC);
  const float4* p3 = (const float4*)(Of3 + (size_t)t * CC);
  float4 a = p0[2 * tid], b = p0[2 * tid + 1];
  float4 a1 = p1[2 * tid], b1 = p1[2 * tid + 1];
  float4 a2 = p2[2 * tid], b2 = p2[2 * tid + 1];
  float4 a3 = p3[2 * tid], b3 = p3[2 * tid + 1];
  a.x += a1.x + a2.x + a3.x; a.y += a1.y + a2.y + a3.y;
  a.z += a1.z + a2.z + a3.z; a.w += a1.w + a2.w + a3.w;
  b.x += b1.x + b2.x + b3.x; b.y += b1.y + b2.y + b3.y;
  b.z += b1.z + b2.z + b3.z; b.w += b1.w + b2.w + b3.w;
  float ss = a.x * a.x + a.y * a.y + a.z * a.z + a.w * a.w +
             b.x * b.x + b.y * b.y + b.z * b.z + b.w * b.w;
#pragma unroll
  for (int msk = 1; msk < 64; msk <<= 1) ss += __shfl_xor(ss, msk);
  __shared__ float red[4];
  if ((tid & 63) == 0) red[tid >> 6] = ss;
  __syncthreads();
  ss = red[0] + red[1] + red[2] + red[3];
  float sc = 1.0f / fmaxf(sqrtf(ss), 1e-12f);
  float4 oa = { a.x * sc, a.y * sc, a.z * sc, a.w * sc };
  float4 obv = { b.x * sc, b.y * sc, b.z * sc, b.w * sc };
  float4* o = (float4*)(out + (size_t)t * CC);
  o[2 * tid] = oa;
  o[2 * tid + 1] = obv;
}

extern "C" void kernel_launch(void* const* d_in, const int* in_sizes, int n_in,
                              void* d_out, int out_size, void* d_ws, size_t ws_size,
                              hipStream_t stream) {
  const float* x   = (const float*)d_in[0];
  const float* wq  = (const float*)d_in[1];
  const float* wk  = (const float*)d_in[2];
  const float* wv  = (const float*)d_in[3];
  const float* wo  = (const float*)d_in[4];
  const float* sqk = (const float*)d_in[5];

  float* out_norm = (float*)d_out;
  float* out_k = out_norm + (size_t)4 * 1024 * 1024;
  float* out_v = out_norm + (size_t)8 * 1024 * 1024;

  char* ws = (char*)d_ws;
  unsigned short* xb  = (unsigned short*)(ws);                      // 0..8MB  (dead after QKV)
  unsigned short* w1b = (unsigned short*)(ws + (8u << 20));         // 8..32MB (dead after QKV)
  unsigned short* wob = (unsigned short*)(ws + (32u << 20));        // 32..40MB
  unsigned short* qb  = (unsigned short*)(ws + (40u << 20));        // 40..48MB (dead after attn)
  unsigned short* kb  = (unsigned short*)(ws + (48u << 20));        // 48..56MB (dead after attn)
  unsigned short* vtb = (unsigned short*)(ws + (56u << 20));        // 56..64MB
  unsigned short* obb = (unsigned short*)(ws + (64u << 20));        // 64..72MB
  float* Qf = (float*)(ws + (72u << 20));                           // 72..88MB

  // attention split partials reuse 0..24MB (dead after QKV GEMM)
  unsigned short* po = (unsigned short*)(ws);                       // 20MB
  float* marr = (float*)(ws + (22u << 20));
  float* larr = (float*)(ws + (23u << 20));

  // out-proj split-K=4 partials (po/qb/kb dead during out-proj)
  float* Of0 = Qf;                          // 72..88MB
  float* Of1 = (float*)(ws);                // 0..16MB
  float* Of2 = (float*)(ws + (16u << 20));  // 16..32MB
  float* Of3 = (float*)(ws + (40u << 20));  // 40..56MB

  // fused converts: one launch, 5 matrices
  k_cvt5<<<dim3(2048, 5), 256, 0, stream>>>(
      x, wq, wk, wv, wo,
      xb, w1b, w1b + (size_t)4 * 1024 * 1024, w1b + (size_t)8 * 1024 * 1024, wob);

  // fused QKV projection: 2048 x 6144 x 2048, 8-phase 256^2
  k_gemm8p<0><<<dim3(24, 8, 1), 512, 0, stream>>>(xb, w1b, 3 * CC, CC, CC,
                                                  Qf, out_k, out_v, nullptr);

  k_rope<<<TT, 256, 0, stream>>>(Qf, out_k, sqk, qb, kb);
  k_vt<<<dim3(32, 2, 16), 256, 0, stream>>>(out_v, vtb);

  k_attn_split<<<dim3(16, 16, 4), 512, 0, stream>>>(qb, kb, vtb, po, marr, larr);
  k_attn_reduce<<<dim3(16, 16), 256, 0, stream>>>(po, marr, larr, obb);

  // output projection: 2048 x 2048 x 2048, split-K=4 (256 blocks, NT=8)
  k_gemm8p<1><<<dim3(8, 8, 4), 512, 0, stream>>>(obb, wob, CC, CC, CC / 4,
                                                 Of0, Of1, Of2, Of3);

  k_l2norm<<<TT, 256, 0, stream>>>(Of0, Of1, Of2, Of3, out_norm);
}

// Round 10
// 216.582 us; speedup vs baseline: 1.0863x; 1.0316x over previous
//
#include <hip/hip_runtime.h>

typedef __bf16 bf16x8 __attribute__((ext_vector_type(8)));
typedef float f32x4 __attribute__((ext_vector_type(4)));
typedef unsigned short us4 __attribute__((ext_vector_type(4)));

constexpr int TT = 2048;   // tokens
constexpr int CC = 2048;   // channels
constexpr int HH = 16;     // heads
constexpr int DD = 128;    // head dim

__device__ __forceinline__ unsigned short f2bf(float f) {
  unsigned u = __builtin_bit_cast(unsigned, f);
  u += 0x7FFFu + ((u >> 16) & 1u);
  return (unsigned short)(u >> 16);
}
__device__ __forceinline__ float bf2f(unsigned short b) {
  unsigned u = ((unsigned)b) << 16;
  return __builtin_bit_cast(float, u);
}

// async global->LDS, 16B per lane. C-style casts lower to addrspacecast.
__device__ __forceinline__ void gld_lds16(const unsigned short* g, unsigned short* l) {
  __builtin_amdgcn_global_load_lds(
      (const __attribute__((address_space(1))) unsigned int*)g,
      (__attribute__((address_space(3))) unsigned int*)l,
      16, 0, 0);
}

// split-slot table for QBLK=128, SPLIT=512 keys: ns(qt)=qt/4+1, 40 slots/head
__device__ __forceinline__ int soff(int qt) {
  int g = qt >> 2, rem = qt & 3;
  return (g + 1) * (2 * g + rem);
}

// ---------------- fused f32 -> bf16 convert (5 matrices, one launch) ----------------
__global__ __launch_bounds__(256) void k_cvt5(
    const float* __restrict__ s0, const float* __restrict__ s1,
    const float* __restrict__ s2, const float* __restrict__ s3,
    const float* __restrict__ s4,
    unsigned short* __restrict__ d0, unsigned short* __restrict__ d1,
    unsigned short* __restrict__ d2, unsigned short* __restrict__ d3,
    unsigned short* __restrict__ d4) {
  const int m = blockIdx.y;
  const float* src = (m == 0) ? s0 : (m == 1) ? s1 : (m == 2) ? s2 : (m == 3) ? s3 : s4;
  unsigned short* dst = (m == 0) ? d0 : (m == 1) ? d1 : (m == 2) ? d2 : (m == 3) ? d3 : d4;
  int i = blockIdx.x * 256 + threadIdx.x;
  const float4* s = (const float4*)src;
  float4 a = s[2 * i], b = s[2 * i + 1];
  us4 lo = { f2bf(a.x), f2bf(a.y), f2bf(a.z), f2bf(a.w) };
  us4 hi = { f2bf(b.x), f2bf(b.y), f2bf(b.z), f2bf(b.w) };
  us4* d = (us4*)dst;
  d[2 * i] = lo;
  d[2 * i + 1] = hi;
}

#define WAIT_LGKM0                                      \
  asm volatile("s_waitcnt lgkmcnt(0)" ::: "memory");    \
  __builtin_amdgcn_sched_barrier(0);
#define BAR __builtin_amdgcn_s_barrier();

// ---------------- QKV GEMM: 256x192 tile, 8-phase, counted vmcnt, 256 blocks ----
// C = A(2048xK) * B(6144xK)^T, K=2048. 512 thr = 8 waves (2M x 4N), wave 128x48.
// LDS: A 2x(256x64)=64KB + B 2x(192x64)=48KB = 112KB -> grid 32x8 = 256 = 1/CU.
// Loads/thread/tile: A=4, B=3. Slots: p1/p2=A(t1)->d1, p3/p4=B(t2)->d0,
// p5/p6=A(t2)->d0, p7/p8=B(t3)->d1. vmcnt(3) at p4 (forces t1) / p8 (forces t2).
// Epilogue: col<2048 -> Q bf16, <4096 -> new_k f32 (h,t,d), else new_v f32.
__global__ __launch_bounds__(512, 2) void k_gemm192(
    const unsigned short* __restrict__ A, const unsigned short* __restrict__ B,
    unsigned short* __restrict__ qraw,
    float* __restrict__ outk, float* __restrict__ outv) {
  __shared__ alignas(16) unsigned short As[2][256 * 64];
  __shared__ alignas(16) unsigned short Bs[2][192 * 64];
  const int K = CC, NT = K >> 6, NT2 = NT >> 1;
  const int tid = threadIdx.x;
  const int m0 = blockIdx.y * 256, n0 = blockIdx.x * 192;
  const int wid = tid >> 6, lane = tid & 63;
  const int wr = wid >> 2, wc = wid & 3;
  const int lr = lane & 15, lg = lane >> 4;

  auto stA = [&](int buf, int jb, int tile) {  // 2 of A's 4 chunk-loads
#pragma unroll
    for (int j = jb; j < jb + 2; ++j) {
      const int ch = tid + j * 512;
      const int r = ch >> 3, c8 = ch & 7;
      gld_lds16(A + (size_t)(m0 + r) * K + tile * 64 + ((c8 ^ (r & 7)) * 8),
                &As[buf][ch * 8]);
    }
  };
  auto stB2 = [&](int buf, int tile) {  // first 2 of B's 3 chunk-loads
#pragma unroll
    for (int j = 0; j < 2; ++j) {
      const int ch = tid + j * 512;
      const int r = ch >> 3, c8 = ch & 7;
      gld_lds16(B + (size_t)(n0 + r) * K + tile * 64 + ((c8 ^ (r & 7)) * 8),
                &Bs[buf][ch * 8]);
    }
  };
  auto stB1 = [&](int buf, int tile) {  // last 1 of B's 3
    const int ch = tid + 1024;
    const int r = ch >> 3, c8 = ch & 7;
    gld_lds16(B + (size_t)(n0 + r) * K + tile * 64 + ((c8 ^ (r & 7)) * 8),
              &Bs[buf][ch * 8]);
  };

  f32x4 acc[8][3] = {};
  bf16x8 alo[4][2], ahi[4][2], b01[2][2], b2v[2];

  auto rdAlo = [&](int d) {
#pragma unroll
    for (int im = 0; im < 4; ++im)
#pragma unroll
      for (int kk = 0; kk < 2; ++kk) {
        const int row = wr * 128 + im * 16 + lr;
        alo[im][kk] = *(const bf16x8*)(&As[d][row * 64 + (((kk * 4 + lg) ^ (row & 7)) * 8)]);
      }
  };
  auto rdAhi = [&](int d) {
#pragma unroll
    for (int im = 0; im < 4; ++im)
#pragma unroll
      for (int kk = 0; kk < 2; ++kk) {
        const int row = wr * 128 + (4 + im) * 16 + lr;
        ahi[im][kk] = *(const bf16x8*)(&As[d][row * 64 + (((kk * 4 + lg) ^ (row & 7)) * 8)]);
      }
  };
  auto rdB01 = [&](int d) {
#pragma unroll
    for (int in = 0; in < 2; ++in)
#pragma unroll
      for (int kk = 0; kk < 2; ++kk) {
        const int row = wc * 48 + in * 16 + lr;
        b01[in][kk] = *(const bf16x8*)(&Bs[d][row * 64 + (((kk * 4 + lg) ^ (row & 7)) * 8)]);
      }
  };
  auto rdB2 = [&](int d) {
#pragma unroll
    for (int kk = 0; kk < 2; ++kk) {
      const int row = wc * 48 + 32 + lr;
      b2v[kk] = *(const bf16x8*)(&Bs[d][row * 64 + (((kk * 4 + lg) ^ (row & 7)) * 8)]);
    }
  };

  auto q_lo01 = [&]() {  // 16 MFMA
    __builtin_amdgcn_s_setprio(1);
#pragma unroll
    for (int im = 0; im < 4; ++im)
#pragma unroll
      for (int in = 0; in < 2; ++in)
#pragma unroll
        for (int kk = 0; kk < 2; ++kk)
          acc[im][in] = __builtin_amdgcn_mfma_f32_16x16x32_bf16(alo[im][kk], b01[in][kk], acc[im][in], 0, 0, 0);
    __builtin_amdgcn_s_setprio(0);
  };
  auto q_lo2 = [&]() {  // 8 MFMA
    __builtin_amdgcn_s_setprio(1);
#pragma unroll
    for (int im = 0; im < 4; ++im)
#pragma unroll
      for (int kk = 0; kk < 2; ++kk)
        acc[im][2] = __builtin_amdgcn_mfma_f32_16x16x32_bf16(alo[im][kk], b2v[kk], acc[im][2], 0, 0, 0);
    __builtin_amdgcn_s_setprio(0);
  };
  auto q_hi2 = [&]() {  // 8 MFMA
    __builtin_amdgcn_s_setprio(1);
#pragma unroll
    for (int im = 0; im < 4; ++im)
#pragma unroll
      for (int kk = 0; kk < 2; ++kk)
        acc[4 + im][2] = __builtin_amdgcn_mfma_f32_16x16x32_bf16(ahi[im][kk], b2v[kk], acc[4 + im][2], 0, 0, 0);
    __builtin_amdgcn_s_setprio(0);
  };
  auto q_hi01 = [&]() {  // 16 MFMA
    __builtin_amdgcn_s_setprio(1);
#pragma unroll
    for (int im = 0; im < 4; ++im)
#pragma unroll
      for (int in = 0; in < 2; ++in)
#pragma unroll
        for (int kk = 0; kk < 2; ++kk)
          acc[4 + im][in] = __builtin_amdgcn_mfma_f32_16x16x32_bf16(ahi[im][kk], b01[in][kk], acc[4 + im][in], 0, 0, 0);
    __builtin_amdgcn_s_setprio(0);
  };

  // ---- prologue: B0,A0 (7 loads) + B1 (3); vmcnt(3) forces tile0 ----
  stB2(0, 0); stB1(0, 0); stA(0, 0, 0); stA(0, 2, 0);
  stB2(1, 1); stB1(1, 1);
  asm volatile("s_waitcnt vmcnt(3)" ::: "memory");
  __builtin_amdgcn_sched_barrier(0);
  BAR

  for (int t = 0; t < NT2; ++t) {
    const int t1 = 2 * t + 1, t2 = 2 * t + 2, t3 = 2 * t + 3;
    const bool s2 = t2 < NT;  // NT even => s3 == s2

    // p1: rd d0.{alo,b01}; stage A(t1) 0,1 -> d1
    rdAlo(0); rdB01(0);
    stA(1, 0, t1);
    BAR WAIT_LGKM0
    q_lo01();
    BAR
    // p2: rd d0.b2; stage A(t1) 2,3 -> d1
    rdB2(0);
    stA(1, 2, t1);
    BAR WAIT_LGKM0
    q_lo2();
    BAR
    // p3: rd d0.ahi; stage B(t2) 0,1 -> d0
    rdAhi(0);
    if (s2) stB2(0, t2);
    BAR WAIT_LGKM0
    q_hi2();
    BAR
    // p4: stage B(t2) 2 -> d0; Q hi x b01; vmcnt forces t1
    if (s2) stB1(0, t2);
    q_hi01();
    if (s2) { asm volatile("s_waitcnt vmcnt(3)" ::: "memory"); }
    else    { asm volatile("s_waitcnt vmcnt(0)" ::: "memory"); }
    __builtin_amdgcn_sched_barrier(0);
    BAR

    // p5: rd d1.{alo,b01}; stage A(t2) 0,1 -> d0
    rdAlo(1); rdB01(1);
    if (s2) stA(0, 0, t2);
    BAR WAIT_LGKM0
    q_lo01();
    BAR
    // p6: rd d1.b2; stage A(t2) 2,3 -> d0
    rdB2(1);
    if (s2) stA(0, 2, t2);
    BAR WAIT_LGKM0
    q_lo2();
    BAR
    // p7: rd d1.ahi; stage B(t3) 0,1 -> d1
    rdAhi(1);
    if (s2) stB2(1, t3);
    BAR WAIT_LGKM0
    q_hi2();
    BAR
    // p8: stage B(t3) 2 -> d1; Q hi x b01; vmcnt forces t2
    if (s2) stB1(1, t3);
    q_hi01();
    if (s2) { asm volatile("s_waitcnt vmcnt(3)" ::: "memory"); }
    else    { asm volatile("s_waitcnt vmcnt(0)" ::: "memory"); }
    __builtin_amdgcn_sched_barrier(0);
    BAR
  }

  // ---- epilogue: Q -> bf16 qraw; K,V -> f32 (h,t,d) ----
#pragma unroll
  for (int mf = 0; mf < 8; ++mf) {
    const int row = m0 + wr * 128 + mf * 16 + lg * 4;
#pragma unroll
    for (int nf = 0; nf < 3; ++nf) {
      const int col = n0 + wc * 48 + nf * 16 + lr;
#pragma unroll
      for (int r = 0; r < 4; ++r) {
        float v = acc[mf][nf][r];
        int rr = row + r;
        if (col < 2048) {
          qraw[(size_t)rr * 2048 + col] = f2bf(v);
        } else if (col < 4096) {
          int c = col - 2048;
          outk[(size_t)(c >> 7) * (TT * DD) + (size_t)rr * DD + (c & 127)] = v;
        } else {
          int c = col - 4096;
          outv[(size_t)(c >> 7) * (TT * DD) + (size_t)rr * DD + (c & 127)] = v;
        }
      }
    }
  }
}

// ---------------- out-proj GEMM: 256x256 8-phase, split-K (from R9) ----------------
__global__ __launch_bounds__(512, 2) void k_gemm8p(
    const unsigned short* __restrict__ A, const unsigned short* __restrict__ B,
    int N, int K, int kspan,
    float* __restrict__ out0, float* __restrict__ out1,
    float* __restrict__ out2, float* __restrict__ out3) {
  __shared__ alignas(16) unsigned short As[2][2][128 * 64];
  __shared__ alignas(16) unsigned short Bs[2][2][128 * 64];
  const int tid = threadIdx.x;
  const int m0 = blockIdx.y * 256, n0 = blockIdx.x * 256;
  const int kbeg = blockIdx.z * kspan;
  const int NT = kspan >> 6, NT2 = NT >> 1;
  const int wid = tid >> 6, lane = tid & 63;
  const int wr = wid >> 2, wc = wid & 3;
  const int lr = lane & 15, lg = lane >> 4;
  const int bh = wc >> 1, brow0 = (wc & 1) * 64;

  const int sr0 = tid >> 3, sc0 = tid & 7;
  const unsigned short* Ab = A + kbeg;
  const unsigned short* Bb = B + kbeg;

  auto stageA = [&](int buf, int half, int tile) {
    const int koff = tile * 64;
#pragma unroll
    for (int j = 0; j < 2; ++j) {
      const int r = sr0 + j * 64;
      gld_lds16(Ab + (size_t)(m0 + half * 128 + r) * K + koff + ((sc0 ^ (r & 7)) * 8),
                &As[buf][half][(tid + j * 512) * 8]);
    }
  };
  auto stageB = [&](int buf, int half, int tile) {
    const int koff = tile * 64;
#pragma unroll
    for (int j = 0; j < 2; ++j) {
      const int r = sr0 + j * 64;
      gld_lds16(Bb + (size_t)(n0 + half * 128 + r) * K + koff + ((sc0 ^ (r & 7)) * 8),
                &Bs[buf][half][(tid + j * 512) * 8]);
    }
  };

  f32x4 acc[8][4] = {};
  bf16x8 alo[4][2], ahi[4][2], ba[2][2], bb[2][2];

  auto rdAlo = [&](int d) {
#pragma unroll
    for (int im = 0; im < 4; ++im)
#pragma unroll
      for (int kk = 0; kk < 2; ++kk) {
        const int row = im * 16 + lr;
        alo[im][kk] = *(const bf16x8*)(&As[d][wr][row * 64 + (((kk * 4 + lg) ^ (row & 7)) * 8)]);
      }
  };
  auto rdAhi = [&](int d) {
#pragma unroll
    for (int im = 0; im < 4; ++im)
#pragma unroll
      for (int kk = 0; kk < 2; ++kk) {
        const int row = (4 + im) * 16 + lr;
        ahi[im][kk] = *(const bf16x8*)(&As[d][wr][row * 64 + (((kk * 4 + lg) ^ (row & 7)) * 8)]);
      }
  };
  auto rdBa = [&](int d) {
#pragma unroll
    for (int in = 0; in < 2; ++in)
#pragma unroll
      for (int kk = 0; kk < 2; ++kk) {
        const int row = brow0 + in * 16 + lr;
        ba[in][kk] = *(const bf16x8*)(&Bs[d][bh][row * 64 + (((kk * 4 + lg) ^ (row & 7)) * 8)]);
      }
  };
  auto rdBb = [&](int d) {
#pragma unroll
    for (int in = 0; in < 2; ++in)
#pragma unroll
      for (int kk = 0; kk < 2; ++kk) {
        const int row = brow0 + (2 + in) * 16 + lr;
        bb[in][kk] = *(const bf16x8*)(&Bs[d][bh][row * 64 + (((kk * 4 + lg) ^ (row & 7)) * 8)]);
      }
  };

#define MFMA_Q(MB, NB, AF, BF)                                                     \
  __builtin_amdgcn_s_setprio(1);                                                   \
  _Pragma("unroll") for (int im = 0; im < 4; ++im)                                 \
      _Pragma("unroll") for (int in = 0; in < 2; ++in)                             \
          _Pragma("unroll") for (int kk = 0; kk < 2; ++kk)                         \
              acc[MB + im][NB + in] = __builtin_amdgcn_mfma_f32_16x16x32_bf16(     \
                  AF[im][kk], BF[in][kk], acc[MB + im][NB + in], 0, 0, 0);         \
  __builtin_amdgcn_s_setprio(0);

  stageB(0, 0, 0); stageB(0, 1, 0); stageA(0, 0, 0); stageA(0, 1, 0);
  if (NT > 1) { stageB(1, 0, 1); stageB(1, 1, 1); }
  asm volatile("s_waitcnt vmcnt(4)" ::: "memory");
  __builtin_amdgcn_sched_barrier(0);
  BAR

  for (int t = 0; t < NT2; ++t) {
    const int t1 = 2 * t + 1, t2 = 2 * t + 2, t3 = 2 * t + 3;
    const bool s2 = t2 < NT, s3 = t3 < NT;

    rdAlo(0); rdBa(0);
    stageA(1, 0, t1);
    BAR WAIT_LGKM0
    MFMA_Q(0, 0, alo, ba)
    BAR
    rdBb(0);
    stageA(1, 1, t1);
    BAR WAIT_LGKM0
    MFMA_Q(0, 2, alo, bb)
    BAR
    rdAhi(0);
    if (s2) stageB(0, 0, t2);
    BAR WAIT_LGKM0
    MFMA_Q(4, 2, ahi, bb)
    BAR
    if (s2) stageB(0, 1, t2);
    MFMA_Q(4, 0, ahi, ba)
    if (s2) { asm volatile("s_waitcnt vmcnt(4)" ::: "memory"); }
    else    { asm volatile("s_waitcnt vmcnt(0)" ::: "memory"); }
    __builtin_amdgcn_sched_barrier(0);
    BAR

    rdAlo(1); rdBa(1);
    if (s2) stageA(0, 0, t2);
    BAR WAIT_LGKM0
    MFMA_Q(0, 0, alo, ba)
    BAR
    rdBb(1);
    if (s2) stageA(0, 1, t2);
    BAR WAIT_LGKM0
    MFMA_Q(0, 2, alo, bb)
    BAR
    rdAhi(1);
    if (s3) stageB(1, 0, t3);
    BAR WAIT_LGKM0
    MFMA_Q(4, 2, ahi, bb)
    BAR
    if (s3) stageB(1, 1, t3);
    MFMA_Q(4, 0, ahi, ba)
    if (s3) { asm volatile("s_waitcnt vmcnt(4)" ::: "memory"); }
    else    { asm volatile("s_waitcnt vmcnt(0)" ::: "memory"); }
    __builtin_amdgcn_sched_barrier(0);
    BAR
  }
#undef MFMA_Q

  int z = blockIdx.z;
  float* dst = (z == 0) ? out0 : (z == 1) ? out1 : (z == 2) ? out2 : out3;
#pragma unroll
  for (int mf = 0; mf < 8; ++mf) {
    const int row = m0 + wr * 128 + mf * 16 + lg * 4;
#pragma unroll
    for (int nf = 0; nf < 4; ++nf) {
      const int col = n0 + wc * 64 + nf * 16 + lr;
#pragma unroll
      for (int r = 0; r < 4; ++r) {
        dst[(size_t)(row + r) * N + col] = acc[mf][nf][r];
      }
    }
  }
}
#undef WAIT_LGKM0
#undef BAR

// ---------------- RoPE + scale: q from bf16 qraw, k from f32; pack bf16 [h][t][d] ----
__global__ __launch_bounds__(256) void k_rope(
    const unsigned short* __restrict__ qraw, const float* __restrict__ Kraw,
    const float* __restrict__ sqk,
    unsigned short* __restrict__ qb, unsigned short* __restrict__ kb) {
  const int t = blockIdx.x;
  for (int i = threadIdx.x; i < HH * 64; i += 256) {
    int h = i >> 6, dp = i & 63;
    float theta = expf(-(float)dp * 0.14391156831212787f);
    float ang = (float)t * theta;
    float sn, cs;
    sincosf(ang, &sn, &cs);
    float qr = bf2f(qraw[(size_t)t * CC + h * DD + dp]);
    float qi = bf2f(qraw[(size_t)t * CC + h * DD + dp + 64]);
    const float* kp = Kraw + (size_t)h * TT * DD + (size_t)t * DD;
    float kr = kp[dp], ki = kp[dp + 64];
    float sr = sqk[h * DD + dp];
    float si = sqk[h * DD + dp + 64];
    float qsr = sr * 512.0f, qsi = si * 512.0f;                         // sqrt(C)*sqrt(D)
    float ksr = sr * 45.25483399593904f, ksi = si * 45.25483399593904f; // sqrt(C)
    unsigned short* qo = qb + ((size_t)h * TT + t) * DD;
    unsigned short* ko = kb + ((size_t)h * TT + t) * DD;
    qo[dp]      = f2bf((qr * cs - qi * sn) * qsr);
    qo[dp + 64] = f2bf((qr * sn + qi * cs) * qsi);
    ko[dp]      = f2bf((kr * cs - ki * sn) * ksr);
    ko[dp + 64] = f2bf((kr * sn + ki * cs) * ksi);
  }
}

// ---------------- V transpose: new_v f32 [h][t][d] -> vt bf16 [h][d][t] ----------------
__global__ __launch_bounds__(256) void k_vt(
    const float* __restrict__ Vraw, unsigned short* __restrict__ vt) {
  const int h = blockIdx.z;
  const int t0 = blockIdx.x * 64, d0 = blockIdx.y * 64;
  __shared__ unsigned short tile[64][65];
  const float* vp = Vraw + (size_t)h * TT * DD;
  for (int i = threadIdx.x; i < 4096; i += 256) {
    int r = i >> 6, c = i & 63;
    tile[r][c] = f2bf(vp[(size_t)(t0 + r) * DD + d0 + c]);
  }
  __syncthreads();
  unsigned short* op = vt + (size_t)h * DD * TT;
  for (int i = threadIdx.x; i < 4096; i += 256) {
    int dr = i >> 6, tc = i & 63;
    op[(size_t)(d0 + dr) * TT + t0 + tc] = tile[tc][dr];
  }
}

// ---------------- causal flash attention, 8-wave LDS-staged, split-K ----------------
__global__ __launch_bounds__(512) void k_attn_split(
    const unsigned short* __restrict__ qb, const unsigned short* __restrict__ kb,
    const unsigned short* __restrict__ vt,
    unsigned short* __restrict__ po, float* __restrict__ marr, float* __restrict__ larr) {
  const int qt = blockIdx.x, h = blockIdx.y, s = blockIdx.z;
  if (4 * s > qt) return;
  const int slot = h * 40 + soff(qt) + s;
  const int kbeg = 512 * s;
  const int kend = min(kbeg + 512, 128 * qt + 128);
  const int ntiles = (kend - kbeg) >> 6;
  const int tid = threadIdx.x;
  const int wid = tid >> 6, lane = tid & 63;
  const int lr = lane & 15, lg = lane >> 4;
  const int q0 = qt * 128 + wid * 16;

  __shared__ alignas(16) unsigned short Ks[64 * 128];
  __shared__ alignas(16) unsigned short Vs[128 * 64];
  __shared__ alignas(16) unsigned short P[8][16][72];

  const unsigned short* qh = qb + (size_t)h * TT * DD;
  const unsigned short* kh = kb + (size_t)h * TT * DD;
  const unsigned short* vh = vt + (size_t)h * DD * TT;

  bf16x8 qf[4];
#pragma unroll
  for (int c = 0; c < 4; ++c)
    qf[c] = *(const bf16x8*)(qh + (size_t)(q0 + lr) * DD + c * 32 + lg * 8);

  f32x4 acc[8] = {};
  float mrow[4] = {-3e38f, -3e38f, -3e38f, -3e38f};
  float lsum[4] = {0.f, 0.f, 0.f, 0.f};

  for (int kt = 0; kt < ntiles; ++kt) {
    const int k0 = kbeg + kt * 64;
#pragma unroll
    for (int half = 0; half < 2; ++half) {
      int ch = tid + half * 512;
      int r = ch >> 4, c4 = ch & 15;
      gld_lds16(kh + (size_t)(k0 + r) * DD + ((c4 ^ (r & 7)) * 8), Ks + ch * 8);
    }
#pragma unroll
    for (int half = 0; half < 2; ++half) {
      int ch = tid + half * 512;
      int d = ch >> 3, c8 = ch & 7;
      gld_lds16(vh + (size_t)d * TT + k0 + ((c8 ^ (d & 7)) * 8), Vs + ch * 8);
    }
    __syncthreads();

    if (k0 <= q0 + 15) {
      f32x4 sv[4] = {};
#pragma unroll
      for (int ktile = 0; ktile < 4; ++ktile) {
        const int row = ktile * 16 + lr;
#pragma unroll
        for (int c = 0; c < 4; ++c) {
          int chn = (c * 4 + lg) ^ (lr & 7);
          bf16x8 kf = *(const bf16x8*)(Ks + row * 128 + chn * 8);
          sv[ktile] = __builtin_amdgcn_mfma_f32_16x16x32_bf16(qf[c], kf, sv[ktile], 0, 0, 0);
        }
      }
      if (k0 + 63 > q0) {
#pragma unroll
        for (int ktile = 0; ktile < 4; ++ktile)
#pragma unroll
          for (int r = 0; r < 4; ++r) {
            int key = k0 + ktile * 16 + lr;
            int qrow = q0 + lg * 4 + r;
            if (key > qrow) sv[ktile][r] = -1e30f;
          }
      }
      float pmax[4];
#pragma unroll
      for (int r = 0; r < 4; ++r)
        pmax[r] = fmaxf(fmaxf(sv[0][r], sv[1][r]), fmaxf(sv[2][r], sv[3][r]));
#pragma unroll
      for (int msk = 1; msk <= 8; msk <<= 1)
#pragma unroll
        for (int r = 0; r < 4; ++r) pmax[r] = fmaxf(pmax[r], __shfl_xor(pmax[r], msk));
      float p[4][4], ps[4], scl[4];
#pragma unroll
      for (int r = 0; r < 4; ++r) {
        float mn = fmaxf(mrow[r], pmax[r]);
        scl[r] = __expf(mrow[r] - mn);
        mrow[r] = mn;
        ps[r] = 0.f;
#pragma unroll
        for (int ktile = 0; ktile < 4; ++ktile) {
          p[ktile][r] = __expf(sv[ktile][r] - mn);
          ps[r] += p[ktile][r];
        }
      }
#pragma unroll
      for (int msk = 1; msk <= 8; msk <<= 1)
#pragma unroll
        for (int r = 0; r < 4; ++r) ps[r] += __shfl_xor(ps[r], msk);
#pragma unroll
      for (int r = 0; r < 4; ++r) lsum[r] = lsum[r] * scl[r] + ps[r];
#pragma unroll
      for (int n = 0; n < 8; ++n)
#pragma unroll
        for (int r = 0; r < 4; ++r) acc[n][r] *= scl[r];
#pragma unroll
      for (int ktile = 0; ktile < 4; ++ktile)
#pragma unroll
        for (int r = 0; r < 4; ++r)
          P[wid][lg * 4 + r][ktile * 16 + lr] = f2bf(p[ktile][r]);
      asm volatile("s_waitcnt lgkmcnt(0)" ::: "memory");
      __builtin_amdgcn_sched_barrier(0);
      bf16x8 pf[2];
#pragma unroll
      for (int ks = 0; ks < 2; ++ks)
        pf[ks] = *(const bf16x8*)(&P[wid][lr][ks * 32 + lg * 8]);
#pragma unroll
      for (int n = 0; n < 8; ++n) {
        const int row = n * 16 + lr;
#pragma unroll
        for (int ks = 0; ks < 2; ++ks) {
          int chn = (ks * 4 + lg) ^ (lr & 7);
          bf16x8 vf = *(const bf16x8*)(Vs + row * 64 + chn * 8);
          acc[n] = __builtin_amdgcn_mfma_f32_16x16x32_bf16(pf[ks], vf, acc[n], 0, 0, 0);
        }
      }
    }
    __syncthreads();
  }

  unsigned short* pob = po + (size_t)slot * (128 * DD);
#pragma unroll
  for (int n = 0; n < 8; ++n)
#pragma unroll
    for (int r = 0; r < 4; ++r) {
      int row = wid * 16 + lg * 4 + r;
      pob[(size_t)row * DD + n * 16 + lr] = f2bf(acc[n][r]);
    }
  if (lr == 0) {
#pragma unroll
    for (int r = 0; r < 4; ++r) {
      int row = wid * 16 + lg * 4 + r;
      marr[(size_t)slot * 128 + row] = mrow[r];
      larr[(size_t)slot * 128 + row] = lsum[r];
    }
  }
}

// ---------------- split reduce ----------------
__global__ __launch_bounds__(256) void k_attn_reduce(
    const unsigned short* __restrict__ po, const float* __restrict__ marr,
    const float* __restrict__ larr, unsigned short* __restrict__ ob) {
  const int qt = blockIdx.x, h = blockIdx.y;
  const int ns = (qt >> 2) + 1;
  const int sb = h * 40 + soff(qt);
  const int tid = threadIdx.x;
  const int row = tid >> 1, d0 = (tid & 1) * 64;
  float mstar = -3e38f;
  for (int s = 0; s < ns; ++s) mstar = fmaxf(mstar, marr[(size_t)(sb + s) * 128 + row]);
  float w[4];
  float ltot = 0.f;
  for (int s = 0; s < ns; ++s) {
    w[s] = __expf(marr[(size_t)(sb + s) * 128 + row] - mstar);
    ltot += w[s] * larr[(size_t)(sb + s) * 128 + row];
  }
  float inv = 1.0f / ltot;
  float o[64] = {};
  for (int s = 0; s < ns; ++s) {
    const bf16x8* pp = (const bf16x8*)(po + (size_t)(sb + s) * (128 * DD) + (size_t)row * DD + d0);
    float ws = w[s];
#pragma unroll
    for (int j = 0; j < 8; ++j) {
      bf16x8 v = pp[j];
#pragma unroll
      for (int e = 0; e < 8; ++e) o[j * 8 + e] += ws * (float)v[e];
    }
  }
  unsigned short* op = ob + (size_t)(qt * 128 + row) * CC + h * DD + d0;
#pragma unroll
  for (int j = 0; j < 16; ++j) {
    us4 t = { f2bf(o[4 * j] * inv), f2bf(o[4 * j + 1] * inv),
              f2bf(o[4 * j + 2] * inv), f2bf(o[4 * j + 3] * inv) };
    ((us4*)op)[j] = t;
  }
}

// ---------------- row l2norm over sum of four split-K partials ----------------
__global__ __launch_bounds__(256) void k_l2norm(
    const float* __restrict__ Of0, const float* __restrict__ Of1,
    const float* __restrict__ Of2, const float* __restrict__ Of3,
    float* __restrict__ out) {
  const int t = blockIdx.x;
  const int tid = threadIdx.x;
  const float4* p0 = (const float4*)(Of0 + (size_t)t * CC);
  const float4* p1 = (const float4*)(Of1 + (size_t)t * CC);
  const float4* p2 = (const float4*)(Of2 + (size_t)t * CC);
  const float4* p3 = (const float4*)(Of3 + (size_t)t * CC);
  float4 a = p0[2 * tid], b = p0[2 * tid + 1];
  float4 a1 = p1[2 * tid], b1 = p1[2 * tid + 1];
  float4 a2 = p2[2 * tid], b2 = p2[2 * tid + 1];
  float4 a3 = p3[2 * tid], b3 = p3[2 * tid + 1];
  a.x += a1.x + a2.x + a3.x; a.y += a1.y + a2.y + a3.y;
  a.z += a1.z + a2.z + a3.z; a.w += a1.w + a2.w + a3.w;
  b.x += b1.x + b2.x + b3.x; b.y += b1.y + b2.y + b3.y;
  b.z += b1.z + b2.z + b3.z; b.w += b1.w + b2.w + b3.w;
  float ss = a.x * a.x + a.y * a.y + a.z * a.z + a.w * a.w +
             b.x * b.x + b.y * b.y + b.z * b.z + b.w * b.w;
#pragma unroll
  for (int msk = 1; msk < 64; msk <<= 1) ss += __shfl_xor(ss, msk);
  __shared__ float red[4];
  if ((tid & 63) == 0) red[tid >> 6] = ss;
  __syncthreads();
  ss = red[0] + red[1] + red[2] + red[3];
  float sc = 1.0f / fmaxf(sqrtf(ss), 1e-12f);
  float4 oa = { a.x * sc, a.y * sc, a.z * sc, a.w * sc };
  float4 obv = { b.x * sc, b.y * sc, b.z * sc, b.w * sc };
  float4* o = (float4*)(out + (size_t)t * CC);
  o[2 * tid] = oa;
  o[2 * tid + 1] = obv;
}

extern "C" void kernel_launch(void* const* d_in, const int* in_sizes, int n_in,
                              void* d_out, int out_size, void* d_ws, size_t ws_size,
                              hipStream_t stream) {
  const float* x   = (const float*)d_in[0];
  const float* wq  = (const float*)d_in[1];
  const float* wk  = (const float*)d_in[2];
  const float* wv  = (const float*)d_in[3];
  const float* wo  = (const float*)d_in[4];
  const float* sqk = (const float*)d_in[5];

  float* out_norm = (float*)d_out;
  float* out_k = out_norm + (size_t)4 * 1024 * 1024;
  float* out_v = out_norm + (size_t)8 * 1024 * 1024;

  char* ws = (char*)d_ws;
  unsigned short* xb  = (unsigned short*)(ws);                      // 0..8MB  (dead after QKV)
  unsigned short* w1b = (unsigned short*)(ws + (8u << 20));         // 8..32MB (dead after QKV)
  unsigned short* wob = (unsigned short*)(ws + (32u << 20));        // 32..40MB
  unsigned short* qb  = (unsigned short*)(ws + (40u << 20));        // 40..48MB (dead after attn)
  unsigned short* kb  = (unsigned short*)(ws + (48u << 20));        // 48..56MB (dead after attn)
  unsigned short* vtb = (unsigned short*)(ws + (56u << 20));        // 56..64MB
  unsigned short* obb = (unsigned short*)(ws + (64u << 20));        // 64..72MB
  unsigned short* qraw = (unsigned short*)(ws + (72u << 20));       // 72..80MB bf16 Q (dead after rope)

  // attention split partials reuse 0..24MB (dead after QKV GEMM)
  unsigned short* po = (unsigned short*)(ws);                       // 20MB
  float* marr = (float*)(ws + (22u << 20));
  float* larr = (float*)(ws + (23u << 20));

  // out-proj split-K=4 partials (po/qb/kb/qraw dead during out-proj)
  float* Of0 = (float*)(ws + (72u << 20));  // 72..88MB
  float* Of1 = (float*)(ws);                // 0..16MB
  float* Of2 = (float*)(ws + (16u << 20));  // 16..32MB
  float* Of3 = (float*)(ws + (40u << 20));  // 40..56MB

  // fused converts: one launch, 5 matrices
  k_cvt5<<<dim3(2048, 5), 256, 0, stream>>>(
      x, wq, wk, wv, wo,
      xb, w1b, w1b + (size_t)4 * 1024 * 1024, w1b + (size_t)8 * 1024 * 1024, wob);

  // fused QKV projection: 2048 x 6144 x 2048, 256x192 tiles -> 256 blocks (1/CU)
  k_gemm192<<<dim3(32, 8), 512, 0, stream>>>(xb, w1b, qraw, out_k, out_v);

  k_rope<<<TT, 256, 0, stream>>>(qraw, out_k, sqk, qb, kb);
  k_vt<<<dim3(32, 2, 16), 256, 0, stream>>>(out_v, vtb);

  k_attn_split<<<dim3(16, 16, 4), 512, 0, stream>>>(qb, kb, vtb, po, marr, larr);
  k_attn_reduce<<<dim3(16, 16), 256, 0, stream>>>(po, marr, larr, obb);

  // output projection: 2048 x 2048 x 2048, split-K=4 (256 blocks)
  k_gemm8p<<<dim3(8, 8, 4), 512, 0, stream>>>(obb, wob, CC, CC, CC / 4,
                                              Of0, Of1, Of2, Of3);

  k_l2norm<<<TT, 256, 0, stream>>>(Of0, Of1, Of2, Of3, out_norm);
}

// Round 11
// 201.810 us; speedup vs baseline: 1.1658x; 1.0732x over previous
//
#include <hip/hip_runtime.h>

typedef __bf16 bf16x8 __attribute__((ext_vector_type(8)));
typedef float f32x4 __attribute__((ext_vector_type(4)));
typedef unsigned short us4 __attribute__((ext_vector_type(4)));

constexpr int TT = 2048;   // tokens
constexpr int CC = 2048;   // channels
constexpr int HH = 16;     // heads
constexpr int DD = 128;    // head dim

__device__ __forceinline__ unsigned short f2bf(float f) {
  unsigned u = __builtin_bit_cast(unsigned, f);
  u += 0x7FFFu + ((u >> 16) & 1u);
  return (unsigned short)(u >> 16);
}
__device__ __forceinline__ float bf2f(unsigned short b) {
  unsigned u = ((unsigned)b) << 16;
  return __builtin_bit_cast(float, u);
}

// async global->LDS, 16B per lane. C-style casts lower to addrspacecast.
__device__ __forceinline__ void gld_lds16(const unsigned short* g, unsigned short* l) {
  __builtin_amdgcn_global_load_lds(
      (const __attribute__((address_space(1))) unsigned int*)g,
      (__attribute__((address_space(3))) unsigned int*)l,
      16, 0, 0);
}

// ---------------- fused f32 -> bf16 convert (5 matrices, one launch) ----------------
__global__ __launch_bounds__(256) void k_cvt5(
    const float* __restrict__ s0, const float* __restrict__ s1,
    const float* __restrict__ s2, const float* __restrict__ s3,
    const float* __restrict__ s4,
    unsigned short* __restrict__ d0, unsigned short* __restrict__ d1,
    unsigned short* __restrict__ d2, unsigned short* __restrict__ d3,
    unsigned short* __restrict__ d4) {
  const int m = blockIdx.y;
  const float* src = (m == 0) ? s0 : (m == 1) ? s1 : (m == 2) ? s2 : (m == 3) ? s3 : s4;
  unsigned short* dst = (m == 0) ? d0 : (m == 1) ? d1 : (m == 2) ? d2 : (m == 3) ? d3 : d4;
  int i = blockIdx.x * 256 + threadIdx.x;
  const float4* s = (const float4*)src;
  float4 a = s[2 * i], b = s[2 * i + 1];
  us4 lo = { f2bf(a.x), f2bf(a.y), f2bf(a.z), f2bf(a.w) };
  us4 hi = { f2bf(b.x), f2bf(b.y), f2bf(b.z), f2bf(b.w) };
  us4* d = (us4*)dst;
  d[2 * i] = lo;
  d[2 * i + 1] = hi;
}

#define WAIT_LGKM0                                      \
  asm volatile("s_waitcnt lgkmcnt(0)" ::: "memory");    \
  __builtin_amdgcn_sched_barrier(0);
#define BAR __builtin_amdgcn_s_barrier();

// ---------------- QKV GEMM: 256x192 tile, 8-phase, counted vmcnt, 256 blocks ----
__global__ __launch_bounds__(512, 2) void k_gemm192(
    const unsigned short* __restrict__ A, const unsigned short* __restrict__ B,
    unsigned short* __restrict__ qraw,
    float* __restrict__ outk, float* __restrict__ outv) {
  __shared__ alignas(16) unsigned short As[2][256 * 64];
  __shared__ alignas(16) unsigned short Bs[2][192 * 64];
  const int K = CC, NT = K >> 6, NT2 = NT >> 1;
  const int tid = threadIdx.x;
  const int m0 = blockIdx.y * 256, n0 = blockIdx.x * 192;
  const int wid = tid >> 6, lane = tid & 63;
  const int wr = wid >> 2, wc = wid & 3;
  const int lr = lane & 15, lg = lane >> 4;

  auto stA = [&](int buf, int jb, int tile) {
#pragma unroll
    for (int j = jb; j < jb + 2; ++j) {
      const int ch = tid + j * 512;
      const int r = ch >> 3, c8 = ch & 7;
      gld_lds16(A + (size_t)(m0 + r) * K + tile * 64 + ((c8 ^ (r & 7)) * 8),
                &As[buf][ch * 8]);
    }
  };
  auto stB2 = [&](int buf, int tile) {
#pragma unroll
    for (int j = 0; j < 2; ++j) {
      const int ch = tid + j * 512;
      const int r = ch >> 3, c8 = ch & 7;
      gld_lds16(B + (size_t)(n0 + r) * K + tile * 64 + ((c8 ^ (r & 7)) * 8),
                &Bs[buf][ch * 8]);
    }
  };
  auto stB1 = [&](int buf, int tile) {
    const int ch = tid + 1024;
    const int r = ch >> 3, c8 = ch & 7;
    gld_lds16(B + (size_t)(n0 + r) * K + tile * 64 + ((c8 ^ (r & 7)) * 8),
              &Bs[buf][ch * 8]);
  };

  f32x4 acc[8][3] = {};
  bf16x8 alo[4][2], ahi[4][2], b01[2][2], b2v[2];

  auto rdAlo = [&](int d) {
#pragma unroll
    for (int im = 0; im < 4; ++im)
#pragma unroll
      for (int kk = 0; kk < 2; ++kk) {
        const int row = wr * 128 + im * 16 + lr;
        alo[im][kk] = *(const bf16x8*)(&As[d][row * 64 + (((kk * 4 + lg) ^ (row & 7)) * 8)]);
      }
  };
  auto rdAhi = [&](int d) {
#pragma unroll
    for (int im = 0; im < 4; ++im)
#pragma unroll
      for (int kk = 0; kk < 2; ++kk) {
        const int row = wr * 128 + (4 + im) * 16 + lr;
        ahi[im][kk] = *(const bf16x8*)(&As[d][row * 64 + (((kk * 4 + lg) ^ (row & 7)) * 8)]);
      }
  };
  auto rdB01 = [&](int d) {
#pragma unroll
    for (int in = 0; in < 2; ++in)
#pragma unroll
      for (int kk = 0; kk < 2; ++kk) {
        const int row = wc * 48 + in * 16 + lr;
        b01[in][kk] = *(const bf16x8*)(&Bs[d][row * 64 + (((kk * 4 + lg) ^ (row & 7)) * 8)]);
      }
  };
  auto rdB2 = [&](int d) {
#pragma unroll
    for (int kk = 0; kk < 2; ++kk) {
      const int row = wc * 48 + 32 + lr;
      b2v[kk] = *(const bf16x8*)(&Bs[d][row * 64 + (((kk * 4 + lg) ^ (row & 7)) * 8)]);
    }
  };

  auto q_lo01 = [&]() {
    __builtin_amdgcn_s_setprio(1);
#pragma unroll
    for (int im = 0; im < 4; ++im)
#pragma unroll
      for (int in = 0; in < 2; ++in)
#pragma unroll
        for (int kk = 0; kk < 2; ++kk)
          acc[im][in] = __builtin_amdgcn_mfma_f32_16x16x32_bf16(alo[im][kk], b01[in][kk], acc[im][in], 0, 0, 0);
    __builtin_amdgcn_s_setprio(0);
  };
  auto q_lo2 = [&]() {
    __builtin_amdgcn_s_setprio(1);
#pragma unroll
    for (int im = 0; im < 4; ++im)
#pragma unroll
      for (int kk = 0; kk < 2; ++kk)
        acc[im][2] = __builtin_amdgcn_mfma_f32_16x16x32_bf16(alo[im][kk], b2v[kk], acc[im][2], 0, 0, 0);
    __builtin_amdgcn_s_setprio(0);
  };
  auto q_hi2 = [&]() {
    __builtin_amdgcn_s_setprio(1);
#pragma unroll
    for (int im = 0; im < 4; ++im)
#pragma unroll
      for (int kk = 0; kk < 2; ++kk)
        acc[4 + im][2] = __builtin_amdgcn_mfma_f32_16x16x32_bf16(ahi[im][kk], b2v[kk], acc[4 + im][2], 0, 0, 0);
    __builtin_amdgcn_s_setprio(0);
  };
  auto q_hi01 = [&]() {
    __builtin_amdgcn_s_setprio(1);
#pragma unroll
    for (int im = 0; im < 4; ++im)
#pragma unroll
      for (int in = 0; in < 2; ++in)
#pragma unroll
        for (int kk = 0; kk < 2; ++kk)
          acc[4 + im][in] = __builtin_amdgcn_mfma_f32_16x16x32_bf16(ahi[im][kk], b01[in][kk], acc[4 + im][in], 0, 0, 0);
    __builtin_amdgcn_s_setprio(0);
  };

  stB2(0, 0); stB1(0, 0); stA(0, 0, 0); stA(0, 2, 0);
  stB2(1, 1); stB1(1, 1);
  asm volatile("s_waitcnt vmcnt(3)" ::: "memory");
  __builtin_amdgcn_sched_barrier(0);
  BAR

  for (int t = 0; t < NT2; ++t) {
    const int t1 = 2 * t + 1, t2 = 2 * t + 2, t3 = 2 * t + 3;
    const bool s2 = t2 < NT;

    rdAlo(0); rdB01(0);
    stA(1, 0, t1);
    BAR WAIT_LGKM0
    q_lo01();
    BAR
    rdB2(0);
    stA(1, 2, t1);
    BAR WAIT_LGKM0
    q_lo2();
    BAR
    rdAhi(0);
    if (s2) stB2(0, t2);
    BAR WAIT_LGKM0
    q_hi2();
    BAR
    if (s2) stB1(0, t2);
    q_hi01();
    if (s2) { asm volatile("s_waitcnt vmcnt(3)" ::: "memory"); }
    else    { asm volatile("s_waitcnt vmcnt(0)" ::: "memory"); }
    __builtin_amdgcn_sched_barrier(0);
    BAR

    rdAlo(1); rdB01(1);
    if (s2) stA(0, 0, t2);
    BAR WAIT_LGKM0
    q_lo01();
    BAR
    rdB2(1);
    if (s2) stA(0, 2, t2);
    BAR WAIT_LGKM0
    q_lo2();
    BAR
    rdAhi(1);
    if (s2) stB2(1, t3);
    BAR WAIT_LGKM0
    q_hi2();
    BAR
    if (s2) stB1(1, t3);
    q_hi01();
    if (s2) { asm volatile("s_waitcnt vmcnt(3)" ::: "memory"); }
    else    { asm volatile("s_waitcnt vmcnt(0)" ::: "memory"); }
    __builtin_amdgcn_sched_barrier(0);
    BAR
  }

#pragma unroll
  for (int mf = 0; mf < 8; ++mf) {
    const int row = m0 + wr * 128 + mf * 16 + lg * 4;
#pragma unroll
    for (int nf = 0; nf < 3; ++nf) {
      const int col = n0 + wc * 48 + nf * 16 + lr;
#pragma unroll
      for (int r = 0; r < 4; ++r) {
        float v = acc[mf][nf][r];
        int rr = row + r;
        if (col < 2048) {
          qraw[(size_t)rr * 2048 + col] = f2bf(v);
        } else if (col < 4096) {
          int c = col - 2048;
          outk[(size_t)(c >> 7) * (TT * DD) + (size_t)rr * DD + (c & 127)] = v;
        } else {
          int c = col - 4096;
          outv[(size_t)(c >> 7) * (TT * DD) + (size_t)rr * DD + (c & 127)] = v;
        }
      }
    }
  }
}

// ---------------- out-proj GEMM: 256x256 8-phase, split-K ----------------
__global__ __launch_bounds__(512, 2) void k_gemm8p(
    const unsigned short* __restrict__ A, const unsigned short* __restrict__ B,
    int N, int K, int kspan,
    float* __restrict__ out0, float* __restrict__ out1,
    float* __restrict__ out2, float* __restrict__ out3) {
  __shared__ alignas(16) unsigned short As[2][2][128 * 64];
  __shared__ alignas(16) unsigned short Bs[2][2][128 * 64];
  const int tid = threadIdx.x;
  const int m0 = blockIdx.y * 256, n0 = blockIdx.x * 256;
  const int kbeg = blockIdx.z * kspan;
  const int NT = kspan >> 6, NT2 = NT >> 1;
  const int wid = tid >> 6, lane = tid & 63;
  const int wr = wid >> 2, wc = wid & 3;
  const int lr = lane & 15, lg = lane >> 4;
  const int bh = wc >> 1, brow0 = (wc & 1) * 64;

  const int sr0 = tid >> 3, sc0 = tid & 7;
  const unsigned short* Ab = A + kbeg;
  const unsigned short* Bb = B + kbeg;

  auto stageA = [&](int buf, int half, int tile) {
    const int koff = tile * 64;
#pragma unroll
    for (int j = 0; j < 2; ++j) {
      const int r = sr0 + j * 64;
      gld_lds16(Ab + (size_t)(m0 + half * 128 + r) * K + koff + ((sc0 ^ (r & 7)) * 8),
                &As[buf][half][(tid + j * 512) * 8]);
    }
  };
  auto stageB = [&](int buf, int half, int tile) {
    const int koff = tile * 64;
#pragma unroll
    for (int j = 0; j < 2; ++j) {
      const int r = sr0 + j * 64;
      gld_lds16(Bb + (size_t)(n0 + half * 128 + r) * K + koff + ((sc0 ^ (r & 7)) * 8),
                &Bs[buf][half][(tid + j * 512) * 8]);
    }
  };

  f32x4 acc[8][4] = {};
  bf16x8 alo[4][2], ahi[4][2], ba[2][2], bb[2][2];

  auto rdAlo = [&](int d) {
#pragma unroll
    for (int im = 0; im < 4; ++im)
#pragma unroll
      for (int kk = 0; kk < 2; ++kk) {
        const int row = im * 16 + lr;
        alo[im][kk] = *(const bf16x8*)(&As[d][wr][row * 64 + (((kk * 4 + lg) ^ (row & 7)) * 8)]);
      }
  };
  auto rdAhi = [&](int d) {
#pragma unroll
    for (int im = 0; im < 4; ++im)
#pragma unroll
      for (int kk = 0; kk < 2; ++kk) {
        const int row = (4 + im) * 16 + lr;
        ahi[im][kk] = *(const bf16x8*)(&As[d][wr][row * 64 + (((kk * 4 + lg) ^ (row & 7)) * 8)]);
      }
  };
  auto rdBa = [&](int d) {
#pragma unroll
    for (int in = 0; in < 2; ++in)
#pragma unroll
      for (int kk = 0; kk < 2; ++kk) {
        const int row = brow0 + in * 16 + lr;
        ba[in][kk] = *(const bf16x8*)(&Bs[d][bh][row * 64 + (((kk * 4 + lg) ^ (row & 7)) * 8)]);
      }
  };
  auto rdBb = [&](int d) {
#pragma unroll
    for (int in = 0; in < 2; ++in)
#pragma unroll
      for (int kk = 0; kk < 2; ++kk) {
        const int row = brow0 + (2 + in) * 16 + lr;
        bb[in][kk] = *(const bf16x8*)(&Bs[d][bh][row * 64 + (((kk * 4 + lg) ^ (row & 7)) * 8)]);
      }
  };

#define MFMA_Q(MB, NB, AF, BF)                                                     \
  __builtin_amdgcn_s_setprio(1);                                                   \
  _Pragma("unroll") for (int im = 0; im < 4; ++im)                                 \
      _Pragma("unroll") for (int in = 0; in < 2; ++in)                             \
          _Pragma("unroll") for (int kk = 0; kk < 2; ++kk)                         \
              acc[MB + im][NB + in] = __builtin_amdgcn_mfma_f32_16x16x32_bf16(     \
                  AF[im][kk], BF[in][kk], acc[MB + im][NB + in], 0, 0, 0);         \
  __builtin_amdgcn_s_setprio(0);

  stageB(0, 0, 0); stageB(0, 1, 0); stageA(0, 0, 0); stageA(0, 1, 0);
  if (NT > 1) { stageB(1, 0, 1); stageB(1, 1, 1); }
  asm volatile("s_waitcnt vmcnt(4)" ::: "memory");
  __builtin_amdgcn_sched_barrier(0);
  BAR

  for (int t = 0; t < NT2; ++t) {
    const int t1 = 2 * t + 1, t2 = 2 * t + 2, t3 = 2 * t + 3;
    const bool s2 = t2 < NT, s3 = t3 < NT;

    rdAlo(0); rdBa(0);
    stageA(1, 0, t1);
    BAR WAIT_LGKM0
    MFMA_Q(0, 0, alo, ba)
    BAR
    rdBb(0);
    stageA(1, 1, t1);
    BAR WAIT_LGKM0
    MFMA_Q(0, 2, alo, bb)
    BAR
    rdAhi(0);
    if (s2) stageB(0, 0, t2);
    BAR WAIT_LGKM0
    MFMA_Q(4, 2, ahi, bb)
    BAR
    if (s2) stageB(0, 1, t2);
    MFMA_Q(4, 0, ahi, ba)
    if (s2) { asm volatile("s_waitcnt vmcnt(4)" ::: "memory"); }
    else    { asm volatile("s_waitcnt vmcnt(0)" ::: "memory"); }
    __builtin_amdgcn_sched_barrier(0);
    BAR

    rdAlo(1); rdBa(1);
    if (s2) stageA(0, 0, t2);
    BAR WAIT_LGKM0
    MFMA_Q(0, 0, alo, ba)
    BAR
    rdBb(1);
    if (s2) stageA(0, 1, t2);
    BAR WAIT_LGKM0
    MFMA_Q(0, 2, alo, bb)
    BAR
    rdAhi(1);
    if (s3) stageB(1, 0, t3);
    BAR WAIT_LGKM0
    MFMA_Q(4, 2, ahi, bb)
    BAR
    if (s3) stageB(1, 1, t3);
    MFMA_Q(4, 0, ahi, ba)
    if (s3) { asm volatile("s_waitcnt vmcnt(4)" ::: "memory"); }
    else    { asm volatile("s_waitcnt vmcnt(0)" ::: "memory"); }
    __builtin_amdgcn_sched_barrier(0);
    BAR
  }
#undef MFMA_Q

  int z = blockIdx.z;
  float* dst = (z == 0) ? out0 : (z == 1) ? out1 : (z == 2) ? out2 : out3;
#pragma unroll
  for (int mf = 0; mf < 8; ++mf) {
    const int row = m0 + wr * 128 + mf * 16 + lg * 4;
#pragma unroll
    for (int nf = 0; nf < 4; ++nf) {
      const int col = n0 + wc * 64 + nf * 16 + lr;
#pragma unroll
      for (int r = 0; r < 4; ++r) {
        dst[(size_t)(row + r) * N + col] = acc[mf][nf][r];
      }
    }
  }
}
#undef WAIT_LGKM0
#undef BAR

// ---------------- RoPE + scale: q from bf16 qraw, k from f32; pack bf16 [h][t][d] ----
__global__ __launch_bounds__(256) void k_rope(
    const unsigned short* __restrict__ qraw, const float* __restrict__ Kraw,
    const float* __restrict__ sqk,
    unsigned short* __restrict__ qb, unsigned short* __restrict__ kb) {
  const int t = blockIdx.x;
  for (int i = threadIdx.x; i < HH * 64; i += 256) {
    int h = i >> 6, dp = i & 63;
    float theta = expf(-(float)dp * 0.14391156831212787f);
    float ang = (float)t * theta;
    float sn, cs;
    sincosf(ang, &sn, &cs);
    float qr = bf2f(qraw[(size_t)t * CC + h * DD + dp]);
    float qi = bf2f(qraw[(size_t)t * CC + h * DD + dp + 64]);
    const float* kp = Kraw + (size_t)h * TT * DD + (size_t)t * DD;
    float kr = kp[dp], ki = kp[dp + 64];
    float sr = sqk[h * DD + dp];
    float si = sqk[h * DD + dp + 64];
    float qsr = sr * 512.0f, qsi = si * 512.0f;                         // sqrt(C)*sqrt(D)
    float ksr = sr * 45.25483399593904f, ksi = si * 45.25483399593904f; // sqrt(C)
    unsigned short* qo = qb + ((size_t)h * TT + t) * DD;
    unsigned short* ko = kb + ((size_t)h * TT + t) * DD;
    qo[dp]      = f2bf((qr * cs - qi * sn) * qsr);
    qo[dp + 64] = f2bf((qr * sn + qi * cs) * qsi);
    ko[dp]      = f2bf((kr * cs - ki * sn) * ksr);
    ko[dp + 64] = f2bf((kr * sn + ki * cs) * ksi);
  }
}

// ---------------- V transpose: new_v f32 [h][t][d] -> vt bf16 [h][d][t] ----------------
__global__ __launch_bounds__(256) void k_vt(
    const float* __restrict__ Vraw, unsigned short* __restrict__ vt) {
  const int h = blockIdx.z;
  const int t0 = blockIdx.x * 64, d0 = blockIdx.y * 64;
  __shared__ unsigned short tile[64][65];
  const float* vp = Vraw + (size_t)h * TT * DD;
  for (int i = threadIdx.x; i < 4096; i += 256) {
    int r = i >> 6, c = i & 63;
    tile[r][c] = f2bf(vp[(size_t)(t0 + r) * DD + d0 + c]);
  }
  __syncthreads();
  unsigned short* op = vt + (size_t)h * DD * TT;
  for (int i = threadIdx.x; i < 4096; i += 256) {
    int dr = i >> 6, tc = i & 63;
    op[(size_t)(d0 + dr) * TT + t0 + tc] = tile[tc][dr];
  }
}

// ---------------- causal flash attention: mirrored-pair blocks, dbuf KV ----------------
// grid (16 pairs, 16 heads) = 256 uniform blocks (1/CU). 512 thr = 8 waves:
// waves 0-3 -> q-tile gA (64 rows), waves 4-7 -> mirror tile gB=31-gA.
// Per-block MFMA work = (gA+1)+(gB+1) = 33 tile-units for every block (no tail).
// K/V tiles (64 keys) double-buffered: stage t+1 right after tile-t barrier
// (t-1 readers provably done), one vmcnt(0)+barrier per tile -> stage latency
// hides under compute. Output normalized in-kernel, written straight to ob.
__global__ __launch_bounds__(512) void k_attn_pair(
    const unsigned short* __restrict__ qb, const unsigned short* __restrict__ kb,
    const unsigned short* __restrict__ vt, unsigned short* __restrict__ ob) {
  const int gA = blockIdx.x, h = blockIdx.y;
  const int gB = 31 - gA;
  const int ntiles = gB + 1;          // keys [0, 64*(gB+1)) cover both tiles
  const int tid = threadIdx.x;
  const int wid = tid >> 6, lane = tid & 63;
  const int lr = lane & 15, lg = lane >> 4;
  const int gq = (wid >> 2) ? gB : gA;
  const int q0 = gq * 64 + (wid & 3) * 16;

  __shared__ alignas(16) unsigned short Ks[2][64 * 128];
  __shared__ alignas(16) unsigned short Vs[2][128 * 64];
  __shared__ alignas(16) unsigned short P[8][16][72];

  const unsigned short* qh = qb + (size_t)h * TT * DD;
  const unsigned short* kh = kb + (size_t)h * TT * DD;
  const unsigned short* vh = vt + (size_t)h * DD * TT;

  auto stageKV = [&](int buf, int kt) {
    const int k0 = kt * 64;
#pragma unroll
    for (int half = 0; half < 2; ++half) {
      int ch = tid + half * 512;
      int r = ch >> 4, c4 = ch & 15;
      gld_lds16(kh + (size_t)(k0 + r) * DD + ((c4 ^ (r & 7)) * 8), Ks[buf] + ch * 8);
    }
#pragma unroll
    for (int half = 0; half < 2; ++half) {
      int ch = tid + half * 512;
      int d = ch >> 3, c8 = ch & 7;
      gld_lds16(vh + (size_t)d * TT + k0 + ((c8 ^ (d & 7)) * 8), Vs[buf] + ch * 8);
    }
  };

  bf16x8 qf[4];
#pragma unroll
  for (int c = 0; c < 4; ++c)
    qf[c] = *(const bf16x8*)(qh + (size_t)(q0 + lr) * DD + c * 32 + lg * 8);

  f32x4 acc[8] = {};
  float mrow[4] = {-3e38f, -3e38f, -3e38f, -3e38f};
  float lsum[4] = {0.f, 0.f, 0.f, 0.f};

  // prologue: stage tile 0
  stageKV(0, 0);
  asm volatile("s_waitcnt vmcnt(0)" ::: "memory");
  __builtin_amdgcn_sched_barrier(0);
  __builtin_amdgcn_s_barrier();

  for (int kt = 0; kt < ntiles; ++kt) {
    const int cur = kt & 1;
    const int k0 = kt * 64;
    // stage next tile into the other buffer (prev readers of it are done)
    if (kt + 1 < ntiles) stageKV(cur ^ 1, kt + 1);

    if (k0 <= q0 + 15) {
      f32x4 sv[4] = {};
#pragma unroll
      for (int ktile = 0; ktile < 4; ++ktile) {
        const int row = ktile * 16 + lr;
#pragma unroll
        for (int c = 0; c < 4; ++c) {
          int chn = (c * 4 + lg) ^ (lr & 7);
          bf16x8 kf = *(const bf16x8*)(Ks[cur] + row * 128 + chn * 8);
          sv[ktile] = __builtin_amdgcn_mfma_f32_16x16x32_bf16(qf[c], kf, sv[ktile], 0, 0, 0);
        }
      }
      if (k0 + 63 > q0) {
#pragma unroll
        for (int ktile = 0; ktile < 4; ++ktile)
#pragma unroll
          for (int r = 0; r < 4; ++r) {
            int key = k0 + ktile * 16 + lr;
            int qrow = q0 + lg * 4 + r;
            if (key > qrow) sv[ktile][r] = -1e30f;
          }
      }
      float pmax[4];
#pragma unroll
      for (int r = 0; r < 4; ++r)
        pmax[r] = fmaxf(fmaxf(sv[0][r], sv[1][r]), fmaxf(sv[2][r], sv[3][r]));
#pragma unroll
      for (int msk = 1; msk <= 8; msk <<= 1)
#pragma unroll
        for (int r = 0; r < 4; ++r) pmax[r] = fmaxf(pmax[r], __shfl_xor(pmax[r], msk));
      float p[4][4], ps[4], scl[4];
#pragma unroll
      for (int r = 0; r < 4; ++r) {
        float mn = fmaxf(mrow[r], pmax[r]);
        scl[r] = __expf(mrow[r] - mn);
        mrow[r] = mn;
        ps[r] = 0.f;
#pragma unroll
        for (int ktile = 0; ktile < 4; ++ktile) {
          p[ktile][r] = __expf(sv[ktile][r] - mn);
          ps[r] += p[ktile][r];
        }
      }
#pragma unroll
      for (int msk = 1; msk <= 8; msk <<= 1)
#pragma unroll
        for (int r = 0; r < 4; ++r) ps[r] += __shfl_xor(ps[r], msk);
#pragma unroll
      for (int r = 0; r < 4; ++r) lsum[r] = lsum[r] * scl[r] + ps[r];
#pragma unroll
      for (int n = 0; n < 8; ++n)
#pragma unroll
        for (int r = 0; r < 4; ++r) acc[n][r] *= scl[r];
#pragma unroll
      for (int ktile = 0; ktile < 4; ++ktile)
#pragma unroll
        for (int r = 0; r < 4; ++r)
          P[wid][lg * 4 + r][ktile * 16 + lr] = f2bf(p[ktile][r]);
      asm volatile("s_waitcnt lgkmcnt(0)" ::: "memory");
      __builtin_amdgcn_sched_barrier(0);
      bf16x8 pf[2];
#pragma unroll
      for (int ks = 0; ks < 2; ++ks)
        pf[ks] = *(const bf16x8*)(&P[wid][lr][ks * 32 + lg * 8]);
#pragma unroll
      for (int n = 0; n < 8; ++n) {
        const int row = n * 16 + lr;
#pragma unroll
        for (int ks = 0; ks < 2; ++ks) {
          int chn = (ks * 4 + lg) ^ (lr & 7);
          bf16x8 vf = *(const bf16x8*)(Vs[cur] + row * 64 + chn * 8);
          acc[n] = __builtin_amdgcn_mfma_f32_16x16x32_bf16(pf[ks], vf, acc[n], 0, 0, 0);
        }
      }
    }
    // next tile's stage loads done; publish
    asm volatile("s_waitcnt vmcnt(0)" ::: "memory");
    __builtin_amdgcn_sched_barrier(0);
    __builtin_amdgcn_s_barrier();
  }

  float inv[4];
#pragma unroll
  for (int r = 0; r < 4; ++r) inv[r] = 1.0f / lsum[r];
#pragma unroll
  for (int n = 0; n < 8; ++n)
#pragma unroll
    for (int r = 0; r < 4; ++r) {
      int t = q0 + lg * 4 + r;
      ob[(size_t)t * CC + h * DD + n * 16 + lr] = f2bf(acc[n][r] * inv[r]);
    }
}

// ---------------- row l2norm over sum of four split-K partials ----------------
__global__ __launch_bounds__(256) void k_l2norm(
    const float* __restrict__ Of0, const float* __restrict__ Of1,
    const float* __restrict__ Of2, const float* __restrict__ Of3,
    float* __restrict__ out) {
  const int t = blockIdx.x;
  const int tid = threadIdx.x;
  const float4* p0 = (const float4*)(Of0 + (size_t)t * CC);
  const float4* p1 = (const float4*)(Of1 + (size_t)t * CC);
  const float4* p2 = (const float4*)(Of2 + (size_t)t * CC);
  const float4* p3 = (const float4*)(Of3 + (size_t)t * CC);
  float4 a = p0[2 * tid], b = p0[2 * tid + 1];
  float4 a1 = p1[2 * tid], b1 = p1[2 * tid + 1];
  float4 a2 = p2[2 * tid], b2 = p2[2 * tid + 1];
  float4 a3 = p3[2 * tid], b3 = p3[2 * tid + 1];
  a.x += a1.x + a2.x + a3.x; a.y += a1.y + a2.y + a3.y;
  a.z += a1.z + a2.z + a3.z; a.w += a1.w + a2.w + a3.w;
  b.x += b1.x + b2.x + b3.x; b.y += b1.y + b2.y + b3.y;
  b.z += b1.z + b2.z + b3.z; b.w += b1.w + b2.w + b3.w;
  float ss = a.x * a.x + a.y * a.y + a.z * a.z + a.w * a.w +
             b.x * b.x + b.y * b.y + b.z * b.z + b.w * b.w;
#pragma unroll
  for (int msk = 1; msk < 64; msk <<= 1) ss += __shfl_xor(ss, msk);
  __shared__ float red[4];
  if ((tid & 63) == 0) red[tid >> 6] = ss;
  __syncthreads();
  ss = red[0] + red[1] + red[2] + red[3];
  float sc = 1.0f / fmaxf(sqrtf(ss), 1e-12f);
  float4 oa = { a.x * sc, a.y * sc, a.z * sc, a.w * sc };
  float4 obv = { b.x * sc, b.y * sc, b.z * sc, b.w * sc };
  float4* o = (float4*)(out + (size_t)t * CC);
  o[2 * tid] = oa;
  o[2 * tid + 1] = obv;
}

extern "C" void kernel_launch(void* const* d_in, const int* in_sizes, int n_in,
                              void* d_out, int out_size, void* d_ws, size_t ws_size,
                              hipStream_t stream) {
  const float* x   = (const float*)d_in[0];
  const float* wq  = (const float*)d_in[1];
  const float* wk  = (const float*)d_in[2];
  const float* wv  = (const float*)d_in[3];
  const float* wo  = (const float*)d_in[4];
  const float* sqk = (const float*)d_in[5];

  float* out_norm = (float*)d_out;
  float* out_k = out_norm + (size_t)4 * 1024 * 1024;
  float* out_v = out_norm + (size_t)8 * 1024 * 1024;

  char* ws = (char*)d_ws;
  unsigned short* xb  = (unsigned short*)(ws);                      // 0..8MB  (dead after QKV)
  unsigned short* w1b = (unsigned short*)(ws + (8u << 20));         // 8..32MB (dead after QKV)
  unsigned short* wob = (unsigned short*)(ws + (32u << 20));        // 32..40MB
  unsigned short* qb  = (unsigned short*)(ws + (40u << 20));        // 40..48MB (dead after attn)
  unsigned short* kb  = (unsigned short*)(ws + (48u << 20));        // 48..56MB (dead after attn)
  unsigned short* vtb = (unsigned short*)(ws + (56u << 20));        // 56..64MB
  unsigned short* obb = (unsigned short*)(ws + (64u << 20));        // 64..72MB
  unsigned short* qraw = (unsigned short*)(ws + (72u << 20));       // 72..80MB (dead after rope)

  // out-proj split-K=4 partials (xb/w1b/qb/kb/qraw dead during out-proj)
  float* Of0 = (float*)(ws + (72u << 20));  // 72..88MB
  float* Of1 = (float*)(ws);                // 0..16MB
  float* Of2 = (float*)(ws + (16u << 20));  // 16..32MB
  float* Of3 = (float*)(ws + (40u << 20));  // 40..56MB

  // fused converts: one launch, 5 matrices
  k_cvt5<<<dim3(2048, 5), 256, 0, stream>>>(
      x, wq, wk, wv, wo,
      xb, w1b, w1b + (size_t)4 * 1024 * 1024, w1b + (size_t)8 * 1024 * 1024, wob);

  // fused QKV projection: 2048 x 6144 x 2048, 256x192 tiles -> 256 blocks (1/CU)
  k_gemm192<<<dim3(32, 8), 512, 0, stream>>>(xb, w1b, qraw, out_k, out_v);

  k_rope<<<TT, 256, 0, stream>>>(qraw, out_k, sqk, qb, kb);
  k_vt<<<dim3(32, 2, 16), 256, 0, stream>>>(out_v, vtb);

  // attention: mirrored-pair blocks, 256 uniform blocks, direct output
  k_attn_pair<<<dim3(16, 16), 512, 0, stream>>>(qb, kb, vtb, obb);

  // output projection: 2048 x 2048 x 2048, split-K=4 (256 blocks)
  k_gemm8p<<<dim3(8, 8, 4), 512, 0, stream>>>(obb, wob, CC, CC, CC / 4,
                                              Of0, Of1, Of2, Of3);

  k_l2norm<<<TT, 256, 0, stream>>>(Of0, Of1, Of2, Of3, out_norm);
}

// Round 12
// 191.218 us; speedup vs baseline: 1.2304x; 1.0554x over previous
//
#include <hip/hip_runtime.h>

typedef __bf16 bf16x8 __attribute__((ext_vector_type(8)));
typedef float f32x4 __attribute__((ext_vector_type(4)));
typedef unsigned short us4 __attribute__((ext_vector_type(4)));

constexpr int TT = 2048;   // tokens
constexpr int CC = 2048;   // channels
constexpr int HH = 16;     // heads
constexpr int DD = 128;    // head dim

__device__ __forceinline__ unsigned short f2bf(float f) {
  unsigned u = __builtin_bit_cast(unsigned, f);
  u += 0x7FFFu + ((u >> 16) & 1u);
  return (unsigned short)(u >> 16);
}
__device__ __forceinline__ float bf2f(unsigned short b) {
  unsigned u = ((unsigned)b) << 16;
  return __builtin_bit_cast(float, u);
}

// async global->LDS, 16B per lane. C-style casts lower to addrspacecast.
__device__ __forceinline__ void gld_lds16(const unsigned short* g, unsigned short* l) {
  __builtin_amdgcn_global_load_lds(
      (const __attribute__((address_space(1))) unsigned int*)g,
      (__attribute__((address_space(3))) unsigned int*)l,
      16, 0, 0);
}

// ---------------- fused f32 -> bf16 convert (5 matrices, one launch) ----------------
__global__ __launch_bounds__(256) void k_cvt5(
    const float* __restrict__ s0, const float* __restrict__ s1,
    const float* __restrict__ s2, const float* __restrict__ s3,
    const float* __restrict__ s4,
    unsigned short* __restrict__ d0, unsigned short* __restrict__ d1,
    unsigned short* __restrict__ d2, unsigned short* __restrict__ d3,
    unsigned short* __restrict__ d4) {
  const int m = blockIdx.y;
  const float* src = (m == 0) ? s0 : (m == 1) ? s1 : (m == 2) ? s2 : (m == 3) ? s3 : s4;
  unsigned short* dst = (m == 0) ? d0 : (m == 1) ? d1 : (m == 2) ? d2 : (m == 3) ? d3 : d4;
  int i = blockIdx.x * 256 + threadIdx.x;
  const float4* s = (const float4*)src;
  float4 a = s[2 * i], b = s[2 * i + 1];
  us4 lo = { f2bf(a.x), f2bf(a.y), f2bf(a.z), f2bf(a.w) };
  us4 hi = { f2bf(b.x), f2bf(b.y), f2bf(b.z), f2bf(b.w) };
  us4* d = (us4*)dst;
  d[2 * i] = lo;
  d[2 * i + 1] = hi;
}

#define WAIT_LGKM0                                      \
  asm volatile("s_waitcnt lgkmcnt(0)" ::: "memory");    \
  __builtin_amdgcn_sched_barrier(0);
#define BAR __builtin_amdgcn_s_barrier();

// ---------------- QKV GEMM: 256x192 tile, 8-phase, counted vmcnt, 256 blocks ----
// Epilogue: Q -> bf16 qraw; new_k -> f32 (h,t,d); new_v -> f32 (h,t,d) AND
// transposed bf16 vtb [h][d][t] (the 4 acc rows per thread are 4 consecutive
// tokens at fixed (h,d) -> one aligned 8B us4 store). k_vt kernel deleted.
__global__ __launch_bounds__(512, 2) void k_gemm192(
    const unsigned short* __restrict__ A, const unsigned short* __restrict__ B,
    unsigned short* __restrict__ qraw,
    float* __restrict__ outk, float* __restrict__ outv,
    unsigned short* __restrict__ vtb) {
  __shared__ alignas(16) unsigned short As[2][256 * 64];
  __shared__ alignas(16) unsigned short Bs[2][192 * 64];
  const int K = CC, NT = K >> 6, NT2 = NT >> 1;
  const int tid = threadIdx.x;
  const int m0 = blockIdx.y * 256, n0 = blockIdx.x * 192;
  const int wid = tid >> 6, lane = tid & 63;
  const int wr = wid >> 2, wc = wid & 3;
  const int lr = lane & 15, lg = lane >> 4;

  auto stA = [&](int buf, int jb, int tile) {
#pragma unroll
    for (int j = jb; j < jb + 2; ++j) {
      const int ch = tid + j * 512;
      const int r = ch >> 3, c8 = ch & 7;
      gld_lds16(A + (size_t)(m0 + r) * K + tile * 64 + ((c8 ^ (r & 7)) * 8),
                &As[buf][ch * 8]);
    }
  };
  auto stB2 = [&](int buf, int tile) {
#pragma unroll
    for (int j = 0; j < 2; ++j) {
      const int ch = tid + j * 512;
      const int r = ch >> 3, c8 = ch & 7;
      gld_lds16(B + (size_t)(n0 + r) * K + tile * 64 + ((c8 ^ (r & 7)) * 8),
                &Bs[buf][ch * 8]);
    }
  };
  auto stB1 = [&](int buf, int tile) {
    const int ch = tid + 1024;
    const int r = ch >> 3, c8 = ch & 7;
    gld_lds16(B + (size_t)(n0 + r) * K + tile * 64 + ((c8 ^ (r & 7)) * 8),
              &Bs[buf][ch * 8]);
  };

  f32x4 acc[8][3] = {};
  bf16x8 alo[4][2], ahi[4][2], b01[2][2], b2v[2];

  auto rdAlo = [&](int d) {
#pragma unroll
    for (int im = 0; im < 4; ++im)
#pragma unroll
      for (int kk = 0; kk < 2; ++kk) {
        const int row = wr * 128 + im * 16 + lr;
        alo[im][kk] = *(const bf16x8*)(&As[d][row * 64 + (((kk * 4 + lg) ^ (row & 7)) * 8)]);
      }
  };
  auto rdAhi = [&](int d) {
#pragma unroll
    for (int im = 0; im < 4; ++im)
#pragma unroll
      for (int kk = 0; kk < 2; ++kk) {
        const int row = wr * 128 + (4 + im) * 16 + lr;
        ahi[im][kk] = *(const bf16x8*)(&As[d][row * 64 + (((kk * 4 + lg) ^ (row & 7)) * 8)]);
      }
  };
  auto rdB01 = [&](int d) {
#pragma unroll
    for (int in = 0; in < 2; ++in)
#pragma unroll
      for (int kk = 0; kk < 2; ++kk) {
        const int row = wc * 48 + in * 16 + lr;
        b01[in][kk] = *(const bf16x8*)(&Bs[d][row * 64 + (((kk * 4 + lg) ^ (row & 7)) * 8)]);
      }
  };
  auto rdB2 = [&](int d) {
#pragma unroll
    for (int kk = 0; kk < 2; ++kk) {
      const int row = wc * 48 + 32 + lr;
      b2v[kk] = *(const bf16x8*)(&Bs[d][row * 64 + (((kk * 4 + lg) ^ (row & 7)) * 8)]);
    }
  };

  auto q_lo01 = [&]() {
    __builtin_amdgcn_s_setprio(1);
#pragma unroll
    for (int im = 0; im < 4; ++im)
#pragma unroll
      for (int in = 0; in < 2; ++in)
#pragma unroll
        for (int kk = 0; kk < 2; ++kk)
          acc[im][in] = __builtin_amdgcn_mfma_f32_16x16x32_bf16(alo[im][kk], b01[in][kk], acc[im][in], 0, 0, 0);
    __builtin_amdgcn_s_setprio(0);
  };
  auto q_lo2 = [&]() {
    __builtin_amdgcn_s_setprio(1);
#pragma unroll
    for (int im = 0; im < 4; ++im)
#pragma unroll
      for (int kk = 0; kk < 2; ++kk)
        acc[im][2] = __builtin_amdgcn_mfma_f32_16x16x32_bf16(alo[im][kk], b2v[kk], acc[im][2], 0, 0, 0);
    __builtin_amdgcn_s_setprio(0);
  };
  auto q_hi2 = [&]() {
    __builtin_amdgcn_s_setprio(1);
#pragma unroll
    for (int im = 0; im < 4; ++im)
#pragma unroll
      for (int kk = 0; kk < 2; ++kk)
        acc[4 + im][2] = __builtin_amdgcn_mfma_f32_16x16x32_bf16(ahi[im][kk], b2v[kk], acc[4 + im][2], 0, 0, 0);
    __builtin_amdgcn_s_setprio(0);
  };
  auto q_hi01 = [&]() {
    __builtin_amdgcn_s_setprio(1);
#pragma unroll
    for (int im = 0; im < 4; ++im)
#pragma unroll
      for (int in = 0; in < 2; ++in)
#pragma unroll
        for (int kk = 0; kk < 2; ++kk)
          acc[4 + im][in] = __builtin_amdgcn_mfma_f32_16x16x32_bf16(ahi[im][kk], b01[in][kk], acc[4 + im][in], 0, 0, 0);
    __builtin_amdgcn_s_setprio(0);
  };

  stB2(0, 0); stB1(0, 0); stA(0, 0, 0); stA(0, 2, 0);
  stB2(1, 1); stB1(1, 1);
  asm volatile("s_waitcnt vmcnt(3)" ::: "memory");
  __builtin_amdgcn_sched_barrier(0);
  BAR

  for (int t = 0; t < NT2; ++t) {
    const int t1 = 2 * t + 1, t2 = 2 * t + 2, t3 = 2 * t + 3;
    const bool s2 = t2 < NT;

    rdAlo(0); rdB01(0);
    stA(1, 0, t1);
    BAR WAIT_LGKM0
    q_lo01();
    BAR
    rdB2(0);
    stA(1, 2, t1);
    BAR WAIT_LGKM0
    q_lo2();
    BAR
    rdAhi(0);
    if (s2) stB2(0, t2);
    BAR WAIT_LGKM0
    q_hi2();
    BAR
    if (s2) stB1(0, t2);
    q_hi01();
    if (s2) { asm volatile("s_waitcnt vmcnt(3)" ::: "memory"); }
    else    { asm volatile("s_waitcnt vmcnt(0)" ::: "memory"); }
    __builtin_amdgcn_sched_barrier(0);
    BAR

    rdAlo(1); rdB01(1);
    if (s2) stA(0, 0, t2);
    BAR WAIT_LGKM0
    q_lo01();
    BAR
    rdB2(1);
    if (s2) stA(0, 2, t2);
    BAR WAIT_LGKM0
    q_lo2();
    BAR
    rdAhi(1);
    if (s2) stB2(1, t3);
    BAR WAIT_LGKM0
    q_hi2();
    BAR
    if (s2) stB1(1, t3);
    q_hi01();
    if (s2) { asm volatile("s_waitcnt vmcnt(3)" ::: "memory"); }
    else    { asm volatile("s_waitcnt vmcnt(0)" ::: "memory"); }
    __builtin_amdgcn_sched_barrier(0);
    BAR
  }

  // ---- epilogue: Q bf16; K f32 (h,t,d); V f32 (h,t,d) + transposed bf16 vtb ----
#pragma unroll
  for (int mf = 0; mf < 8; ++mf) {
    const int row = m0 + wr * 128 + mf * 16 + lg * 4;
#pragma unroll
    for (int nf = 0; nf < 3; ++nf) {
      const int col = n0 + wc * 48 + nf * 16 + lr;
      if (col < 2048) {
#pragma unroll
        for (int r = 0; r < 4; ++r)
          qraw[(size_t)(row + r) * 2048 + col] = f2bf(acc[mf][nf][r]);
      } else if (col < 4096) {
        const int c = col - 2048;
#pragma unroll
        for (int r = 0; r < 4; ++r)
          outk[(size_t)(c >> 7) * (TT * DD) + (size_t)(row + r) * DD + (c & 127)] = acc[mf][nf][r];
      } else {
        const int c = col - 4096;
        const int hh = c >> 7, d2 = c & 127;
        us4 tv;
#pragma unroll
        for (int r = 0; r < 4; ++r) {
          float v = acc[mf][nf][r];
          outv[(size_t)hh * (TT * DD) + (size_t)(row + r) * DD + d2] = v;
          tv[r] = f2bf(v);
        }
        *(us4*)(vtb + (size_t)hh * (size_t)(DD * TT) + (size_t)d2 * TT + row) = tv;
      }
    }
  }
}

// ---------------- out-proj GEMM: 256x256 8-phase, split-K, bf16 partials ----------------
__global__ __launch_bounds__(512, 2) void k_gemm8p(
    const unsigned short* __restrict__ A, const unsigned short* __restrict__ B,
    int N, int K, int kspan,
    unsigned short* __restrict__ out0, unsigned short* __restrict__ out1,
    unsigned short* __restrict__ out2, unsigned short* __restrict__ out3) {
  __shared__ alignas(16) unsigned short As[2][2][128 * 64];
  __shared__ alignas(16) unsigned short Bs[2][2][128 * 64];
  const int tid = threadIdx.x;
  const int m0 = blockIdx.y * 256, n0 = blockIdx.x * 256;
  const int kbeg = blockIdx.z * kspan;
  const int NT = kspan >> 6, NT2 = NT >> 1;
  const int wid = tid >> 6, lane = tid & 63;
  const int wr = wid >> 2, wc = wid & 3;
  const int lr = lane & 15, lg = lane >> 4;
  const int bh = wc >> 1, brow0 = (wc & 1) * 64;

  const int sr0 = tid >> 3, sc0 = tid & 7;
  const unsigned short* Ab = A + kbeg;
  const unsigned short* Bb = B + kbeg;

  auto stageA = [&](int buf, int half, int tile) {
    const int koff = tile * 64;
#pragma unroll
    for (int j = 0; j < 2; ++j) {
      const int r = sr0 + j * 64;
      gld_lds16(Ab + (size_t)(m0 + half * 128 + r) * K + koff + ((sc0 ^ (r & 7)) * 8),
                &As[buf][half][(tid + j * 512) * 8]);
    }
  };
  auto stageB = [&](int buf, int half, int tile) {
    const int koff = tile * 64;
#pragma unroll
    for (int j = 0; j < 2; ++j) {
      const int r = sr0 + j * 64;
      gld_lds16(Bb + (size_t)(n0 + half * 128 + r) * K + koff + ((sc0 ^ (r & 7)) * 8),
                &Bs[buf][half][(tid + j * 512) * 8]);
    }
  };

  f32x4 acc[8][4] = {};
  bf16x8 alo[4][2], ahi[4][2], ba[2][2], bb[2][2];

  auto rdAlo = [&](int d) {
#pragma unroll
    for (int im = 0; im < 4; ++im)
#pragma unroll
      for (int kk = 0; kk < 2; ++kk) {
        const int row = im * 16 + lr;
        alo[im][kk] = *(const bf16x8*)(&As[d][wr][row * 64 + (((kk * 4 + lg) ^ (row & 7)) * 8)]);
      }
  };
  auto rdAhi = [&](int d) {
#pragma unroll
    for (int im = 0; im < 4; ++im)
#pragma unroll
      for (int kk = 0; kk < 2; ++kk) {
        const int row = (4 + im) * 16 + lr;
        ahi[im][kk] = *(const bf16x8*)(&As[d][wr][row * 64 + (((kk * 4 + lg) ^ (row & 7)) * 8)]);
      }
  };
  auto rdBa = [&](int d) {
#pragma unroll
    for (int in = 0; in < 2; ++in)
#pragma unroll
      for (int kk = 0; kk < 2; ++kk) {
        const int row = brow0 + in * 16 + lr;
        ba[in][kk] = *(const bf16x8*)(&Bs[d][bh][row * 64 + (((kk * 4 + lg) ^ (row & 7)) * 8)]);
      }
  };
  auto rdBb = [&](int d) {
#pragma unroll
    for (int in = 0; in < 2; ++in)
#pragma unroll
      for (int kk = 0; kk < 2; ++kk) {
        const int row = brow0 + (2 + in) * 16 + lr;
        bb[in][kk] = *(const bf16x8*)(&Bs[d][bh][row * 64 + (((kk * 4 + lg) ^ (row & 7)) * 8)]);
      }
  };

#define MFMA_Q(MB, NB, AF, BF)                                                     \
  __builtin_amdgcn_s_setprio(1);                                                   \
  _Pragma("unroll") for (int im = 0; im < 4; ++im)                                 \
      _Pragma("unroll") for (int in = 0; in < 2; ++in)                             \
          _Pragma("unroll") for (int kk = 0; kk < 2; ++kk)                         \
              acc[MB + im][NB + in] = __builtin_amdgcn_mfma_f32_16x16x32_bf16(     \
                  AF[im][kk], BF[in][kk], acc[MB + im][NB + in], 0, 0, 0);         \
  __builtin_amdgcn_s_setprio(0);

  stageB(0, 0, 0); stageB(0, 1, 0); stageA(0, 0, 0); stageA(0, 1, 0);
  if (NT > 1) { stageB(1, 0, 1); stageB(1, 1, 1); }
  asm volatile("s_waitcnt vmcnt(4)" ::: "memory");
  __builtin_amdgcn_sched_barrier(0);
  BAR

  for (int t = 0; t < NT2; ++t) {
    const int t1 = 2 * t + 1, t2 = 2 * t + 2, t3 = 2 * t + 3;
    const bool s2 = t2 < NT, s3 = t3 < NT;

    rdAlo(0); rdBa(0);
    stageA(1, 0, t1);
    BAR WAIT_LGKM0
    MFMA_Q(0, 0, alo, ba)
    BAR
    rdBb(0);
    stageA(1, 1, t1);
    BAR WAIT_LGKM0
    MFMA_Q(0, 2, alo, bb)
    BAR
    rdAhi(0);
    if (s2) stageB(0, 0, t2);
    BAR WAIT_LGKM0
    MFMA_Q(4, 2, ahi, bb)
    BAR
    if (s2) stageB(0, 1, t2);
    MFMA_Q(4, 0, ahi, ba)
    if (s2) { asm volatile("s_waitcnt vmcnt(4)" ::: "memory"); }
    else    { asm volatile("s_waitcnt vmcnt(0)" ::: "memory"); }
    __builtin_amdgcn_sched_barrier(0);
    BAR

    rdAlo(1); rdBa(1);
    if (s2) stageA(0, 0, t2);
    BAR WAIT_LGKM0
    MFMA_Q(0, 0, alo, ba)
    BAR
    rdBb(1);
    if (s2) stageA(0, 1, t2);
    BAR WAIT_LGKM0
    MFMA_Q(0, 2, alo, bb)
    BAR
    rdAhi(1);
    if (s3) stageB(1, 0, t3);
    BAR WAIT_LGKM0
    MFMA_Q(4, 2, ahi, bb)
    BAR
    if (s3) stageB(1, 1, t3);
    MFMA_Q(4, 0, ahi, ba)
    if (s3) { asm volatile("s_waitcnt vmcnt(4)" ::: "memory"); }
    else    { asm volatile("s_waitcnt vmcnt(0)" ::: "memory"); }
    __builtin_amdgcn_sched_barrier(0);
    BAR
  }
#undef MFMA_Q

  int z = blockIdx.z;
  unsigned short* dst = (z == 0) ? out0 : (z == 1) ? out1 : (z == 2) ? out2 : out3;
#pragma unroll
  for (int mf = 0; mf < 8; ++mf) {
    const int row = m0 + wr * 128 + mf * 16 + lg * 4;
#pragma unroll
    for (int nf = 0; nf < 4; ++nf) {
      const int col = n0 + wc * 64 + nf * 16 + lr;
#pragma unroll
      for (int r = 0; r < 4; ++r) {
        dst[(size_t)(row + r) * N + col] = f2bf(acc[mf][nf][r]);
      }
    }
  }
}
#undef WAIT_LGKM0
#undef BAR

// ---------------- RoPE + scale: q from bf16 qraw, k from f32; pack bf16 [h][t][d] ----
__global__ __launch_bounds__(256) void k_rope(
    const unsigned short* __restrict__ qraw, const float* __restrict__ Kraw,
    const float* __restrict__ sqk,
    unsigned short* __restrict__ qb, unsigned short* __restrict__ kb) {
  const int t = blockIdx.x;
  for (int i = threadIdx.x; i < HH * 64; i += 256) {
    int h = i >> 6, dp = i & 63;
    float theta = expf(-(float)dp * 0.14391156831212787f);
    float ang = (float)t * theta;
    float sn, cs;
    sincosf(ang, &sn, &cs);
    float qr = bf2f(qraw[(size_t)t * CC + h * DD + dp]);
    float qi = bf2f(qraw[(size_t)t * CC + h * DD + dp + 64]);
    const float* kp = Kraw + (size_t)h * TT * DD + (size_t)t * DD;
    float kr = kp[dp], ki = kp[dp + 64];
    float sr = sqk[h * DD + dp];
    float si = sqk[h * DD + dp + 64];
    float qsr = sr * 512.0f, qsi = si * 512.0f;                         // sqrt(C)*sqrt(D)
    float ksr = sr * 45.25483399593904f, ksi = si * 45.25483399593904f; // sqrt(C)
    unsigned short* qo = qb + ((size_t)h * TT + t) * DD;
    unsigned short* ko = kb + ((size_t)h * TT + t) * DD;
    qo[dp]      = f2bf((qr * cs - qi * sn) * qsr);
    qo[dp + 64] = f2bf((qr * sn + qi * cs) * qsi);
    ko[dp]      = f2bf((kr * cs - ki * sn) * ksr);
    ko[dp + 64] = f2bf((kr * sn + ki * cs) * ksi);
  }
}

// ---------------- causal flash attention: mirrored-pair blocks, dbuf KV ----------------
__global__ __launch_bounds__(512) void k_attn_pair(
    const unsigned short* __restrict__ qb, const unsigned short* __restrict__ kb,
    const unsigned short* __restrict__ vt, unsigned short* __restrict__ ob) {
  const int gA = blockIdx.x, h = blockIdx.y;
  const int gB = 31 - gA;
  const int ntiles = gB + 1;
  const int tid = threadIdx.x;
  const int wid = tid >> 6, lane = tid & 63;
  const int lr = lane & 15, lg = lane >> 4;
  const int gq = (wid >> 2) ? gB : gA;
  const int q0 = gq * 64 + (wid & 3) * 16;

  __shared__ alignas(16) unsigned short Ks[2][64 * 128];
  __shared__ alignas(16) unsigned short Vs[2][128 * 64];
  __shared__ alignas(16) unsigned short P[8][16][72];

  const unsigned short* qh = qb + (size_t)h * TT * DD;
  const unsigned short* kh = kb + (size_t)h * TT * DD;
  const unsigned short* vh = vt + (size_t)h * DD * TT;

  auto stageKV = [&](int buf, int kt) {
    const int k0 = kt * 64;
#pragma unroll
    for (int half = 0; half < 2; ++half) {
      int ch = tid + half * 512;
      int r = ch >> 4, c4 = ch & 15;
      gld_lds16(kh + (size_t)(k0 + r) * DD + ((c4 ^ (r & 7)) * 8), Ks[buf] + ch * 8);
    }
#pragma unroll
    for (int half = 0; half < 2; ++half) {
      int ch = tid + half * 512;
      int d = ch >> 3, c8 = ch & 7;
      gld_lds16(vh + (size_t)d * TT + k0 + ((c8 ^ (d & 7)) * 8), Vs[buf] + ch * 8);
    }
  };

  bf16x8 qf[4];
#pragma unroll
  for (int c = 0; c < 4; ++c)
    qf[c] = *(const bf16x8*)(qh + (size_t)(q0 + lr) * DD + c * 32 + lg * 8);

  f32x4 acc[8] = {};
  float mrow[4] = {-3e38f, -3e38f, -3e38f, -3e38f};
  float lsum[4] = {0.f, 0.f, 0.f, 0.f};

  stageKV(0, 0);
  asm volatile("s_waitcnt vmcnt(0)" ::: "memory");
  __builtin_amdgcn_sched_barrier(0);
  __builtin_amdgcn_s_barrier();

  for (int kt = 0; kt < ntiles; ++kt) {
    const int cur = kt & 1;
    const int k0 = kt * 64;
    if (kt + 1 < ntiles) stageKV(cur ^ 1, kt + 1);

    if (k0 <= q0 + 15) {
      f32x4 sv[4] = {};
#pragma unroll
      for (int ktile = 0; ktile < 4; ++ktile) {
        const int row = ktile * 16 + lr;
#pragma unroll
        for (int c = 0; c < 4; ++c) {
          int chn = (c * 4 + lg) ^ (lr & 7);
          bf16x8 kf = *(const bf16x8*)(Ks[cur] + row * 128 + chn * 8);
          sv[ktile] = __builtin_amdgcn_mfma_f32_16x16x32_bf16(qf[c], kf, sv[ktile], 0, 0, 0);
        }
      }
      if (k0 + 63 > q0) {
#pragma unroll
        for (int ktile = 0; ktile < 4; ++ktile)
#pragma unroll
          for (int r = 0; r < 4; ++r) {
            int key = k0 + ktile * 16 + lr;
            int qrow = q0 + lg * 4 + r;
            if (key > qrow) sv[ktile][r] = -1e30f;
          }
      }
      float pmax[4];
#pragma unroll
      for (int r = 0; r < 4; ++r)
        pmax[r] = fmaxf(fmaxf(sv[0][r], sv[1][r]), fmaxf(sv[2][r], sv[3][r]));
#pragma unroll
      for (int msk = 1; msk <= 8; msk <<= 1)
#pragma unroll
        for (int r = 0; r < 4; ++r) pmax[r] = fmaxf(pmax[r], __shfl_xor(pmax[r], msk));
      float p[4][4], ps[4], scl[4];
#pragma unroll
      for (int r = 0; r < 4; ++r) {
        float mn = fmaxf(mrow[r], pmax[r]);
        scl[r] = __expf(mrow[r] - mn);
        mrow[r] = mn;
        ps[r] = 0.f;
#pragma unroll
        for (int ktile = 0; ktile < 4; ++ktile) {
          p[ktile][r] = __expf(sv[ktile][r] - mn);
          ps[r] += p[ktile][r];
        }
      }
#pragma unroll
      for (int msk = 1; msk <= 8; msk <<= 1)
#pragma unroll
        for (int r = 0; r < 4; ++r) ps[r] += __shfl_xor(ps[r], msk);
#pragma unroll
      for (int r = 0; r < 4; ++r) lsum[r] = lsum[r] * scl[r] + ps[r];
#pragma unroll
      for (int n = 0; n < 8; ++n)
#pragma unroll
        for (int r = 0; r < 4; ++r) acc[n][r] *= scl[r];
#pragma unroll
      for (int ktile = 0; ktile < 4; ++ktile)
#pragma unroll
        for (int r = 0; r < 4; ++r)
          P[wid][lg * 4 + r][ktile * 16 + lr] = f2bf(p[ktile][r]);
      asm volatile("s_waitcnt lgkmcnt(0)" ::: "memory");
      __builtin_amdgcn_sched_barrier(0);
      bf16x8 pf[2];
#pragma unroll
      for (int ks = 0; ks < 2; ++ks)
        pf[ks] = *(const bf16x8*)(&P[wid][lr][ks * 32 + lg * 8]);
#pragma unroll
      for (int n = 0; n < 8; ++n) {
        const int row = n * 16 + lr;
#pragma unroll
        for (int ks = 0; ks < 2; ++ks) {
          int chn = (ks * 4 + lg) ^ (lr & 7);
          bf16x8 vf = *(const bf16x8*)(Vs[cur] + row * 64 + chn * 8);
          acc[n] = __builtin_amdgcn_mfma_f32_16x16x32_bf16(pf[ks], vf, acc[n], 0, 0, 0);
        }
      }
    }
    asm volatile("s_waitcnt vmcnt(0)" ::: "memory");
    __builtin_amdgcn_sched_barrier(0);
    __builtin_amdgcn_s_barrier();
  }

  float inv[4];
#pragma unroll
  for (int r = 0; r < 4; ++r) inv[r] = 1.0f / lsum[r];
#pragma unroll
  for (int n = 0; n < 8; ++n)
#pragma unroll
    for (int r = 0; r < 4; ++r) {
      int t = q0 + lg * 4 + r;
      ob[(size_t)t * CC + h * DD + n * 16 + lr] = f2bf(acc[n][r] * inv[r]);
    }
}

// ---------------- row l2norm over sum of four bf16 split-K partials ----------------
__global__ __launch_bounds__(256) void k_l2norm(
    const unsigned short* __restrict__ Of0, const unsigned short* __restrict__ Of1,
    const unsigned short* __restrict__ Of2, const unsigned short* __restrict__ Of3,
    float* __restrict__ out) {
  const int t = blockIdx.x;
  const int tid = threadIdx.x;
  const size_t base = (size_t)t * CC + tid * 8;
  bf16x8 a0 = *(const bf16x8*)(Of0 + base);
  bf16x8 a1 = *(const bf16x8*)(Of1 + base);
  bf16x8 a2 = *(const bf16x8*)(Of2 + base);
  bf16x8 a3 = *(const bf16x8*)(Of3 + base);
  float v[8];
  float ss = 0.f;
#pragma unroll
  for (int j = 0; j < 8; ++j) {
    v[j] = (float)a0[j] + (float)a1[j] + (float)a2[j] + (float)a3[j];
    ss += v[j] * v[j];
  }
#pragma unroll
  for (int msk = 1; msk < 64; msk <<= 1) ss += __shfl_xor(ss, msk);
  __shared__ float red[4];
  if ((tid & 63) == 0) red[tid >> 6] = ss;
  __syncthreads();
  ss = red[0] + red[1] + red[2] + red[3];
  float sc = 1.0f / fmaxf(sqrtf(ss), 1e-12f);
  float4 oa = { v[0] * sc, v[1] * sc, v[2] * sc, v[3] * sc };
  float4 obv = { v[4] * sc, v[5] * sc, v[6] * sc, v[7] * sc };
  float4* o = (float4*)(out + base);
  o[0] = oa;
  o[1] = obv;
}

extern "C" void kernel_launch(void* const* d_in, const int* in_sizes, int n_in,
                              void* d_out, int out_size, void* d_ws, size_t ws_size,
                              hipStream_t stream) {
  const float* x   = (const float*)d_in[0];
  const float* wq  = (const float*)d_in[1];
  const float* wk  = (const float*)d_in[2];
  const float* wv  = (const float*)d_in[3];
  const float* wo  = (const float*)d_in[4];
  const float* sqk = (const float*)d_in[5];

  float* out_norm = (float*)d_out;
  float* out_k = out_norm + (size_t)4 * 1024 * 1024;
  float* out_v = out_norm + (size_t)8 * 1024 * 1024;

  char* ws = (char*)d_ws;
  unsigned short* xb  = (unsigned short*)(ws);                      // 0..8MB  (dead after QKV)
  unsigned short* w1b = (unsigned short*)(ws + (8u << 20));         // 8..32MB (dead after QKV)
  unsigned short* wob = (unsigned short*)(ws + (32u << 20));        // 32..40MB
  unsigned short* qb  = (unsigned short*)(ws + (40u << 20));        // 40..48MB (dead after attn)
  unsigned short* kb  = (unsigned short*)(ws + (48u << 20));        // 48..56MB (dead after attn)
  unsigned short* vtb = (unsigned short*)(ws + (56u << 20));        // 56..64MB (dead after attn)
  unsigned short* obb = (unsigned short*)(ws + (64u << 20));        // 64..72MB
  unsigned short* qraw = (unsigned short*)(ws + (72u << 20));       // 72..80MB (dead after rope)

  // out-proj split-K=4 bf16 partials (xb/w1b/qb/qraw dead during out-proj)
  unsigned short* Of0 = (unsigned short*)(ws + (72u << 20));  // 72..80MB
  unsigned short* Of1 = (unsigned short*)(ws);                // 0..8MB
  unsigned short* Of2 = (unsigned short*)(ws + (8u << 20));   // 8..16MB
  unsigned short* Of3 = (unsigned short*)(ws + (16u << 20));  // 16..24MB

  // fused converts: one launch, 5 matrices
  k_cvt5<<<dim3(2048, 5), 256, 0, stream>>>(
      x, wq, wk, wv, wo,
      xb, w1b, w1b + (size_t)4 * 1024 * 1024, w1b + (size_t)8 * 1024 * 1024, wob);

  // fused QKV projection (+ fused V-transpose): 2048 x 6144 x 2048, 256 blocks
  k_gemm192<<<dim3(32, 8), 512, 0, stream>>>(xb, w1b, qraw, out_k, out_v, vtb);

  k_rope<<<TT, 256, 0, stream>>>(qraw, out_k, sqk, qb, kb);

  // attention: mirrored-pair blocks, 256 uniform blocks, direct output
  k_attn_pair<<<dim3(16, 16), 512, 0, stream>>>(qb, kb, vtb, obb);

  // output projection: 2048 x 2048 x 2048, split-K=4 (256 blocks), bf16 partials
  k_gemm8p<<<dim3(8, 8, 4), 512, 0, stream>>>(obb, wob, CC, CC, CC / 4,
                                              Of0, Of1, Of2, Of3);

  k_l2norm<<<TT, 256, 0, stream>>>(Of0, Of1, Of2, Of3, out_norm);
}

// Round 13
// 186.626 us; speedup vs baseline: 1.2607x; 1.0246x over previous
//
#include <hip/hip_runtime.h>

typedef __bf16 bf16x8 __attribute__((ext_vector_type(8)));
typedef float f32x4 __attribute__((ext_vector_type(4)));
typedef unsigned short us4 __attribute__((ext_vector_type(4)));

constexpr int TT = 2048;   // tokens
constexpr int CC = 2048;   // channels
constexpr int HH = 16;     // heads
constexpr int DD = 128;    // head dim

__device__ __forceinline__ unsigned short f2bf(float f) {
  unsigned u = __builtin_bit_cast(unsigned, f);
  u += 0x7FFFu + ((u >> 16) & 1u);
  return (unsigned short)(u >> 16);
}
__device__ __forceinline__ float bf2f(unsigned short b) {
  unsigned u = ((unsigned)b) << 16;
  return __builtin_bit_cast(float, u);
}

// async global->LDS, 16B per lane. C-style casts lower to addrspacecast.
__device__ __forceinline__ void gld_lds16(const unsigned short* g, unsigned short* l) {
  __builtin_amdgcn_global_load_lds(
      (const __attribute__((address_space(1))) unsigned int*)g,
      (__attribute__((address_space(3))) unsigned int*)l,
      16, 0, 0);
}

// ---------------- fused f32 -> bf16 convert (5 matrices, one launch) ----------------
__global__ __launch_bounds__(256) void k_cvt5(
    const float* __restrict__ s0, const float* __restrict__ s1,
    const float* __restrict__ s2, const float* __restrict__ s3,
    const float* __restrict__ s4,
    unsigned short* __restrict__ d0, unsigned short* __restrict__ d1,
    unsigned short* __restrict__ d2, unsigned short* __restrict__ d3,
    unsigned short* __restrict__ d4) {
  const int m = blockIdx.y;
  const float* src = (m == 0) ? s0 : (m == 1) ? s1 : (m == 2) ? s2 : (m == 3) ? s3 : s4;
  unsigned short* dst = (m == 0) ? d0 : (m == 1) ? d1 : (m == 2) ? d2 : (m == 3) ? d3 : d4;
  int i = blockIdx.x * 256 + threadIdx.x;
  const float4* s = (const float4*)src;
  float4 a = s[2 * i], b = s[2 * i + 1];
  us4 lo = { f2bf(a.x), f2bf(a.y), f2bf(a.z), f2bf(a.w) };
  us4 hi = { f2bf(b.x), f2bf(b.y), f2bf(b.z), f2bf(b.w) };
  us4* d = (us4*)dst;
  d[2 * i] = lo;
  d[2 * i + 1] = hi;
}

#define WAIT_LGKM0                                      \
  asm volatile("s_waitcnt lgkmcnt(0)" ::: "memory");    \
  __builtin_amdgcn_sched_barrier(0);
#define BAR __builtin_amdgcn_s_barrier();

// ---------------- QKV GEMM: 256x192 tile, 3 phases/tile (16 MFMA each) ----------------
// Ledger (per 2-tile iter): evenP1 st A(t1)x2, evenP2 st A(t1)x2, evenP3 st B(t2)x3
// -> vmcnt(3) forces t1; odd mirror (A(t2), B(t3)) -> vmcnt(3) forces t2. Tails vmcnt(0).
__global__ __launch_bounds__(512, 2) void k_gemm192(
    const unsigned short* __restrict__ A, const unsigned short* __restrict__ B,
    unsigned short* __restrict__ qraw,
    float* __restrict__ outk, float* __restrict__ outv,
    unsigned short* __restrict__ vtb) {
  __shared__ alignas(16) unsigned short As[2][256 * 64];
  __shared__ alignas(16) unsigned short Bs[2][192 * 64];
  const int K = CC, NT = K >> 6, NT2 = NT >> 1;
  const int tid = threadIdx.x;
  const int m0 = blockIdx.y * 256, n0 = blockIdx.x * 192;
  const int wid = tid >> 6, lane = tid & 63;
  const int wr = wid >> 2, wc = wid & 3;
  const int lr = lane & 15, lg = lane >> 4;

  auto stA = [&](int buf, int jb, int tile) {
#pragma unroll
    for (int j = jb; j < jb + 2; ++j) {
      const int ch = tid + j * 512;
      const int r = ch >> 3, c8 = ch & 7;
      gld_lds16(A + (size_t)(m0 + r) * K + tile * 64 + ((c8 ^ (r & 7)) * 8),
                &As[buf][ch * 8]);
    }
  };
  auto stB2 = [&](int buf, int tile) {
#pragma unroll
    for (int j = 0; j < 2; ++j) {
      const int ch = tid + j * 512;
      const int r = ch >> 3, c8 = ch & 7;
      gld_lds16(B + (size_t)(n0 + r) * K + tile * 64 + ((c8 ^ (r & 7)) * 8),
                &Bs[buf][ch * 8]);
    }
  };
  auto stB1 = [&](int buf, int tile) {
    const int ch = tid + 1024;
    const int r = ch >> 3, c8 = ch & 7;
    gld_lds16(B + (size_t)(n0 + r) * K + tile * 64 + ((c8 ^ (r & 7)) * 8),
              &Bs[buf][ch * 8]);
  };

  f32x4 acc[8][3] = {};
  bf16x8 alo[4][2], ahi[4][2], b01[2][2], b2v[2];

  auto rdAlo = [&](int d) {
#pragma unroll
    for (int im = 0; im < 4; ++im)
#pragma unroll
      for (int kk = 0; kk < 2; ++kk) {
        const int row = wr * 128 + im * 16 + lr;
        alo[im][kk] = *(const bf16x8*)(&As[d][row * 64 + (((kk * 4 + lg) ^ (row & 7)) * 8)]);
      }
  };
  auto rdAhi = [&](int d) {
#pragma unroll
    for (int im = 0; im < 4; ++im)
#pragma unroll
      for (int kk = 0; kk < 2; ++kk) {
        const int row = wr * 128 + (4 + im) * 16 + lr;
        ahi[im][kk] = *(const bf16x8*)(&As[d][row * 64 + (((kk * 4 + lg) ^ (row & 7)) * 8)]);
      }
  };
  auto rdB01 = [&](int d) {
#pragma unroll
    for (int in = 0; in < 2; ++in)
#pragma unroll
      for (int kk = 0; kk < 2; ++kk) {
        const int row = wc * 48 + in * 16 + lr;
        b01[in][kk] = *(const bf16x8*)(&Bs[d][row * 64 + (((kk * 4 + lg) ^ (row & 7)) * 8)]);
      }
  };
  auto rdB2 = [&](int d) {
#pragma unroll
    for (int kk = 0; kk < 2; ++kk) {
      const int row = wc * 48 + 32 + lr;
      b2v[kk] = *(const bf16x8*)(&Bs[d][row * 64 + (((kk * 4 + lg) ^ (row & 7)) * 8)]);
    }
  };

  auto q_lo01 = [&]() {  // 16 MFMA
    __builtin_amdgcn_s_setprio(1);
#pragma unroll
    for (int im = 0; im < 4; ++im)
#pragma unroll
      for (int in = 0; in < 2; ++in)
#pragma unroll
        for (int kk = 0; kk < 2; ++kk)
          acc[im][in] = __builtin_amdgcn_mfma_f32_16x16x32_bf16(alo[im][kk], b01[in][kk], acc[im][in], 0, 0, 0);
    __builtin_amdgcn_s_setprio(0);
  };
  auto q_mid16 = [&]() {  // 16 MFMA: lo x b2 + hi x b2
    __builtin_amdgcn_s_setprio(1);
#pragma unroll
    for (int im = 0; im < 4; ++im)
#pragma unroll
      for (int kk = 0; kk < 2; ++kk)
        acc[im][2] = __builtin_amdgcn_mfma_f32_16x16x32_bf16(alo[im][kk], b2v[kk], acc[im][2], 0, 0, 0);
#pragma unroll
    for (int im = 0; im < 4; ++im)
#pragma unroll
      for (int kk = 0; kk < 2; ++kk)
        acc[4 + im][2] = __builtin_amdgcn_mfma_f32_16x16x32_bf16(ahi[im][kk], b2v[kk], acc[4 + im][2], 0, 0, 0);
    __builtin_amdgcn_s_setprio(0);
  };
  auto q_hi01 = [&]() {  // 16 MFMA
    __builtin_amdgcn_s_setprio(1);
#pragma unroll
    for (int im = 0; im < 4; ++im)
#pragma unroll
      for (int in = 0; in < 2; ++in)
#pragma unroll
        for (int kk = 0; kk < 2; ++kk)
          acc[4 + im][in] = __builtin_amdgcn_mfma_f32_16x16x32_bf16(ahi[im][kk], b01[in][kk], acc[4 + im][in], 0, 0, 0);
    __builtin_amdgcn_s_setprio(0);
  };

  // prologue: tile0 (7 loads) + B(t1) (3 loads); vmcnt(3) forces tile0
  stB2(0, 0); stB1(0, 0); stA(0, 0, 0); stA(0, 2, 0);
  stB2(1, 1); stB1(1, 1);
  asm volatile("s_waitcnt vmcnt(3)" ::: "memory");
  __builtin_amdgcn_sched_barrier(0);
  BAR

  for (int t = 0; t < NT2; ++t) {
    const int t1 = 2 * t + 1, t2 = 2 * t + 2, t3 = 2 * t + 3;
    const bool s2 = t2 < NT;  // NT even => covers t3 too

    // ===== even tile (d0) =====
    rdAlo(0); rdB01(0);
    stA(1, 0, t1);
    BAR WAIT_LGKM0
    q_lo01();
    BAR
    rdB2(0); rdAhi(0);
    stA(1, 2, t1);
    BAR WAIT_LGKM0
    q_mid16();
    BAR
    if (s2) { stB2(0, t2); stB1(0, t2); }
    q_hi01();
    if (s2) { asm volatile("s_waitcnt vmcnt(3)" ::: "memory"); }
    else    { asm volatile("s_waitcnt vmcnt(0)" ::: "memory"); }
    __builtin_amdgcn_sched_barrier(0);
    BAR

    // ===== odd tile (d1) =====
    rdAlo(1); rdB01(1);
    if (s2) stA(0, 0, t2);
    BAR WAIT_LGKM0
    q_lo01();
    BAR
    rdB2(1); rdAhi(1);
    if (s2) stA(0, 2, t2);
    BAR WAIT_LGKM0
    q_mid16();
    BAR
    if (s2) { stB2(1, t3); stB1(1, t3); }
    q_hi01();
    if (s2) { asm volatile("s_waitcnt vmcnt(3)" ::: "memory"); }
    else    { asm volatile("s_waitcnt vmcnt(0)" ::: "memory"); }
    __builtin_amdgcn_sched_barrier(0);
    BAR
  }

  // ---- epilogue: Q bf16; K f32 (h,t,d); V f32 (h,t,d) + transposed bf16 vtb ----
#pragma unroll
  for (int mf = 0; mf < 8; ++mf) {
    const int row = m0 + wr * 128 + mf * 16 + lg * 4;
#pragma unroll
    for (int nf = 0; nf < 3; ++nf) {
      const int col = n0 + wc * 48 + nf * 16 + lr;
      if (col < 2048) {
#pragma unroll
        for (int r = 0; r < 4; ++r)
          qraw[(size_t)(row + r) * 2048 + col] = f2bf(acc[mf][nf][r]);
      } else if (col < 4096) {
        const int c = col - 2048;
#pragma unroll
        for (int r = 0; r < 4; ++r)
          outk[(size_t)(c >> 7) * (TT * DD) + (size_t)(row + r) * DD + (c & 127)] = acc[mf][nf][r];
      } else {
        const int c = col - 4096;
        const int hh = c >> 7, d2 = c & 127;
        us4 tv;
#pragma unroll
        for (int r = 0; r < 4; ++r) {
          float v = acc[mf][nf][r];
          outv[(size_t)hh * (TT * DD) + (size_t)(row + r) * DD + d2] = v;
          tv[r] = f2bf(v);
        }
        *(us4*)(vtb + (size_t)hh * (size_t)(DD * TT) + (size_t)d2 * TT + row) = tv;
      }
    }
  }
}

// ---------------- out-proj GEMM: 256x256, 3 phases/tile, split-K, bf16 partials ----
__global__ __launch_bounds__(512, 2) void k_gemm8p(
    const unsigned short* __restrict__ A, const unsigned short* __restrict__ B,
    int N, int K, int kspan,
    unsigned short* __restrict__ out0, unsigned short* __restrict__ out1,
    unsigned short* __restrict__ out2, unsigned short* __restrict__ out3) {
  __shared__ alignas(16) unsigned short As[2][2][128 * 64];
  __shared__ alignas(16) unsigned short Bs[2][2][128 * 64];
  const int tid = threadIdx.x;
  const int m0 = blockIdx.y * 256, n0 = blockIdx.x * 256;
  const int kbeg = blockIdx.z * kspan;
  const int NT = kspan >> 6, NT2 = NT >> 1;
  const int wid = tid >> 6, lane = tid & 63;
  const int wr = wid >> 2, wc = wid & 3;
  const int lr = lane & 15, lg = lane >> 4;
  const int bh = wc >> 1, brow0 = (wc & 1) * 64;

  const int sr0 = tid >> 3, sc0 = tid & 7;
  const unsigned short* Ab = A + kbeg;
  const unsigned short* Bb = B + kbeg;

  auto stageA = [&](int buf, int half, int tile) {
    const int koff = tile * 64;
#pragma unroll
    for (int j = 0; j < 2; ++j) {
      const int r = sr0 + j * 64;
      gld_lds16(Ab + (size_t)(m0 + half * 128 + r) * K + koff + ((sc0 ^ (r & 7)) * 8),
                &As[buf][half][(tid + j * 512) * 8]);
    }
  };
  auto stageB = [&](int buf, int half, int tile) {
    const int koff = tile * 64;
#pragma unroll
    for (int j = 0; j < 2; ++j) {
      const int r = sr0 + j * 64;
      gld_lds16(Bb + (size_t)(n0 + half * 128 + r) * K + koff + ((sc0 ^ (r & 7)) * 8),
                &Bs[buf][half][(tid + j * 512) * 8]);
    }
  };

  f32x4 acc[8][4] = {};
  bf16x8 alo[4][2], ahi[4][2], ba[2][2], bb[2][2];

  auto rdAlo = [&](int d) {
#pragma unroll
    for (int im = 0; im < 4; ++im)
#pragma unroll
      for (int kk = 0; kk < 2; ++kk) {
        const int row = im * 16 + lr;
        alo[im][kk] = *(const bf16x8*)(&As[d][wr][row * 64 + (((kk * 4 + lg) ^ (row & 7)) * 8)]);
      }
  };
  auto rdAhi = [&](int d) {
#pragma unroll
    for (int im = 0; im < 4; ++im)
#pragma unroll
      for (int kk = 0; kk < 2; ++kk) {
        const int row = (4 + im) * 16 + lr;
        ahi[im][kk] = *(const bf16x8*)(&As[d][wr][row * 64 + (((kk * 4 + lg) ^ (row & 7)) * 8)]);
      }
  };
  auto rdBa = [&](int d) {
#pragma unroll
    for (int in = 0; in < 2; ++in)
#pragma unroll
      for (int kk = 0; kk < 2; ++kk) {
        const int row = brow0 + in * 16 + lr;
        ba[in][kk] = *(const bf16x8*)(&Bs[d][bh][row * 64 + (((kk * 4 + lg) ^ (row & 7)) * 8)]);
      }
  };
  auto rdBb = [&](int d) {
#pragma unroll
    for (int in = 0; in < 2; ++in)
#pragma unroll
      for (int kk = 0; kk < 2; ++kk) {
        const int row = brow0 + (2 + in) * 16 + lr;
        bb[in][kk] = *(const bf16x8*)(&Bs[d][bh][row * 64 + (((kk * 4 + lg) ^ (row & 7)) * 8)]);
      }
  };

#define MFMA_Q(MB, NB, AF, BF)                                                     \
  _Pragma("unroll") for (int im = 0; im < 4; ++im)                                 \
      _Pragma("unroll") for (int in = 0; in < 2; ++in)                             \
          _Pragma("unroll") for (int kk = 0; kk < 2; ++kk)                         \
              acc[MB + im][NB + in] = __builtin_amdgcn_mfma_f32_16x16x32_bf16(     \
                  AF[im][kk], BF[in][kk], acc[MB + im][NB + in], 0, 0, 0);

  stageB(0, 0, 0); stageB(0, 1, 0); stageA(0, 0, 0); stageA(0, 1, 0);
  if (NT > 1) { stageB(1, 0, 1); stageB(1, 1, 1); }
  asm volatile("s_waitcnt vmcnt(4)" ::: "memory");
  __builtin_amdgcn_sched_barrier(0);
  BAR

  for (int t = 0; t < NT2; ++t) {
    const int t1 = 2 * t + 1, t2 = 2 * t + 2, t3 = 2 * t + 3;
    const bool s2 = t2 < NT, s3 = t3 < NT;

    // ===== even tile (d0): P1 {rd alo,ba,bb; st A(t1) both halves; 32 MFMA} =====
    rdAlo(0); rdBa(0); rdBb(0);
    stageA(1, 0, t1); stageA(1, 1, t1);
    BAR WAIT_LGKM0
    __builtin_amdgcn_s_setprio(1);
    MFMA_Q(0, 0, alo, ba)
    MFMA_Q(0, 2, alo, bb)
    __builtin_amdgcn_s_setprio(0);
    BAR
    // P2 {rd ahi; st B(t2) h0; 16 MFMA}
    rdAhi(0);
    if (s2) stageB(0, 0, t2);
    BAR WAIT_LGKM0
    __builtin_amdgcn_s_setprio(1);
    MFMA_Q(4, 2, ahi, bb)
    __builtin_amdgcn_s_setprio(0);
    BAR
    // P3 {st B(t2) h1; 16 MFMA; vmcnt forces t1}
    if (s2) stageB(0, 1, t2);
    __builtin_amdgcn_s_setprio(1);
    MFMA_Q(4, 0, ahi, ba)
    __builtin_amdgcn_s_setprio(0);
    if (s2) { asm volatile("s_waitcnt vmcnt(4)" ::: "memory"); }
    else    { asm volatile("s_waitcnt vmcnt(0)" ::: "memory"); }
    __builtin_amdgcn_sched_barrier(0);
    BAR

    // ===== odd tile (d1) =====
    rdAlo(1); rdBa(1); rdBb(1);
    if (s2) { stageA(0, 0, t2); stageA(0, 1, t2); }
    BAR WAIT_LGKM0
    __builtin_amdgcn_s_setprio(1);
    MFMA_Q(0, 0, alo, ba)
    MFMA_Q(0, 2, alo, bb)
    __builtin_amdgcn_s_setprio(0);
    BAR
    rdAhi(1);
    if (s3) stageB(1, 0, t3);
    BAR WAIT_LGKM0
    __builtin_amdgcn_s_setprio(1);
    MFMA_Q(4, 2, ahi, bb)
    __builtin_amdgcn_s_setprio(0);
    BAR
    if (s3) stageB(1, 1, t3);
    __builtin_amdgcn_s_setprio(1);
    MFMA_Q(4, 0, ahi, ba)
    __builtin_amdgcn_s_setprio(0);
    if (s3) { asm volatile("s_waitcnt vmcnt(4)" ::: "memory"); }
    else    { asm volatile("s_waitcnt vmcnt(0)" ::: "memory"); }
    __builtin_amdgcn_sched_barrier(0);
    BAR
  }
#undef MFMA_Q

  int z = blockIdx.z;
  unsigned short* dst = (z == 0) ? out0 : (z == 1) ? out1 : (z == 2) ? out2 : out3;
#pragma unroll
  for (int mf = 0; mf < 8; ++mf) {
    const int row = m0 + wr * 128 + mf * 16 + lg * 4;
#pragma unroll
    for (int nf = 0; nf < 4; ++nf) {
      const int col = n0 + wc * 64 + nf * 16 + lr;
#pragma unroll
      for (int r = 0; r < 4; ++r) {
        dst[(size_t)(row + r) * N + col] = f2bf(acc[mf][nf][r]);
      }
    }
  }
}
#undef WAIT_LGKM0
#undef BAR

// ---------------- RoPE + scale: shared sincos table (16 heads share angles) ----------
__global__ __launch_bounds__(256) void k_rope(
    const unsigned short* __restrict__ qraw, const float* __restrict__ Kraw,
    const float* __restrict__ sqk,
    unsigned short* __restrict__ qb, unsigned short* __restrict__ kb) {
  const int t = blockIdx.x;
  __shared__ float sn_s[64], cs_s[64];
  if (threadIdx.x < 64) {
    float theta = expf(-(float)threadIdx.x * 0.14391156831212787f);
    float sn, cs;
    sincosf((float)t * theta, &sn, &cs);
    sn_s[threadIdx.x] = sn;
    cs_s[threadIdx.x] = cs;
  }
  __syncthreads();
  for (int i = threadIdx.x; i < HH * 64; i += 256) {
    int h = i >> 6, dp = i & 63;
    float sn = sn_s[dp], cs = cs_s[dp];
    float qr = bf2f(qraw[(size_t)t * CC + h * DD + dp]);
    float qi = bf2f(qraw[(size_t)t * CC + h * DD + dp + 64]);
    const float* kp = Kraw + (size_t)h * TT * DD + (size_t)t * DD;
    float kr = kp[dp], ki = kp[dp + 64];
    float sr = sqk[h * DD + dp];
    float si = sqk[h * DD + dp + 64];
    float qsr = sr * 512.0f, qsi = si * 512.0f;                         // sqrt(C)*sqrt(D)
    float ksr = sr * 45.25483399593904f, ksi = si * 45.25483399593904f; // sqrt(C)
    unsigned short* qo = qb + ((size_t)h * TT + t) * DD;
    unsigned short* ko = kb + ((size_t)h * TT + t) * DD;
    qo[dp]      = f2bf((qr * cs - qi * sn) * qsr);
    qo[dp + 64] = f2bf((qr * sn + qi * cs) * qsi);
    ko[dp]      = f2bf((kr * cs - ki * sn) * ksr);
    ko[dp + 64] = f2bf((kr * sn + ki * cs) * ksi);
  }
}

// ---------------- causal flash attention: mirrored-pair blocks, dbuf KV ----------------
__global__ __launch_bounds__(512) void k_attn_pair(
    const unsigned short* __restrict__ qb, const unsigned short* __restrict__ kb,
    const unsigned short* __restrict__ vt, unsigned short* __restrict__ ob) {
  const int gA = blockIdx.x, h = blockIdx.y;
  const int gB = 31 - gA;
  const int ntiles = gB + 1;
  const int tid = threadIdx.x;
  const int wid = tid >> 6, lane = tid & 63;
  const int lr = lane & 15, lg = lane >> 4;
  const int gq = (wid >> 2) ? gB : gA;
  const int q0 = gq * 64 + (wid & 3) * 16;

  __shared__ alignas(16) unsigned short Ks[2][64 * 128];
  __shared__ alignas(16) unsigned short Vs[2][128 * 64];
  __shared__ alignas(16) unsigned short P[8][16][72];

  const unsigned short* qh = qb + (size_t)h * TT * DD;
  const unsigned short* kh = kb + (size_t)h * TT * DD;
  const unsigned short* vh = vt + (size_t)h * DD * TT;

  auto stageKV = [&](int buf, int kt) {
    const int k0 = kt * 64;
#pragma unroll
    for (int half = 0; half < 2; ++half) {
      int ch = tid + half * 512;
      int r = ch >> 4, c4 = ch & 15;
      gld_lds16(kh + (size_t)(k0 + r) * DD + ((c4 ^ (r & 7)) * 8), Ks[buf] + ch * 8);
    }
#pragma unroll
    for (int half = 0; half < 2; ++half) {
      int ch = tid + half * 512;
      int d = ch >> 3, c8 = ch & 7;
      gld_lds16(vh + (size_t)d * TT + k0 + ((c8 ^ (d & 7)) * 8), Vs[buf] + ch * 8);
    }
  };

  bf16x8 qf[4];
#pragma unroll
  for (int c = 0; c < 4; ++c)
    qf[c] = *(const bf16x8*)(qh + (size_t)(q0 + lr) * DD + c * 32 + lg * 8);

  f32x4 acc[8] = {};
  float mrow[4] = {-3e38f, -3e38f, -3e38f, -3e38f};
  float lsum[4] = {0.f, 0.f, 0.f, 0.f};

  stageKV(0, 0);
  asm volatile("s_waitcnt vmcnt(0)" ::: "memory");
  __builtin_amdgcn_sched_barrier(0);
  __builtin_amdgcn_s_barrier();

  for (int kt = 0; kt < ntiles; ++kt) {
    const int cur = kt & 1;
    const int k0 = kt * 64;
    if (kt + 1 < ntiles) stageKV(cur ^ 1, kt + 1);

    if (k0 <= q0 + 15) {
      f32x4 sv[4] = {};
#pragma unroll
      for (int ktile = 0; ktile < 4; ++ktile) {
        const int row = ktile * 16 + lr;
#pragma unroll
        for (int c = 0; c < 4; ++c) {
          int chn = (c * 4 + lg) ^ (lr & 7);
          bf16x8 kf = *(const bf16x8*)(Ks[cur] + row * 128 + chn * 8);
          sv[ktile] = __builtin_amdgcn_mfma_f32_16x16x32_bf16(qf[c], kf, sv[ktile], 0, 0, 0);
        }
      }
      if (k0 + 63 > q0) {
#pragma unroll
        for (int ktile = 0; ktile < 4; ++ktile)
#pragma unroll
          for (int r = 0; r < 4; ++r) {
            int key = k0 + ktile * 16 + lr;
            int qrow = q0 + lg * 4 + r;
            if (key > qrow) sv[ktile][r] = -1e30f;
          }
      }
      float pmax[4];
#pragma unroll
      for (int r = 0; r < 4; ++r)
        pmax[r] = fmaxf(fmaxf(sv[0][r], sv[1][r]), fmaxf(sv[2][r], sv[3][r]));
#pragma unroll
      for (int msk = 1; msk <= 8; msk <<= 1)
#pragma unroll
        for (int r = 0; r < 4; ++r) pmax[r] = fmaxf(pmax[r], __shfl_xor(pmax[r], msk));
      float p[4][4], ps[4], scl[4];
#pragma unroll
      for (int r = 0; r < 4; ++r) {
        float mn = fmaxf(mrow[r], pmax[r]);
        scl[r] = __expf(mrow[r] - mn);
        mrow[r] = mn;
        ps[r] = 0.f;
#pragma unroll
        for (int ktile = 0; ktile < 4; ++ktile) {
          p[ktile][r] = __expf(sv[ktile][r] - mn);
          ps[r] += p[ktile][r];
        }
      }
#pragma unroll
      for (int msk = 1; msk <= 8; msk <<= 1)
#pragma unroll
        for (int r = 0; r < 4; ++r) ps[r] += __shfl_xor(ps[r], msk);
#pragma unroll
      for (int r = 0; r < 4; ++r) lsum[r] = lsum[r] * scl[r] + ps[r];
#pragma unroll
      for (int n = 0; n < 8; ++n)
#pragma unroll
        for (int r = 0; r < 4; ++r) acc[n][r] *= scl[r];
#pragma unroll
      for (int ktile = 0; ktile < 4; ++ktile)
#pragma unroll
        for (int r = 0; r < 4; ++r)
          P[wid][lg * 4 + r][ktile * 16 + lr] = f2bf(p[ktile][r]);
      asm volatile("s_waitcnt lgkmcnt(0)" ::: "memory");
      __builtin_amdgcn_sched_barrier(0);
      bf16x8 pf[2];
#pragma unroll
      for (int ks = 0; ks < 2; ++ks)
        pf[ks] = *(const bf16x8*)(&P[wid][lr][ks * 32 + lg * 8]);
#pragma unroll
      for (int n = 0; n < 8; ++n) {
        const int row = n * 16 + lr;
#pragma unroll
        for (int ks = 0; ks < 2; ++ks) {
          int chn = (ks * 4 + lg) ^ (lr & 7);
          bf16x8 vf = *(const bf16x8*)(Vs[cur] + row * 64 + chn * 8);
          acc[n] = __builtin_amdgcn_mfma_f32_16x16x32_bf16(pf[ks], vf, acc[n], 0, 0, 0);
        }
      }
    }
    asm volatile("s_waitcnt vmcnt(0)" ::: "memory");
    __builtin_amdgcn_sched_barrier(0);
    __builtin_amdgcn_s_barrier();
  }

  float inv[4];
#pragma unroll
  for (int r = 0; r < 4; ++r) inv[r] = 1.0f / lsum[r];
#pragma unroll
  for (int n = 0; n < 8; ++n)
#pragma unroll
    for (int r = 0; r < 4; ++r) {
      int t = q0 + lg * 4 + r;
      ob[(size_t)t * CC + h * DD + n * 16 + lr] = f2bf(acc[n][r] * inv[r]);
    }
}

// ---------------- row l2norm over sum of four bf16 split-K partials ----------------
__global__ __launch_bounds__(256) void k_l2norm(
    const unsigned short* __restrict__ Of0, const unsigned short* __restrict__ Of1,
    const unsigned short* __restrict__ Of2, const unsigned short* __restrict__ Of3,
    float* __restrict__ out) {
  const int t = blockIdx.x;
  const int tid = threadIdx.x;
  const size_t base = (size_t)t * CC + tid * 8;
  bf16x8 a0 = *(const bf16x8*)(Of0 + base);
  bf16x8 a1 = *(const bf16x8*)(Of1 + base);
  bf16x8 a2 = *(const bf16x8*)(Of2 + base);
  bf16x8 a3 = *(const bf16x8*)(Of3 + base);
  float v[8];
  float ss = 0.f;
#pragma unroll
  for (int j = 0; j < 8; ++j) {
    v[j] = (float)a0[j] + (float)a1[j] + (float)a2[j] + (float)a3[j];
    ss += v[j] * v[j];
  }
#pragma unroll
  for (int msk = 1; msk < 64; msk <<= 1) ss += __shfl_xor(ss, msk);
  __shared__ float red[4];
  if ((tid & 63) == 0) red[tid >> 6] = ss;
  __syncthreads();
  ss = red[0] + red[1] + red[2] + red[3];
  float sc = 1.0f / fmaxf(sqrtf(ss), 1e-12f);
  float4 oa = { v[0] * sc, v[1] * sc, v[2] * sc, v[3] * sc };
  float4 obv = { v[4] * sc, v[5] * sc, v[6] * sc, v[7] * sc };
  float4* o = (float4*)(out + base);
  o[0] = oa;
  o[1] = obv;
}

extern "C" void kernel_launch(void* const* d_in, const int* in_sizes, int n_in,
                              void* d_out, int out_size, void* d_ws, size_t ws_size,
                              hipStream_t stream) {
  const float* x   = (const float*)d_in[0];
  const float* wq  = (const float*)d_in[1];
  const float* wk  = (const float*)d_in[2];
  const float* wv  = (const float*)d_in[3];
  const float* wo  = (const float*)d_in[4];
  const float* sqk = (const float*)d_in[5];

  float* out_norm = (float*)d_out;
  float* out_k = out_norm + (size_t)4 * 1024 * 1024;
  float* out_v = out_norm + (size_t)8 * 1024 * 1024;

  char* ws = (char*)d_ws;
  unsigned short* xb  = (unsigned short*)(ws);                      // 0..8MB  (dead after QKV)
  unsigned short* w1b = (unsigned short*)(ws + (8u << 20));         // 8..32MB (dead after QKV)
  unsigned short* wob = (unsigned short*)(ws + (32u << 20));        // 32..40MB
  unsigned short* qb  = (unsigned short*)(ws + (40u << 20));        // 40..48MB (dead after attn)
  unsigned short* kb  = (unsigned short*)(ws + (48u << 20));        // 48..56MB (dead after attn)
  unsigned short* vtb = (unsigned short*)(ws + (56u << 20));        // 56..64MB (dead after attn)
  unsigned short* obb = (unsigned short*)(ws + (64u << 20));        // 64..72MB
  unsigned short* qraw = (unsigned short*)(ws + (72u << 20));       // 72..80MB (dead after rope)

  // out-proj split-K=4 bf16 partials (xb/w1b/qb/qraw dead during out-proj)
  unsigned short* Of0 = (unsigned short*)(ws + (72u << 20));  // 72..80MB
  unsigned short* Of1 = (unsigned short*)(ws);                // 0..8MB
  unsigned short* Of2 = (unsigned short*)(ws + (8u << 20));   // 8..16MB
  unsigned short* Of3 = (unsigned short*)(ws + (16u << 20));  // 16..24MB

  // fused converts: one launch, 5 matrices
  k_cvt5<<<dim3(2048, 5), 256, 0, stream>>>(
      x, wq, wk, wv, wo,
      xb, w1b, w1b + (size_t)4 * 1024 * 1024, w1b + (size_t)8 * 1024 * 1024, wob);

  // fused QKV projection (+ fused V-transpose): 2048 x 6144 x 2048, 256 blocks
  k_gemm192<<<dim3(32, 8), 512, 0, stream>>>(xb, w1b, qraw, out_k, out_v, vtb);

  k_rope<<<TT, 256, 0, stream>>>(qraw, out_k, sqk, qb, kb);

  // attention: mirrored-pair blocks, 256 uniform blocks, direct output
  k_attn_pair<<<dim3(16, 16), 512, 0, stream>>>(qb, kb, vtb, obb);

  // output projection: 2048 x 2048 x 2048, split-K=4 (256 blocks), bf16 partials
  k_gemm8p<<<dim3(8, 8, 4), 512, 0, stream>>>(obb, wob, CC, CC, CC / 4,
                                              Of0, Of1, Of2, Of3);

  k_l2norm<<<TT, 256, 0, stream>>>(Of0, Of1, Of2, Of3, out_norm);
}